// Round 8
// baseline (312.304 us; speedup 1.0000x reference)
//
#include <hip/hip_runtime.h>
#include <hip/hip_bf16.h>
#include <math.h>

#define E_    8
#define HID_  1024
#define FFN_  2048
#define M_    2048     // B*S
#define NP_   (M_*2)   // total (token, expert) pairs

typedef __attribute__((ext_vector_type(8))) short bf16x8;
typedef __attribute__((ext_vector_type(4))) float f32x4;

typedef const __attribute__((address_space(1))) void GVOID;
typedef __attribute__((address_space(3))) void LVOID;

#define VMCNT6 asm volatile("s_waitcnt vmcnt(6)" ::: "memory")

__device__ __forceinline__ short f2bf(float f) {
    union { __hip_bfloat16 b; short s; } u;
    u.b = __float2bfloat16(f);
    return u.s;
}

// ---------------------------------------------------------------------------
// w1 + w2 fp32 -> bf16 in one kernel (grid-stride over both)
// ---------------------------------------------------------------------------
__global__ __launch_bounds__(256) void cvt_w_kernel(
    const float* __restrict__ w1, const float* __restrict__ w2,
    __hip_bfloat16* __restrict__ w1bf, __hip_bfloat16* __restrict__ w2bf)
{
    const int n1 = (E_*2*FFN_*HID_)/4;
    const int n2 = (E_*HID_*FFN_)/4;
    int stride = gridDim.x * 256;
    for (int i = blockIdx.x * 256 + threadIdx.x; i < n1 + n2; i += stride) {
        float4 v;
        if (i < n1) v = ((const float4*)w1)[i];
        else        v = ((const float4*)w2)[i - n1];
        short4 o;
        o.x = f2bf(v.x); o.y = f2bf(v.y); o.z = f2bf(v.z); o.w = f2bf(v.w);
        if (i < n1) ((short4*)w1bf)[i] = o;
        else        ((short4*)w2bf)[i - n1] = o;
    }
}

// ---------------------------------------------------------------------------
// Router (+ fused x->bf16 conversion): one wave per token.
// ---------------------------------------------------------------------------
__global__ __launch_bounds__(64) void router_kernel(
    const float* __restrict__ x, const float* __restrict__ rw,
    const float* __restrict__ rb, int* __restrict__ ids,
    float* __restrict__ wts, int* __restrict__ cnt,
    float* __restrict__ topk_out, __hip_bfloat16* __restrict__ xb)
{
    const int m    = blockIdx.x;
    const int lane = threadIdx.x;
    const float4* xm4 = (const float4*)(x + (size_t)m * HID_);

    float4 xv[4];
#pragma unroll
    for (int j = 0; j < 4; ++j) xv[j] = xm4[j*64 + lane];

    short4* xbr = (short4*)(xb + (size_t)m * HID_);
#pragma unroll
    for (int j = 0; j < 4; ++j) {
        short4 o;
        o.x = f2bf(xv[j].x); o.y = f2bf(xv[j].y);
        o.z = f2bf(xv[j].z); o.w = f2bf(xv[j].w);
        xbr[j*64 + lane] = o;
    }

    float lg[E_];
#pragma unroll
    for (int e = 0; e < E_; ++e) {
        const float4* we4 = (const float4*)(rw + e * HID_);
        float s = 0.f;
#pragma unroll
        for (int j = 0; j < 4; ++j) {
            float4 w = we4[j*64 + lane];
            s = fmaf(xv[j].x, w.x, s);
            s = fmaf(xv[j].y, w.y, s);
            s = fmaf(xv[j].z, w.z, s);
            s = fmaf(xv[j].w, w.w, s);
        }
        lg[e] = s;
    }
#pragma unroll
    for (int off = 32; off; off >>= 1)
#pragma unroll
        for (int e = 0; e < E_; ++e) lg[e] += __shfl_xor(lg[e], off);

    if (lane == 0) {
        float l2[E_], p[E_];
        float mx = -1e30f;
#pragma unroll
        for (int e = 0; e < E_; ++e) { l2[e] = lg[e] + rb[e]; mx = fmaxf(mx, l2[e]); }
        float sum = 0.f;
#pragma unroll
        for (int e = 0; e < E_; ++e) { p[e] = expf(l2[e] - mx); sum += p[e]; }
        float inv = 1.f / sum;
#pragma unroll
        for (int e = 0; e < E_; ++e) p[e] *= inv;

        int   i1 = -1, i2 = -1;
        float v1 = -1e30f, v2 = -1e30f;
#pragma unroll
        for (int e = 0; e < E_; ++e) {
            float pe = p[e];
            if (pe > v1)      { v2 = v1; i2 = i1; v1 = pe; i1 = e; }
            else if (pe > v2) { v2 = pe; i2 = e; }
        }
        ids[2*m]   = i1;  ids[2*m+1]   = i2;
        wts[2*m]   = v1;  wts[2*m+1]   = v2;
        topk_out[2*m]   = v1;
        topk_out[2*m+1] = v2;
        atomicAdd(&cnt[i1], 1);
        atomicAdd(&cnt[i2], 1);
    }
}

__global__ void offsets_kernel(const int* __restrict__ cnt,
                               int* __restrict__ off, int* __restrict__ fill)
{
    if (threadIdx.x == 0 && blockIdx.x == 0) {
        int acc = 0;
        for (int e = 0; e < E_; ++e) { off[e] = acc; fill[e] = acc; acc += cnt[e]; }
    }
}

__global__ __launch_bounds__(256) void scatter_kernel(
    const int* __restrict__ ids, const float* __restrict__ wts,
    int* __restrict__ fill, int* __restrict__ gtok, float* __restrict__ gwt,
    int* __restrict__ pos)
{
    int m = blockIdx.x * 256 + threadIdx.x;
    if (m >= M_) return;
#pragma unroll
    for (int s = 0; s < 2; ++s) {
        int e = ids[2*m + s];
        int p = atomicAdd(&fill[e], 1);
        gtok[p] = m;
        gwt[p]  = wts[2*m + s];
        pos[2*m + s] = p;
    }
}

// ===========================================================================
// TIER-2 GEMMs: 128x128 block, 4 waves of 64x64 (acc[4][4]).
// A operand: per-lane bf16x8 fragment loads STRAIGHT FROM GLOBAL (L2/L3
// resident: xb=4MB, h=16MB), double-buffered in registers one K-step ahead.
// B operand: LDS, triple-buffered via global_load_lds, depth-2 prefetch,
// counted vmcnt(6): at each barrier only {B(t+2):2, A(t+1):4} are in flight
// (the compiler's wait on A(t) regs before COMPUTE retires older B(t+1)).
// LDS swizzle on B: 16B chunk p of row r holds global chunk p ^ ((r>>1)&3).
// ===========================================================================

// GEMM1: 128 gathered tokens x 64 h-cols (128 gu rows). K = 1024, NT = 32.
__global__ __launch_bounds__(256, 3) void gemm1_kernel(
    const __hip_bfloat16* __restrict__ xb, const __hip_bfloat16* __restrict__ w1bf,
    const float* __restrict__ w1b, const int* __restrict__ gtok,
    const int* __restrict__ cnt, const int* __restrict__ off,
    __hip_bfloat16* __restrict__ h)
{
    const int e  = blockIdx.z;
    const int ce = cnt[e];
    const int t0 = blockIdx.y * 128;
    if (t0 >= ce) return;
    const int n0   = blockIdx.x * 64;
    const int base = off[e];
    const __hip_bfloat16* w1e = w1bf + (size_t)e * (2*FFN_) * HID_;

    __shared__ __align__(16) __hip_bfloat16 Bs[3][128*32];

    const int tid  = threadIdx.x;
    const int lane = tid & 63;
    const int wid  = tid >> 6;
    const int wm   = wid >> 1;
    const int wn   = wid & 1;
    const int cf   = lane >> 4;

    // B stage sources (2 x 16B per thread), inverse-swizzled
    const __hip_bfloat16* bsrc[2];
#pragma unroll
    for (int q = 0; q < 2; ++q) {
        int slot = q*256 + tid;
        int r = slot >> 2, p = slot & 3;
        int c = p ^ ((r >> 1) & 3);
        int q2 = r >> 5, s = r & 31;
        int grow = (q2 & 1) ? (FFN_ + n0 + (q2>>1)*32 + s)
                            : (       n0 + (q2>>1)*32 + s);
        bsrc[q] = w1e + (size_t)grow * HID_ + c*8;
    }

    // A fragment base pointers (4 per thread, gathered rows)
    const __hip_bfloat16* abase[4];
#pragma unroll
    for (int m = 0; m < 4; ++m) {
        int row = t0 + wm*64 + m*16 + (lane & 15);
        int rr  = min(row, ce - 1);
        abase[m] = xb + (size_t)gtok[base + rr] * HID_ + cf*8;
    }

    auto STAGE_B = [&](int b, int k0) {
#pragma unroll
        for (int q = 0; q < 2; ++q)
            __builtin_amdgcn_global_load_lds((GVOID*)(bsrc[q] + k0),
                (LVOID*)(&Bs[b][(q*256 + wid*64)*8]), 16, 0, 0);
    };

    f32x4 acc[4][4];
#pragma unroll
    for (int m = 0; m < 4; ++m)
#pragma unroll
        for (int n = 0; n < 4; ++n) acc[m][n] = (f32x4){0.f,0.f,0.f,0.f};

    auto COMPUTE = [&](int cb, bf16x8* af) {
        bf16x8 bfr[4];
#pragma unroll
        for (int n = 0; n < 4; ++n) {
            int r = wn*64 + n*16 + (lane & 15);
            int sw = cf ^ ((r >> 1) & 3);
            bfr[n] = *(bf16x8*)&Bs[cb][r*32 + sw*8];
        }
        __builtin_amdgcn_s_setprio(1);
#pragma unroll
        for (int m = 0; m < 4; ++m)
#pragma unroll
            for (int n = 0; n < 4; ++n)
                acc[m][n] = __builtin_amdgcn_mfma_f32_16x16x32_bf16(
                    af[m], bfr[n], acc[m][n], 0, 0, 0);
        __builtin_amdgcn_s_setprio(0);
    };

    const int NT = HID_/32;   // 32
    bf16x8 aA[4], aB[4];

    STAGE_B(0, 0);
    STAGE_B(1, 32);
#pragma unroll
    for (int m = 0; m < 4; ++m) aA[m] = *(const bf16x8*)(abase[m]);
    VMCNT6;
    __builtin_amdgcn_s_barrier();

    int cb = 0;
    auto ITER = [&](int t, bf16x8* aCur, bf16x8* aNxt) {
        int sb = cb + 2; if (sb >= 3) sb -= 3;
        if (t <= NT-3) STAGE_B(sb, (t+2)*32);
#pragma unroll
        for (int m = 0; m < 4; ++m)
            aNxt[m] = *(const bf16x8*)(abase[m] + (t+1)*32);
        COMPUTE(cb, aCur);
        VMCNT6;
        __builtin_amdgcn_s_barrier();
        if (++cb == 3) cb = 0;
    };

    for (int t = 0; t < NT-2; t += 2) {   // t = 0..29 in pairs
        ITER(t,   aA, aB);
        ITER(t+1, aB, aA);
    }
    ITER(NT-2, aA, aB);                   // computes tile 30, loads A(31)
    COMPUTE(cb, aB);                      // tile 31

    // Epilogue: fused SiLU(gate)*up -> h (bf16)
    const float* w1be = w1b + e*2*FFN_;
#pragma unroll
    for (int n = 0; n < 2; ++n) {
        int col = n0 + wn*32 + n*16 + (lane & 15);
        float bg = w1be[col];
        float bu = w1be[FFN_ + col];
#pragma unroll
        for (int m = 0; m < 4; ++m) {
            int rb2 = t0 + wm*64 + m*16 + (lane >> 4)*4;
#pragma unroll
            for (int i = 0; i < 4; ++i) {
                int t = rb2 + i;
                if (t < ce) {
                    float g = acc[m][n][i]   + bg;
                    float u = acc[m][n+2][i] + bu;
                    float hv = (g / (1.f + __expf(-g))) * u;
                    h[(size_t)(base + t)*FFN_ + col] = __float2bfloat16(hv);
                }
            }
        }
    }
}

// GEMM2: 128 pairs x 128 hid cols, split-K=2 (z = e + 8*ks). Plain stores
// into dpair[ks]; combine sums 4 slices. K-half = 1024, NT = 32.
__global__ __launch_bounds__(256, 3) void gemm2_kernel(
    const __hip_bfloat16* __restrict__ h, const __hip_bfloat16* __restrict__ w2bf,
    const float* __restrict__ w2b, const float* __restrict__ gwt,
    const int* __restrict__ cnt, const int* __restrict__ off,
    float* __restrict__ dpair)
{
    const int e  = blockIdx.z & 7;
    const int ks = blockIdx.z >> 3;
    const int ce = cnt[e];
    const int t0 = blockIdx.y * 128;
    if (t0 >= ce) return;
    const int n0    = blockIdx.x * 128;
    const int base  = off[e];
    const int kbase = ks * (FFN_/2);
    const __hip_bfloat16* w2e = w2bf + (size_t)e * HID_ * FFN_;

    __shared__ __align__(16) __hip_bfloat16 Bs[3][128*32];

    const int tid  = threadIdx.x;
    const int lane = tid & 63;
    const int wid  = tid >> 6;
    const int wm   = wid >> 1;
    const int wn   = wid & 1;
    const int cf   = lane >> 4;

    const __hip_bfloat16* bsrc[2];
#pragma unroll
    for (int q = 0; q < 2; ++q) {
        int slot = q*256 + tid;
        int r = slot >> 2, p = slot & 3;
        int c = p ^ ((r >> 1) & 3);
        bsrc[q] = w2e + (size_t)(n0 + r) * FFN_ + kbase + c*8;
    }

    const __hip_bfloat16* abase[4];
#pragma unroll
    for (int m = 0; m < 4; ++m) {
        int row = t0 + wm*64 + m*16 + (lane & 15);
        int rr  = min(row, ce - 1);
        abase[m] = h + (size_t)(base + rr) * FFN_ + kbase + cf*8;
    }

    auto STAGE_B = [&](int b, int k0) {
#pragma unroll
        for (int q = 0; q < 2; ++q)
            __builtin_amdgcn_global_load_lds((GVOID*)(bsrc[q] + k0),
                (LVOID*)(&Bs[b][(q*256 + wid*64)*8]), 16, 0, 0);
    };

    f32x4 acc[4][4];
#pragma unroll
    for (int m = 0; m < 4; ++m)
#pragma unroll
        for (int n = 0; n < 4; ++n) acc[m][n] = (f32x4){0.f,0.f,0.f,0.f};

    auto COMPUTE = [&](int cb, bf16x8* af) {
        bf16x8 bfr[4];
#pragma unroll
        for (int n = 0; n < 4; ++n) {
            int r = wn*64 + n*16 + (lane & 15);
            int sw = cf ^ ((r >> 1) & 3);
            bfr[n] = *(bf16x8*)&Bs[cb][r*32 + sw*8];
        }
        __builtin_amdgcn_s_setprio(1);
#pragma unroll
        for (int m = 0; m < 4; ++m)
#pragma unroll
            for (int n = 0; n < 4; ++n)
                acc[m][n] = __builtin_amdgcn_mfma_f32_16x16x32_bf16(
                    af[m], bfr[n], acc[m][n], 0, 0, 0);
        __builtin_amdgcn_s_setprio(0);
    };

    const int NT = (FFN_/2)/32;   // 32
    bf16x8 aA[4], aB[4];

    STAGE_B(0, 0);
    STAGE_B(1, 32);
#pragma unroll
    for (int m = 0; m < 4; ++m) aA[m] = *(const bf16x8*)(abase[m]);
    VMCNT6;
    __builtin_amdgcn_s_barrier();

    int cb = 0;
    auto ITER = [&](int t, bf16x8* aCur, bf16x8* aNxt) {
        int sb = cb + 2; if (sb >= 3) sb -= 3;
        if (t <= NT-3) STAGE_B(sb, (t+2)*32);
#pragma unroll
        for (int m = 0; m < 4; ++m)
            aNxt[m] = *(const bf16x8*)(abase[m] + (t+1)*32);
        COMPUTE(cb, aCur);
        VMCNT6;
        __builtin_amdgcn_s_barrier();
        if (++cb == 3) cb = 0;
    };

    for (int t = 0; t < NT-2; t += 2) {
        ITER(t,   aA, aB);
        ITER(t+1, aB, aA);
    }
    ITER(NT-2, aA, aB);
    COMPUTE(cb, aB);

    const float* w2be = w2b + e*HID_;
    float* dpk = dpair + (size_t)ks * NP_ * HID_;
#pragma unroll
    for (int n = 0; n < 4; ++n) {
        int col = n0 + wn*64 + n*16 + (lane & 15);
        float bias = (ks == 0) ? w2be[col] : 0.f;
#pragma unroll
        for (int m = 0; m < 4; ++m) {
            int rb2 = t0 + wm*64 + m*16 + (lane >> 4)*4;
#pragma unroll
            for (int i = 0; i < 4; ++i) {
                int t = rb2 + i;
                if (t < ce) {
                    int p   = base + t;
                    float w = gwt[p];
                    dpk[(size_t)p*HID_ + col] = w * (acc[m][n][i] + bias);
                }
            }
        }
    }
}

// out[m][c] = d0[p0][c]+d1[p0][c]+d0[p1][c]+d1[p1][c]   (fixed order)
__global__ __launch_bounds__(256) void combine_kernel(
    const float* __restrict__ dpair, const int* __restrict__ pos,
    float* __restrict__ out)
{
    int idx = blockIdx.x * 256 + threadIdx.x;
    int m   = idx >> 8;
    int c4  = (idx & 255) * 4;
    int p0 = pos[2*m], p1 = pos[2*m+1];
    const float* d0 = dpair;
    const float* d1 = dpair + (size_t)NP_ * HID_;
    float4 a0 = *(const float4*)(d0 + (size_t)p0*HID_ + c4);
    float4 a1 = *(const float4*)(d1 + (size_t)p0*HID_ + c4);
    float4 b0 = *(const float4*)(d0 + (size_t)p1*HID_ + c4);
    float4 b1 = *(const float4*)(d1 + (size_t)p1*HID_ + c4);
    float4 o = make_float4((a0.x+a1.x)+(b0.x+b1.x), (a0.y+a1.y)+(b0.y+b1.y),
                           (a0.z+a1.z)+(b0.z+b1.z), (a0.w+a1.w)+(b0.w+b1.w));
    *(float4*)(out + (size_t)m*HID_ + c4) = o;
}

// ===========================================================================
// FALLBACK (proven round-2 structure) — only if ws_size too small for tier2.
// ===========================================================================
__global__ __launch_bounds__(256) void gemm1_rs_kernel(
    const __hip_bfloat16* __restrict__ xb, const float* __restrict__ w1,
    const float* __restrict__ w1b, const int* __restrict__ gtok,
    const int* __restrict__ cnt, const int* __restrict__ off,
    __hip_bfloat16* __restrict__ h)
{
    const int e  = blockIdx.z;
    const int ce = cnt[e];
    const int t0 = blockIdx.y * 128;
    if (t0 >= ce) return;
    const int n0   = blockIdx.x * 64;
    const int base = off[e];
    const float* w1e = w1 + (size_t)e * (2*FFN_) * HID_;

    __shared__ __align__(16) __hip_bfloat16 As[128*64];
    __shared__ __align__(16) __hip_bfloat16 Bs[128*64];

    const int tid  = threadIdx.x;
    const int lane = tid & 63;
    const int wid  = tid >> 6;
    const int wm   = wid >> 1;
    const int wn   = wid & 1;

    const __hip_bfloat16* asrc[4];
#pragma unroll
    for (int q = 0; q < 4; ++q) {
        int slot = q*256 + tid;
        int r = slot >> 3, p = slot & 7;
        int rr  = min(t0 + r, ce - 1);
        int tok = gtok[base + rr];
        int c = p ^ (r & 7);
        asrc[q] = xb + (size_t)tok * HID_ + c*8;
    }

    const int brow = tid >> 1;
    const int hk   = tid & 1;
    const int q2 = brow >> 5, s = brow & 31;
    const int grow = (q2 & 1) ? (FFN_ + n0 + (q2>>1)*32 + s)
                              : (       n0 + (q2>>1)*32 + s);
    const float* bsrc = w1e + (size_t)grow * HID_ + hk*32;

    f32x4 acc[4][4];
#pragma unroll
    for (int m = 0; m < 4; ++m)
#pragma unroll
        for (int n = 0; n < 4; ++n) acc[m][n] = (f32x4){0.f,0.f,0.f,0.f};

    float4 breg[8];
#pragma unroll
    for (int j = 0; j < 8; ++j) breg[j] = *(const float4*)(bsrc + j*4);

    for (int k0 = 0; k0 < HID_; k0 += 64) {
#pragma unroll
        for (int q = 0; q < 4; ++q) {
            __builtin_amdgcn_global_load_lds(
                (GVOID*)(asrc[q] + k0),
                (LVOID*)(&As[(q*256 + wid*64)*8]), 16, 0, 0);
        }
#pragma unroll
        for (int cc = 0; cc < 4; ++cc) {
            union { bf16x8 v; short s8[8]; } u;
            const float* f0 = (const float*)&breg[2*cc];
#pragma unroll
            for (int j = 0; j < 8; ++j) u.s8[j] = f2bf(f0[j]);
            int c = hk*4 + cc, p = c ^ (brow & 7);
            *(bf16x8*)&Bs[brow*64 + p*8] = u.v;
        }
        __syncthreads();

        if (k0 + 64 < HID_) {
#pragma unroll
            for (int j = 0; j < 8; ++j) breg[j] = *(const float4*)(bsrc + (k0+64) + j*4);
        }

        bf16x8 af[4][2], bfr[4][2];
#pragma unroll
        for (int m = 0; m < 4; ++m)
#pragma unroll
            for (int kk = 0; kk < 2; ++kk) {
                int r = wm*64 + m*16 + (lane & 15);
                int c = kk*4 + (lane >> 4), p = c ^ (r & 7);
                af[m][kk] = *(bf16x8*)&As[r*64 + p*8];
            }
#pragma unroll
        for (int n = 0; n < 4; ++n)
#pragma unroll
            for (int kk = 0; kk < 2; ++kk) {
                int r = wn*64 + n*16 + (lane & 15);
                int c = kk*4 + (lane >> 4), p = c ^ (r & 7);
                bfr[n][kk] = *(bf16x8*)&Bs[r*64 + p*8];
            }
#pragma unroll
        for (int kk = 0; kk < 2; ++kk)
#pragma unroll
            for (int m = 0; m < 4; ++m)
#pragma unroll
                for (int n = 0; n < 4; ++n)
                    acc[m][n] = __builtin_amdgcn_mfma_f32_16x16x32_bf16(
                        af[m][kk], bfr[n][kk], acc[m][n], 0, 0, 0);
        __syncthreads();
    }

    const float* w1be = w1b + e*2*FFN_;
#pragma unroll
    for (int n = 0; n < 2; ++n) {
        int col = n0 + wn*32 + n*16 + (lane & 15);
        float bg = w1be[col];
        float bu = w1be[FFN_ + col];
#pragma unroll
        for (int m = 0; m < 4; ++m) {
            int rb2 = t0 + wm*64 + m*16 + (lane >> 4)*4;
#pragma unroll
            for (int i = 0; i < 4; ++i) {
                int t = rb2 + i;
                if (t < ce) {
                    float g = acc[m][n][i]   + bg;
                    float u = acc[m][n+2][i] + bu;
                    float hv = (g / (1.f + __expf(-g))) * u;
                    h[(size_t)(base + t)*FFN_ + col] = __float2bfloat16(hv);
                }
            }
        }
    }
}

__global__ __launch_bounds__(256) void gemm2_rs_kernel(
    const __hip_bfloat16* __restrict__ h, const float* __restrict__ w2,
    const float* __restrict__ w2b, const int* __restrict__ gtok,
    const float* __restrict__ gwt, const int* __restrict__ cnt,
    const int* __restrict__ off, float* __restrict__ out)
{
    const int e  = blockIdx.z;
    const int ce = cnt[e];
    const int t0 = blockIdx.y * 128;
    if (t0 >= ce) return;
    const int n0   = blockIdx.x * 128;
    const int base = off[e];
    const float* w2e = w2 + (size_t)e * HID_ * FFN_;

    __shared__ __align__(16) __hip_bfloat16 As[128*64];
    __shared__ __align__(16) __hip_bfloat16 Bs[128*64];

    const int tid  = threadIdx.x;
    const int lane = tid & 63;
    const int wid  = tid >> 6;
    const int wm   = wid >> 1;
    const int wn   = wid & 1;

    const __hip_bfloat16* asrc[4];
#pragma unroll
    for (int q = 0; q < 4; ++q) {
        int slot = q*256 + tid;
        int r = slot >> 3, p = slot & 7;
        int rr = min(t0 + r, ce - 1);
        int c = p ^ (r & 7);
        asrc[q] = h + (size_t)(base + rr) * FFN_ + c*8;
    }

    const int brow = tid >> 1;
    const int hk   = tid & 1;
    const float* bsrc = w2e + (size_t)(n0 + brow) * FFN_ + hk*32;

    f32x4 acc[4][4];
#pragma unroll
    for (int m = 0; m < 4; ++m)
#pragma unroll
        for (int n = 0; n < 4; ++n) acc[m][n] = (f32x4){0.f,0.f,0.f,0.f};

    float4 breg[8];
#pragma unroll
    for (int j = 0; j < 8; ++j) breg[j] = *(const float4*)(bsrc + j*4);

    for (int k0 = 0; k0 < FFN_; k0 += 64) {
#pragma unroll
        for (int q = 0; q < 4; ++q) {
            __builtin_amdgcn_global_load_lds(
                (GVOID*)(asrc[q] + k0),
                (LVOID*)(&As[(q*256 + wid*64)*8]), 16, 0, 0);
        }
#pragma unroll
        for (int cc = 0; cc < 4; ++cc) {
            union { bf16x8 v; short s8[8]; } u;
            const float* f0 = (const float*)&breg[2*cc];
#pragma unroll
            for (int j = 0; j < 8; ++j) u.s8[j] = f2bf(f0[j]);
            int c = hk*4 + cc, p = c ^ (brow & 7);
            *(bf16x8*)&Bs[brow*64 + p*8] = u.v;
        }
        __syncthreads();

        if (k0 + 64 < FFN_) {
#pragma unroll
            for (int j = 0; j < 8; ++j) breg[j] = *(const float4*)(bsrc + (k0+64) + j*4);
        }

        bf16x8 af[4][2], bfr[4][2];
#pragma unroll
        for (int m = 0; m < 4; ++m)
#pragma unroll
            for (int kk = 0; kk < 2; ++kk) {
                int r = wm*64 + m*16 + (lane & 15);
                int c = kk*4 + (lane >> 4), p = c ^ (r & 7);
                af[m][kk] = *(bf16x8*)&As[r*64 + p*8];
            }
#pragma unroll
        for (int n = 0; n < 4; ++n)
#pragma unroll
            for (int kk = 0; kk < 2; ++kk) {
                int r = wn*64 + n*16 + (lane & 15);
                int c = kk*4 + (lane >> 4), p = c ^ (r & 7);
                bfr[n][kk] = *(bf16x8*)&Bs[r*64 + p*8];
            }
#pragma unroll
        for (int kk = 0; kk < 2; ++kk)
#pragma unroll
            for (int m = 0; m < 4; ++m)
#pragma unroll
                for (int n = 0; n < 4; ++n)
                    acc[m][n] = __builtin_amdgcn_mfma_f32_16x16x32_bf16(
                        af[m][kk], bfr[n][kk], acc[m][n], 0, 0, 0);
        __syncthreads();
    }

    const float* w2be = w2b + e*HID_;
#pragma unroll
    for (int n = 0; n < 4; ++n) {
        int col = n0 + wn*64 + n*16 + (lane & 15);
        float bias = w2be[col];
#pragma unroll
        for (int m = 0; m < 4; ++m) {
            int rb2 = t0 + wm*64 + m*16 + (lane >> 4)*4;
#pragma unroll
            for (int i = 0; i < 4; ++i) {
                int t = rb2 + i;
                if (t < ce) {
                    int p   = base + t;
                    float w = gwt[p];
                    atomicAdd(&out[(size_t)gtok[p]*HID_ + col], w * (acc[m][n][i] + bias));
                }
            }
        }
    }
}

// ---------------------------------------------------------------------------
extern "C" void kernel_launch(void* const* d_in, const int* in_sizes, int n_in,
                              void* d_out, int out_size, void* d_ws, size_t ws_size,
                              hipStream_t stream)
{
    const float* x   = (const float*)d_in[0];
    const float* rw  = (const float*)d_in[1];
    const float* rb  = (const float*)d_in[2];
    const float* w1  = (const float*)d_in[3];
    const float* w1b = (const float*)d_in[4];
    const float* w2  = (const float*)d_in[5];
    const float* w2b = (const float*)d_in[6];

    float* out      = (float*)d_out;
    float* topk_out = out + (size_t)M_ * HID_;

    char*  ws   = (char*)d_ws;
    int*   ids  = (int*)  (ws);
    float* wts  = (float*)(ws + 16384);
    int*   gtok = (int*)  (ws + 32768);
    float* gwt  = (float*)(ws + 49152);
    int*   cnt  = (int*)  (ws + 65536);
    int*   off  = (int*)  (ws + 65536 + 128);
    int*   fill = (int*)  (ws + 65536 + 256);
    int*   pos  = (int*)  (ws + 98304);

    const size_t MB = 1024*1024;
    __hip_bfloat16* xb    = (__hip_bfloat16*)(ws + 131072);            // 4 MB
    __hip_bfloat16* h     = (__hip_bfloat16*)(ws + 131072 + 4*MB);     // 16 MB
    float*          dpair = (float*)         (ws + 131072 + 20*MB);    // 32 MB (2 slices)
    __hip_bfloat16* w1bf  = (__hip_bfloat16*)(ws + 131072 + 52*MB);    // 64 MB
    __hip_bfloat16* w2bf  = (__hip_bfloat16*)(ws + 131072 + 116*MB);   // 32 MB
    const bool tier2 = (ws_size >= 131072 + 148*MB);

    hipMemsetAsync(cnt, 0, E_ * sizeof(int), stream);

    router_kernel<<<M_, 64, 0, stream>>>(x, rw, rb, ids, wts, cnt, topk_out, xb);
    offsets_kernel<<<1, 64, 0, stream>>>(cnt, off, fill);
    scatter_kernel<<<M_/256, 256, 0, stream>>>(ids, wts, fill, gtok, gwt, pos);

    if (tier2) {
        cvt_w_kernel<<<4096, 256, 0, stream>>>(w1, w2, w1bf, w2bf);

        dim3 g1(FFN_/64, M_/128, E_);        // (32, 16, 8)
        gemm1_kernel<<<g1, 256, 0, stream>>>(xb, w1bf, w1b, gtok, cnt, off, h);

        dim3 g2(HID_/128, M_/128, 2*E_);     // (8, 16, 16) split-K=2
        gemm2_kernel<<<g2, 256, 0, stream>>>(h, w2bf, w2b, gwt, cnt, off, dpair);

        combine_kernel<<<(M_*HID_)/(256*4), 256, 0, stream>>>(dpair, pos, out);
    } else {
        hipMemsetAsync(out, 0, (size_t)M_ * HID_ * sizeof(float), stream);

        dim3 g1(FFN_/64, M_/128, E_);
        gemm1_rs_kernel<<<g1, 256, 0, stream>>>(xb, w1, w1b, gtok, cnt, off, h);

        dim3 g2(HID_/128, M_/128, E_);
        gemm2_rs_kernel<<<g2, 256, 0, stream>>>(h, w2, w2b, gtok, gwt, cnt, off, out);
    }
}

// Round 9
// 286.976 us; speedup vs baseline: 1.0883x; 1.0883x over previous
//
#include <hip/hip_runtime.h>
#include <hip/hip_bf16.h>
#include <math.h>

#define E_    8
#define HID_  1024
#define FFN_  2048
#define M_    2048     // B*S
#define NP_   (M_*2)   // total (token, expert) pairs

typedef __attribute__((ext_vector_type(8))) short bf16x8;
typedef __attribute__((ext_vector_type(4))) float f32x4;

typedef const __attribute__((address_space(1))) void GVOID;
typedef __attribute__((address_space(3))) void LVOID;

#define VMCNT8 asm volatile("s_waitcnt vmcnt(8)" ::: "memory")
#define VMCNT4 asm volatile("s_waitcnt vmcnt(4)" ::: "memory")
#define VMCNT0 asm volatile("s_waitcnt vmcnt(0)" ::: "memory")

__device__ __forceinline__ short f2bf(float f) {
    union { __hip_bfloat16 b; short s; } u;
    u.b = __float2bfloat16(f);
    return u.s;
}

// ---------------------------------------------------------------------------
// w1 + w2 fp32 -> bf16 in one kernel (grid-stride over both)
// ---------------------------------------------------------------------------
__global__ __launch_bounds__(256) void cvt_w_kernel(
    const float* __restrict__ w1, const float* __restrict__ w2,
    __hip_bfloat16* __restrict__ w1bf, __hip_bfloat16* __restrict__ w2bf)
{
    const int n1 = (E_*2*FFN_*HID_)/4;
    const int n2 = (E_*HID_*FFN_)/4;
    int stride = gridDim.x * 256;
    for (int i = blockIdx.x * 256 + threadIdx.x; i < n1 + n2; i += stride) {
        float4 v;
        if (i < n1) v = ((const float4*)w1)[i];
        else        v = ((const float4*)w2)[i - n1];
        short4 o;
        o.x = f2bf(v.x); o.y = f2bf(v.y); o.z = f2bf(v.z); o.w = f2bf(v.w);
        if (i < n1) ((short4*)w1bf)[i] = o;
        else        ((short4*)w2bf)[i - n1] = o;
    }
}

// ---------------------------------------------------------------------------
// Router (+ fused x->bf16 conversion): one wave per token.  [proven]
// ---------------------------------------------------------------------------
__global__ __launch_bounds__(64) void router_kernel(
    const float* __restrict__ x, const float* __restrict__ rw,
    const float* __restrict__ rb, int* __restrict__ ids,
    float* __restrict__ wts, int* __restrict__ cnt,
    float* __restrict__ topk_out, __hip_bfloat16* __restrict__ xb)
{
    const int m    = blockIdx.x;
    const int lane = threadIdx.x;
    const float4* xm4 = (const float4*)(x + (size_t)m * HID_);

    float4 xv[4];
#pragma unroll
    for (int j = 0; j < 4; ++j) xv[j] = xm4[j*64 + lane];

    short4* xbr = (short4*)(xb + (size_t)m * HID_);
#pragma unroll
    for (int j = 0; j < 4; ++j) {
        short4 o;
        o.x = f2bf(xv[j].x); o.y = f2bf(xv[j].y);
        o.z = f2bf(xv[j].z); o.w = f2bf(xv[j].w);
        xbr[j*64 + lane] = o;
    }

    float lg[E_];
#pragma unroll
    for (int e = 0; e < E_; ++e) {
        const float4* we4 = (const float4*)(rw + e * HID_);
        float s = 0.f;
#pragma unroll
        for (int j = 0; j < 4; ++j) {
            float4 w = we4[j*64 + lane];
            s = fmaf(xv[j].x, w.x, s);
            s = fmaf(xv[j].y, w.y, s);
            s = fmaf(xv[j].z, w.z, s);
            s = fmaf(xv[j].w, w.w, s);
        }
        lg[e] = s;
    }
#pragma unroll
    for (int off = 32; off; off >>= 1)
#pragma unroll
        for (int e = 0; e < E_; ++e) lg[e] += __shfl_xor(lg[e], off);

    if (lane == 0) {
        float l2[E_], p[E_];
        float mx = -1e30f;
#pragma unroll
        for (int e = 0; e < E_; ++e) { l2[e] = lg[e] + rb[e]; mx = fmaxf(mx, l2[e]); }
        float sum = 0.f;
#pragma unroll
        for (int e = 0; e < E_; ++e) { p[e] = expf(l2[e] - mx); sum += p[e]; }
        float inv = 1.f / sum;
#pragma unroll
        for (int e = 0; e < E_; ++e) p[e] *= inv;

        int   i1 = -1, i2 = -1;
        float v1 = -1e30f, v2 = -1e30f;
#pragma unroll
        for (int e = 0; e < E_; ++e) {
            float pe = p[e];
            if (pe > v1)      { v2 = v1; i2 = i1; v1 = pe; i1 = e; }
            else if (pe > v2) { v2 = pe; i2 = e; }
        }
        ids[2*m]   = i1;  ids[2*m+1]   = i2;
        wts[2*m]   = v1;  wts[2*m+1]   = v2;
        topk_out[2*m]   = v1;
        topk_out[2*m+1] = v2;
        atomicAdd(&cnt[i1], 1);
        atomicAdd(&cnt[i2], 1);
    }
}

__global__ void offsets_kernel(const int* __restrict__ cnt,
                               int* __restrict__ off, int* __restrict__ fill)
{
    if (threadIdx.x == 0 && blockIdx.x == 0) {
        int acc = 0;
        for (int e = 0; e < E_; ++e) { off[e] = acc; fill[e] = acc; acc += cnt[e]; }
    }
}

__global__ __launch_bounds__(256) void scatter_kernel(
    const int* __restrict__ ids, const float* __restrict__ wts,
    int* __restrict__ fill, int* __restrict__ gtok, float* __restrict__ gwt,
    int* __restrict__ pos)
{
    int m = blockIdx.x * 256 + threadIdx.x;
    if (m >= M_) return;
#pragma unroll
    for (int s = 0; s < 2; ++s) {
        int e = ids[2*m + s];
        int p = atomicAdd(&fill[e], 1);
        gtok[p] = m;
        gwt[p]  = wts[2*m + s];
        pos[2*m + s] = p;
    }
}

// ===========================================================================
// TIER-2 GEMMs: round-6 structure (128x128 block, 4 waves of 64x64, BK=32,
// both operands via global_load_lds) with QUAD-buffered LDS, depth-3
// prefetch: stage tile t+3 each iter, counted vmcnt(8) at the barrier so
// tiles t+2 and t+3 (8 loads) stay in flight -> ~3 compute phases of HBM
// latency cover for the cold weight stream.  Epilogue: vmcnt(4), vmcnt(0).
// LDS swizzle: 16B chunk p of row r holds global chunk p ^ ((r>>1)&3).
// ===========================================================================

// GEMM1: 128 gathered tokens x 64 h-cols (128 gu rows). K = 1024, NT = 32.
__global__ __launch_bounds__(256, 2) void gemm1_kernel(
    const __hip_bfloat16* __restrict__ xb, const __hip_bfloat16* __restrict__ w1bf,
    const float* __restrict__ w1b, const int* __restrict__ gtok,
    const int* __restrict__ cnt, const int* __restrict__ off,
    __hip_bfloat16* __restrict__ h)
{
    const int e  = blockIdx.z;
    const int ce = cnt[e];
    const int t0 = blockIdx.y * 128;
    if (t0 >= ce) return;
    const int n0   = blockIdx.x * 64;
    const int base = off[e];
    const __hip_bfloat16* w1e = w1bf + (size_t)e * (2*FFN_) * HID_;

    __shared__ __align__(16) __hip_bfloat16 As[4][128*32];
    __shared__ __align__(16) __hip_bfloat16 Bs[4][128*32];

    const int tid  = threadIdx.x;
    const int lane = tid & 63;
    const int wid  = tid >> 6;
    const int wm   = wid >> 1;
    const int wn   = wid & 1;
    const int cf   = lane >> 4;

    const __hip_bfloat16 *asrc[2], *bsrc[2];
#pragma unroll
    for (int q = 0; q < 2; ++q) {
        int slot = q*256 + tid;
        int r = slot >> 2, p = slot & 3;
        int c = p ^ ((r >> 1) & 3);
        int rr  = min(t0 + r, ce - 1);
        asrc[q] = xb + (size_t)gtok[base + rr] * HID_ + c*8;
        int q2 = r >> 5, s = r & 31;
        int grow = (q2 & 1) ? (FFN_ + n0 + (q2>>1)*32 + s)
                            : (       n0 + (q2>>1)*32 + s);
        bsrc[q] = w1e + (size_t)grow * HID_ + c*8;
    }

    auto STAGE = [&](int b, int k0) {
#pragma unroll
        for (int q = 0; q < 2; ++q)
            __builtin_amdgcn_global_load_lds((GVOID*)(asrc[q] + k0),
                (LVOID*)(&As[b][(q*256 + wid*64)*8]), 16, 0, 0);
#pragma unroll
        for (int q = 0; q < 2; ++q)
            __builtin_amdgcn_global_load_lds((GVOID*)(bsrc[q] + k0),
                (LVOID*)(&Bs[b][(q*256 + wid*64)*8]), 16, 0, 0);
    };

    f32x4 acc[4][4];
#pragma unroll
    for (int m = 0; m < 4; ++m)
#pragma unroll
        for (int n = 0; n < 4; ++n) acc[m][n] = (f32x4){0.f,0.f,0.f,0.f};

    auto COMPUTE = [&](int cb) {
        bf16x8 af[4], bfr[4];
#pragma unroll
        for (int m = 0; m < 4; ++m) {
            int r = wm*64 + m*16 + (lane & 15);
            int sw = cf ^ ((r >> 1) & 3);
            af[m] = *(bf16x8*)&As[cb][r*32 + sw*8];
        }
#pragma unroll
        for (int n = 0; n < 4; ++n) {
            int r = wn*64 + n*16 + (lane & 15);
            int sw = cf ^ ((r >> 1) & 3);
            bfr[n] = *(bf16x8*)&Bs[cb][r*32 + sw*8];
        }
        __builtin_amdgcn_s_setprio(1);
#pragma unroll
        for (int m = 0; m < 4; ++m)
#pragma unroll
            for (int n = 0; n < 4; ++n)
                acc[m][n] = __builtin_amdgcn_mfma_f32_16x16x32_bf16(
                    af[m], bfr[n], acc[m][n], 0, 0, 0);
        __builtin_amdgcn_s_setprio(0);
    };

    const int NT = HID_/32;   // 32
    STAGE(0, 0);
    STAGE(1, 32);
    STAGE(2, 64);
    VMCNT8;                               // tile 0 landed
    __builtin_amdgcn_s_barrier();

    for (int t = 0; t < NT-3; ++t) {
        STAGE((t+3) & 3, (t+3)*32);
        COMPUTE(t & 3);
        VMCNT8;                           // tile t+1 landed; t+2,t+3 in flight
        __builtin_amdgcn_s_barrier();
    }
    COMPUTE((NT-3) & 3);                  // t = NT-3
    VMCNT4;                               // tile NT-2 landed
    __builtin_amdgcn_s_barrier();
    COMPUTE((NT-2) & 3);                  // t = NT-2
    VMCNT0;                               // tile NT-1 landed
    __builtin_amdgcn_s_barrier();
    COMPUTE((NT-1) & 3);                  // t = NT-1

    // Epilogue: fused SiLU(gate)*up -> h (bf16)
    const float* w1be = w1b + e*2*FFN_;
#pragma unroll
    for (int n = 0; n < 2; ++n) {
        int col = n0 + wn*32 + n*16 + (lane & 15);
        float bg = w1be[col];
        float bu = w1be[FFN_ + col];
#pragma unroll
        for (int m = 0; m < 4; ++m) {
            int rb2 = t0 + wm*64 + m*16 + (lane >> 4)*4;
#pragma unroll
            for (int i = 0; i < 4; ++i) {
                int t = rb2 + i;
                if (t < ce) {
                    float g = acc[m][n][i]   + bg;
                    float u = acc[m][n+2][i] + bu;
                    float hv = (g / (1.f + __expf(-g))) * u;
                    h[(size_t)(base + t)*FFN_ + col] = __float2bfloat16(hv);
                }
            }
        }
    }
}

// GEMM2: 128 pairs x 128 hid cols, split-K=2 (z = e + 8*ks). Plain stores
// into dpair[ks]; combine sums 4 slices. K-half = 1024, NT = 32.
__global__ __launch_bounds__(256, 2) void gemm2_kernel(
    const __hip_bfloat16* __restrict__ h, const __hip_bfloat16* __restrict__ w2bf,
    const float* __restrict__ w2b, const float* __restrict__ gwt,
    const int* __restrict__ cnt, const int* __restrict__ off,
    float* __restrict__ dpair)
{
    const int e  = blockIdx.z & 7;
    const int ks = blockIdx.z >> 3;
    const int ce = cnt[e];
    const int t0 = blockIdx.y * 128;
    if (t0 >= ce) return;
    const int n0    = blockIdx.x * 128;
    const int base  = off[e];
    const int kbase = ks * (FFN_/2);
    const __hip_bfloat16* w2e = w2bf + (size_t)e * HID_ * FFN_;

    __shared__ __align__(16) __hip_bfloat16 As[4][128*32];
    __shared__ __align__(16) __hip_bfloat16 Bs[4][128*32];

    const int tid  = threadIdx.x;
    const int lane = tid & 63;
    const int wid  = tid >> 6;
    const int wm   = wid >> 1;
    const int wn   = wid & 1;
    const int cf   = lane >> 4;

    const __hip_bfloat16 *asrc[2], *bsrc[2];
#pragma unroll
    for (int q = 0; q < 2; ++q) {
        int slot = q*256 + tid;
        int r = slot >> 2, p = slot & 3;
        int c = p ^ ((r >> 1) & 3);
        int rr = min(t0 + r, ce - 1);
        asrc[q] = h   + (size_t)(base + rr) * FFN_ + kbase + c*8;
        bsrc[q] = w2e + (size_t)(n0 + r)    * FFN_ + kbase + c*8;
    }

    auto STAGE = [&](int b, int k0) {
#pragma unroll
        for (int q = 0; q < 2; ++q)
            __builtin_amdgcn_global_load_lds((GVOID*)(asrc[q] + k0),
                (LVOID*)(&As[b][(q*256 + wid*64)*8]), 16, 0, 0);
#pragma unroll
        for (int q = 0; q < 2; ++q)
            __builtin_amdgcn_global_load_lds((GVOID*)(bsrc[q] + k0),
                (LVOID*)(&Bs[b][(q*256 + wid*64)*8]), 16, 0, 0);
    };

    f32x4 acc[4][4];
#pragma unroll
    for (int m = 0; m < 4; ++m)
#pragma unroll
        for (int n = 0; n < 4; ++n) acc[m][n] = (f32x4){0.f,0.f,0.f,0.f};

    auto COMPUTE = [&](int cb) {
        bf16x8 af[4], bfr[4];
#pragma unroll
        for (int m = 0; m < 4; ++m) {
            int r = wm*64 + m*16 + (lane & 15);
            int sw = cf ^ ((r >> 1) & 3);
            af[m] = *(bf16x8*)&As[cb][r*32 + sw*8];
        }
#pragma unroll
        for (int n = 0; n < 4; ++n) {
            int r = wn*64 + n*16 + (lane & 15);
            int sw = cf ^ ((r >> 1) & 3);
            bfr[n] = *(bf16x8*)&Bs[cb][r*32 + sw*8];
        }
        __builtin_amdgcn_s_setprio(1);
#pragma unroll
        for (int m = 0; m < 4; ++m)
#pragma unroll
            for (int n = 0; n < 4; ++n)
                acc[m][n] = __builtin_amdgcn_mfma_f32_16x16x32_bf16(
                    af[m], bfr[n], acc[m][n], 0, 0, 0);
        __builtin_amdgcn_s_setprio(0);
    };

    const int NT = (FFN_/2)/32;   // 32
    STAGE(0, 0);
    STAGE(1, 32);
    STAGE(2, 64);
    VMCNT8;
    __builtin_amdgcn_s_barrier();

    for (int t = 0; t < NT-3; ++t) {
        STAGE((t+3) & 3, (t+3)*32);
        COMPUTE(t & 3);
        VMCNT8;
        __builtin_amdgcn_s_barrier();
    }
    COMPUTE((NT-3) & 3);
    VMCNT4;
    __builtin_amdgcn_s_barrier();
    COMPUTE((NT-2) & 3);
    VMCNT0;
    __builtin_amdgcn_s_barrier();
    COMPUTE((NT-1) & 3);

    const float* w2be = w2b + e*HID_;
    float* dpk = dpair + (size_t)ks * NP_ * HID_;
#pragma unroll
    for (int n = 0; n < 4; ++n) {
        int col = n0 + wn*64 + n*16 + (lane & 15);
        float bias = (ks == 0) ? w2be[col] : 0.f;
#pragma unroll
        for (int m = 0; m < 4; ++m) {
            int rb2 = t0 + wm*64 + m*16 + (lane >> 4)*4;
#pragma unroll
            for (int i = 0; i < 4; ++i) {
                int t = rb2 + i;
                if (t < ce) {
                    int p   = base + t;
                    float w = gwt[p];
                    dpk[(size_t)p*HID_ + col] = w * (acc[m][n][i] + bias);
                }
            }
        }
    }
}

// out[m][c] = d0[p0][c]+d1[p0][c]+d0[p1][c]+d1[p1][c]   (fixed order)
__global__ __launch_bounds__(256) void combine_kernel(
    const float* __restrict__ dpair, const int* __restrict__ pos,
    float* __restrict__ out)
{
    int idx = blockIdx.x * 256 + threadIdx.x;
    int m   = idx >> 8;
    int c4  = (idx & 255) * 4;
    int p0 = pos[2*m], p1 = pos[2*m+1];
    const float* d0 = dpair;
    const float* d1 = dpair + (size_t)NP_ * HID_;
    float4 a0 = *(const float4*)(d0 + (size_t)p0*HID_ + c4);
    float4 a1 = *(const float4*)(d1 + (size_t)p0*HID_ + c4);
    float4 b0 = *(const float4*)(d0 + (size_t)p1*HID_ + c4);
    float4 b1 = *(const float4*)(d1 + (size_t)p1*HID_ + c4);
    float4 o = make_float4((a0.x+a1.x)+(b0.x+b1.x), (a0.y+a1.y)+(b0.y+b1.y),
                           (a0.z+a1.z)+(b0.z+b1.z), (a0.w+a1.w)+(b0.w+b1.w));
    *(float4*)(out + (size_t)m*HID_ + c4) = o;
}

// ===========================================================================
// FALLBACK (proven round-2 structure) — only if ws_size too small for tier2.
// ===========================================================================
__global__ __launch_bounds__(256) void gemm1_rs_kernel(
    const __hip_bfloat16* __restrict__ xb, const float* __restrict__ w1,
    const float* __restrict__ w1b, const int* __restrict__ gtok,
    const int* __restrict__ cnt, const int* __restrict__ off,
    __hip_bfloat16* __restrict__ h)
{
    const int e  = blockIdx.z;
    const int ce = cnt[e];
    const int t0 = blockIdx.y * 128;
    if (t0 >= ce) return;
    const int n0   = blockIdx.x * 64;
    const int base = off[e];
    const float* w1e = w1 + (size_t)e * (2*FFN_) * HID_;

    __shared__ __align__(16) __hip_bfloat16 As[128*64];
    __shared__ __align__(16) __hip_bfloat16 Bs[128*64];

    const int tid  = threadIdx.x;
    const int lane = tid & 63;
    const int wid  = tid >> 6;
    const int wm   = wid >> 1;
    const int wn   = wid & 1;

    const __hip_bfloat16* asrc[4];
#pragma unroll
    for (int q = 0; q < 4; ++q) {
        int slot = q*256 + tid;
        int r = slot >> 3, p = slot & 7;
        int rr  = min(t0 + r, ce - 1);
        int tok = gtok[base + rr];
        int c = p ^ (r & 7);
        asrc[q] = xb + (size_t)tok * HID_ + c*8;
    }

    const int brow = tid >> 1;
    const int hk   = tid & 1;
    const int q2 = brow >> 5, s = brow & 31;
    const int grow = (q2 & 1) ? (FFN_ + n0 + (q2>>1)*32 + s)
                              : (       n0 + (q2>>1)*32 + s);
    const float* bsrc = w1e + (size_t)grow * HID_ + hk*32;

    f32x4 acc[4][4];
#pragma unroll
    for (int m = 0; m < 4; ++m)
#pragma unroll
        for (int n = 0; n < 4; ++n) acc[m][n] = (f32x4){0.f,0.f,0.f,0.f};

    float4 breg[8];
#pragma unroll
    for (int j = 0; j < 8; ++j) breg[j] = *(const float4*)(bsrc + j*4);

    for (int k0 = 0; k0 < HID_; k0 += 64) {
#pragma unroll
        for (int q = 0; q < 4; ++q) {
            __builtin_amdgcn_global_load_lds(
                (GVOID*)(asrc[q] + k0),
                (LVOID*)(&As[(q*256 + wid*64)*8]), 16, 0, 0);
        }
#pragma unroll
        for (int cc = 0; cc < 4; ++cc) {
            union { bf16x8 v; short s8[8]; } u;
            const float* f0 = (const float*)&breg[2*cc];
#pragma unroll
            for (int j = 0; j < 8; ++j) u.s8[j] = f2bf(f0[j]);
            int c = hk*4 + cc, p = c ^ (brow & 7);
            *(bf16x8*)&Bs[brow*64 + p*8] = u.v;
        }
        __syncthreads();

        if (k0 + 64 < HID_) {
#pragma unroll
            for (int j = 0; j < 8; ++j) breg[j] = *(const float4*)(bsrc + (k0+64) + j*4);
        }

        bf16x8 af[4][2], bfr[4][2];
#pragma unroll
        for (int m = 0; m < 4; ++m)
#pragma unroll
            for (int kk = 0; kk < 2; ++kk) {
                int r = wm*64 + m*16 + (lane & 15);
                int c = kk*4 + (lane >> 4), p = c ^ (r & 7);
                af[m][kk] = *(bf16x8*)&As[r*64 + p*8];
            }
#pragma unroll
        for (int n = 0; n < 4; ++n)
#pragma unroll
            for (int kk = 0; kk < 2; ++kk) {
                int r = wn*64 + n*16 + (lane & 15);
                int c = kk*4 + (lane >> 4), p = c ^ (r & 7);
                bfr[n][kk] = *(bf16x8*)&Bs[r*64 + p*8];
            }
#pragma unroll
        for (int kk = 0; kk < 2; ++kk)
#pragma unroll
            for (int m = 0; m < 4; ++m)
#pragma unroll
                for (int n = 0; n < 4; ++n)
                    acc[m][n] = __builtin_amdgcn_mfma_f32_16x16x32_bf16(
                        af[m][kk], bfr[n][kk], acc[m][n], 0, 0, 0);
        __syncthreads();
    }

    const float* w1be = w1b + e*2*FFN_;
#pragma unroll
    for (int n = 0; n < 2; ++n) {
        int col = n0 + wn*32 + n*16 + (lane & 15);
        float bg = w1be[col];
        float bu = w1be[FFN_ + col];
#pragma unroll
        for (int m = 0; m < 4; ++m) {
            int rb2 = t0 + wm*64 + m*16 + (lane >> 4)*4;
#pragma unroll
            for (int i = 0; i < 4; ++i) {
                int t = rb2 + i;
                if (t < ce) {
                    float g = acc[m][n][i]   + bg;
                    float u = acc[m][n+2][i] + bu;
                    float hv = (g / (1.f + __expf(-g))) * u;
                    h[(size_t)(base + t)*FFN_ + col] = __float2bfloat16(hv);
                }
            }
        }
    }
}

__global__ __launch_bounds__(256) void gemm2_rs_kernel(
    const __hip_bfloat16* __restrict__ h, const float* __restrict__ w2,
    const float* __restrict__ w2b, const int* __restrict__ gtok,
    const float* __restrict__ gwt, const int* __restrict__ cnt,
    const int* __restrict__ off, float* __restrict__ out)
{
    const int e  = blockIdx.z;
    const int ce = cnt[e];
    const int t0 = blockIdx.y * 128;
    if (t0 >= ce) return;
    const int n0   = blockIdx.x * 128;
    const int base = off[e];
    const float* w2e = w2 + (size_t)e * HID_ * FFN_;

    __shared__ __align__(16) __hip_bfloat16 As[128*64];
    __shared__ __align__(16) __hip_bfloat16 Bs[128*64];

    const int tid  = threadIdx.x;
    const int lane = tid & 63;
    const int wid  = tid >> 6;
    const int wm   = wid >> 1;
    const int wn   = wid & 1;

    const __hip_bfloat16* asrc[4];
#pragma unroll
    for (int q = 0; q < 4; ++q) {
        int slot = q*256 + tid;
        int r = slot >> 3, p = slot & 7;
        int rr = min(t0 + r, ce - 1);
        int c = p ^ (r & 7);
        asrc[q] = h + (size_t)(base + rr) * FFN_ + c*8;
    }

    const int brow = tid >> 1;
    const int hk   = tid & 1;
    const float* bsrc = w2e + (size_t)(n0 + brow) * FFN_ + hk*32;

    f32x4 acc[4][4];
#pragma unroll
    for (int m = 0; m < 4; ++m)
#pragma unroll
        for (int n = 0; n < 4; ++n) acc[m][n] = (f32x4){0.f,0.f,0.f,0.f};

    float4 breg[8];
#pragma unroll
    for (int j = 0; j < 8; ++j) breg[j] = *(const float4*)(bsrc + j*4);

    for (int k0 = 0; k0 < FFN_; k0 += 64) {
#pragma unroll
        for (int q = 0; q < 4; ++q) {
            __builtin_amdgcn_global_load_lds(
                (GVOID*)(asrc[q] + k0),
                (LVOID*)(&As[(q*256 + wid*64)*8]), 16, 0, 0);
        }
#pragma unroll
        for (int cc = 0; cc < 4; ++cc) {
            union { bf16x8 v; short s8[8]; } u;
            const float* f0 = (const float*)&breg[2*cc];
#pragma unroll
            for (int j = 0; j < 8; ++j) u.s8[j] = f2bf(f0[j]);
            int c = hk*4 + cc, p = c ^ (brow & 7);
            *(bf16x8*)&Bs[brow*64 + p*8] = u.v;
        }
        __syncthreads();

        if (k0 + 64 < FFN_) {
#pragma unroll
            for (int j = 0; j < 8; ++j) breg[j] = *(const float4*)(bsrc + (k0+64) + j*4);
        }

        bf16x8 af[4][2], bfr[4][2];
#pragma unroll
        for (int m = 0; m < 4; ++m)
#pragma unroll
            for (int kk = 0; kk < 2; ++kk) {
                int r = wm*64 + m*16 + (lane & 15);
                int c = kk*4 + (lane >> 4), p = c ^ (r & 7);
                af[m][kk] = *(bf16x8*)&As[r*64 + p*8];
            }
#pragma unroll
        for (int n = 0; n < 4; ++n)
#pragma unroll
            for (int kk = 0; kk < 2; ++kk) {
                int r = wn*64 + n*16 + (lane & 15);
                int c = kk*4 + (lane >> 4), p = c ^ (r & 7);
                bfr[n][kk] = *(bf16x8*)&Bs[r*64 + p*8];
            }
#pragma unroll
        for (int kk = 0; kk < 2; ++kk)
#pragma unroll
            for (int m = 0; m < 4; ++m)
#pragma unroll
                for (int n = 0; n < 4; ++n)
                    acc[m][n] = __builtin_amdgcn_mfma_f32_16x16x32_bf16(
                        af[m][kk], bfr[n][kk], acc[m][n], 0, 0, 0);
        __syncthreads();
    }

    const float* w2be = w2b + e*HID_;
#pragma unroll
    for (int n = 0; n < 4; ++n) {
        int col = n0 + wn*64 + n*16 + (lane & 15);
        float bias = w2be[col];
#pragma unroll
        for (int m = 0; m < 4; ++m) {
            int rb2 = t0 + wm*64 + m*16 + (lane >> 4)*4;
#pragma unroll
            for (int i = 0; i < 4; ++i) {
                int t = rb2 + i;
                if (t < ce) {
                    int p   = base + t;
                    float w = gwt[p];
                    atomicAdd(&out[(size_t)gtok[p]*HID_ + col], w * (acc[m][n][i] + bias));
                }
            }
        }
    }
}

// ---------------------------------------------------------------------------
extern "C" void kernel_launch(void* const* d_in, const int* in_sizes, int n_in,
                              void* d_out, int out_size, void* d_ws, size_t ws_size,
                              hipStream_t stream)
{
    const float* x   = (const float*)d_in[0];
    const float* rw  = (const float*)d_in[1];
    const float* rb  = (const float*)d_in[2];
    const float* w1  = (const float*)d_in[3];
    const float* w1b = (const float*)d_in[4];
    const float* w2  = (const float*)d_in[5];
    const float* w2b = (const float*)d_in[6];

    float* out      = (float*)d_out;
    float* topk_out = out + (size_t)M_ * HID_;

    char*  ws   = (char*)d_ws;
    int*   ids  = (int*)  (ws);
    float* wts  = (float*)(ws + 16384);
    int*   gtok = (int*)  (ws + 32768);
    float* gwt  = (float*)(ws + 49152);
    int*   cnt  = (int*)  (ws + 65536);
    int*   off  = (int*)  (ws + 65536 + 128);
    int*   fill = (int*)  (ws + 65536 + 256);
    int*   pos  = (int*)  (ws + 98304);

    const size_t MB = 1024*1024;
    __hip_bfloat16* xb    = (__hip_bfloat16*)(ws + 131072);            // 4 MB
    __hip_bfloat16* h     = (__hip_bfloat16*)(ws + 131072 + 4*MB);     // 16 MB
    float*          dpair = (float*)         (ws + 131072 + 20*MB);    // 32 MB (2 slices)
    __hip_bfloat16* w1bf  = (__hip_bfloat16*)(ws + 131072 + 52*MB);    // 64 MB
    __hip_bfloat16* w2bf  = (__hip_bfloat16*)(ws + 131072 + 116*MB);   // 32 MB
    const bool tier2 = (ws_size >= 131072 + 148*MB);

    hipMemsetAsync(cnt, 0, E_ * sizeof(int), stream);

    router_kernel<<<M_, 64, 0, stream>>>(x, rw, rb, ids, wts, cnt, topk_out, xb);
    offsets_kernel<<<1, 64, 0, stream>>>(cnt, off, fill);
    scatter_kernel<<<M_/256, 256, 0, stream>>>(ids, wts, fill, gtok, gwt, pos);

    if (tier2) {
        cvt_w_kernel<<<4096, 256, 0, stream>>>(w1, w2, w1bf, w2bf);

        dim3 g1(FFN_/64, M_/128, E_);        // (32, 16, 8)
        gemm1_kernel<<<g1, 256, 0, stream>>>(xb, w1bf, w1b, gtok, cnt, off, h);

        dim3 g2(HID_/128, M_/128, 2*E_);     // (8, 16, 16) split-K=2
        gemm2_kernel<<<g2, 256, 0, stream>>>(h, w2bf, w2b, gwt, cnt, off, dpair);

        combine_kernel<<<(M_*HID_)/(256*4), 256, 0, stream>>>(dpair, pos, out);
    } else {
        hipMemsetAsync(out, 0, (size_t)M_ * HID_ * sizeof(float), stream);

        dim3 g1(FFN_/64, M_/128, E_);
        gemm1_rs_kernel<<<g1, 256, 0, stream>>>(xb, w1, w1b, gtok, cnt, off, h);

        dim3 g2(HID_/128, M_/128, E_);
        gemm2_rs_kernel<<<g2, 256, 0, stream>>>(h, w2, w2b, gtok, gwt, cnt, off, out);
    }
}

// Round 10
// 252.160 us; speedup vs baseline: 1.2385x; 1.1381x over previous
//
#include <hip/hip_runtime.h>
#include <hip/hip_bf16.h>
#include <math.h>

#define E_    8
#define HID_  1024
#define FFN_  2048
#define M_    2048     // B*S
#define NP_   (M_*2)   // total (token, expert) pairs

typedef __attribute__((ext_vector_type(8))) short bf16x8;
typedef __attribute__((ext_vector_type(4))) float f32x4;

typedef const __attribute__((address_space(1))) void GVOID;
typedef __attribute__((address_space(3))) void LVOID;

#define VMCNT4 asm volatile("s_waitcnt vmcnt(4)" ::: "memory")
#define VMCNT0 asm volatile("s_waitcnt vmcnt(0)" ::: "memory")

__device__ __forceinline__ short f2bf(float f) {
    union { __hip_bfloat16 b; short s; } u;
    u.b = __float2bfloat16(f);
    return u.s;
}

// ---------------------------------------------------------------------------
// w1 + w2 fp32 -> bf16 in one kernel (grid-stride over both)
// ---------------------------------------------------------------------------
__global__ __launch_bounds__(256) void cvt_w_kernel(
    const float* __restrict__ w1, const float* __restrict__ w2,
    __hip_bfloat16* __restrict__ w1bf, __hip_bfloat16* __restrict__ w2bf)
{
    const int n1 = (E_*2*FFN_*HID_)/4;
    const int n2 = (E_*HID_*FFN_)/4;
    int stride = gridDim.x * 256;
    for (int i = blockIdx.x * 256 + threadIdx.x; i < n1 + n2; i += stride) {
        float4 v;
        if (i < n1) v = ((const float4*)w1)[i];
        else        v = ((const float4*)w2)[i - n1];
        short4 o;
        o.x = f2bf(v.x); o.y = f2bf(v.y); o.z = f2bf(v.z); o.w = f2bf(v.w);
        if (i < n1) ((short4*)w1bf)[i] = o;
        else        ((short4*)w2bf)[i - n1] = o;
    }
}

// ---------------------------------------------------------------------------
// Router (+ fused x->bf16 conversion): one wave per token.  [proven]
// ---------------------------------------------------------------------------
__global__ __launch_bounds__(64) void router_kernel(
    const float* __restrict__ x, const float* __restrict__ rw,
    const float* __restrict__ rb, int* __restrict__ ids,
    float* __restrict__ wts, int* __restrict__ cnt,
    float* __restrict__ topk_out, __hip_bfloat16* __restrict__ xb)
{
    const int m    = blockIdx.x;
    const int lane = threadIdx.x;
    const float4* xm4 = (const float4*)(x + (size_t)m * HID_);

    float4 xv[4];
#pragma unroll
    for (int j = 0; j < 4; ++j) xv[j] = xm4[j*64 + lane];

    short4* xbr = (short4*)(xb + (size_t)m * HID_);
#pragma unroll
    for (int j = 0; j < 4; ++j) {
        short4 o;
        o.x = f2bf(xv[j].x); o.y = f2bf(xv[j].y);
        o.z = f2bf(xv[j].z); o.w = f2bf(xv[j].w);
        xbr[j*64 + lane] = o;
    }

    float lg[E_];
#pragma unroll
    for (int e = 0; e < E_; ++e) {
        const float4* we4 = (const float4*)(rw + e * HID_);
        float s = 0.f;
#pragma unroll
        for (int j = 0; j < 4; ++j) {
            float4 w = we4[j*64 + lane];
            s = fmaf(xv[j].x, w.x, s);
            s = fmaf(xv[j].y, w.y, s);
            s = fmaf(xv[j].z, w.z, s);
            s = fmaf(xv[j].w, w.w, s);
        }
        lg[e] = s;
    }
#pragma unroll
    for (int off = 32; off; off >>= 1)
#pragma unroll
        for (int e = 0; e < E_; ++e) lg[e] += __shfl_xor(lg[e], off);

    if (lane == 0) {
        float l2[E_], p[E_];
        float mx = -1e30f;
#pragma unroll
        for (int e = 0; e < E_; ++e) { l2[e] = lg[e] + rb[e]; mx = fmaxf(mx, l2[e]); }
        float sum = 0.f;
#pragma unroll
        for (int e = 0; e < E_; ++e) { p[e] = expf(l2[e] - mx); sum += p[e]; }
        float inv = 1.f / sum;
#pragma unroll
        for (int e = 0; e < E_; ++e) p[e] *= inv;

        int   i1 = -1, i2 = -1;
        float v1 = -1e30f, v2 = -1e30f;
#pragma unroll
        for (int e = 0; e < E_; ++e) {
            float pe = p[e];
            if (pe > v1)      { v2 = v1; i2 = i1; v1 = pe; i1 = e; }
            else if (pe > v2) { v2 = pe; i2 = e; }
        }
        ids[2*m]   = i1;  ids[2*m+1]   = i2;
        wts[2*m]   = v1;  wts[2*m+1]   = v2;
        topk_out[2*m]   = v1;
        topk_out[2*m+1] = v2;
        atomicAdd(&cnt[i1], 1);
        atomicAdd(&cnt[i2], 1);
    }
}

__global__ void offsets_kernel(const int* __restrict__ cnt,
                               int* __restrict__ off, int* __restrict__ fill)
{
    if (threadIdx.x == 0 && blockIdx.x == 0) {
        int acc = 0;
        for (int e = 0; e < E_; ++e) { off[e] = acc; fill[e] = acc; acc += cnt[e]; }
    }
}

__global__ __launch_bounds__(256) void scatter_kernel(
    const int* __restrict__ ids, const float* __restrict__ wts,
    int* __restrict__ fill, int* __restrict__ gtok, float* __restrict__ gwt,
    int* __restrict__ pos)
{
    int m = blockIdx.x * 256 + threadIdx.x;
    if (m >= M_) return;
#pragma unroll
    for (int s = 0; s < 2; ++s) {
        int e = ids[2*m + s];
        int p = atomicAdd(&fill[e], 1);
        gtok[p] = m;
        gwt[p]  = wts[2*m + s];
        pos[2*m + s] = p;
    }
}

// ===========================================================================
// TIER-2 GEMMs [measured optimum, 252us config]: 128x128 block, 4 waves of
// 64x64, BK=32, TRIPLE-buffered LDS (48KB), depth-2 prefetch, counted
// vmcnt(4) at barriers (only newest tile's 4 loads stay in flight).
// LDS swizzle: 16B chunk p of row r holds global chunk p ^ ((r>>1)&3).
// ===========================================================================

// GEMM1: 128 gathered tokens x 64 h-cols. K = HID = 1024, NT = 32 steps.
__global__ __launch_bounds__(256, 3) void gemm1_kernel(
    const __hip_bfloat16* __restrict__ xb, const __hip_bfloat16* __restrict__ w1bf,
    const float* __restrict__ w1b, const int* __restrict__ gtok,
    const int* __restrict__ cnt, const int* __restrict__ off,
    __hip_bfloat16* __restrict__ h)
{
    const int e  = blockIdx.z;
    const int ce = cnt[e];
    const int t0 = blockIdx.y * 128;
    if (t0 >= ce) return;
    const int n0   = blockIdx.x * 64;
    const int base = off[e];
    const __hip_bfloat16* w1e = w1bf + (size_t)e * (2*FFN_) * HID_;

    __shared__ __align__(16) __hip_bfloat16 As[3][128*32];
    __shared__ __align__(16) __hip_bfloat16 Bs[3][128*32];

    const int tid  = threadIdx.x;
    const int lane = tid & 63;
    const int wid  = tid >> 6;
    const int wm   = wid >> 1;
    const int wn   = wid & 1;

    const __hip_bfloat16 *asrc[2], *bsrc[2];
#pragma unroll
    for (int q = 0; q < 2; ++q) {
        int slot = q*256 + tid;
        int r = slot >> 2, p = slot & 3;
        int c = p ^ ((r >> 1) & 3);
        int rr  = min(t0 + r, ce - 1);
        asrc[q] = xb + (size_t)gtok[base + rr] * HID_ + c*8;
        int q2 = r >> 5, s = r & 31;
        int grow = (q2 & 1) ? (FFN_ + n0 + (q2>>1)*32 + s)
                            : (       n0 + (q2>>1)*32 + s);
        bsrc[q] = w1e + (size_t)grow * HID_ + c*8;
    }

    auto STAGE = [&](int b, int k0) {
#pragma unroll
        for (int q = 0; q < 2; ++q)
            __builtin_amdgcn_global_load_lds((GVOID*)(asrc[q] + k0),
                (LVOID*)(&As[b][(q*256 + wid*64)*8]), 16, 0, 0);
#pragma unroll
        for (int q = 0; q < 2; ++q)
            __builtin_amdgcn_global_load_lds((GVOID*)(bsrc[q] + k0),
                (LVOID*)(&Bs[b][(q*256 + wid*64)*8]), 16, 0, 0);
    };

    f32x4 acc[4][4];
#pragma unroll
    for (int m = 0; m < 4; ++m)
#pragma unroll
        for (int n = 0; n < 4; ++n) acc[m][n] = (f32x4){0.f,0.f,0.f,0.f};

    const int cf = lane >> 4;
    auto COMPUTE = [&](int cb) {
        bf16x8 af[4], bfr[4];
#pragma unroll
        for (int m = 0; m < 4; ++m) {
            int r = wm*64 + m*16 + (lane & 15);
            int sw = cf ^ ((r >> 1) & 3);
            af[m] = *(bf16x8*)&As[cb][r*32 + sw*8];
        }
#pragma unroll
        for (int n = 0; n < 4; ++n) {
            int r = wn*64 + n*16 + (lane & 15);
            int sw = cf ^ ((r >> 1) & 3);
            bfr[n] = *(bf16x8*)&Bs[cb][r*32 + sw*8];
        }
        __builtin_amdgcn_s_setprio(1);
#pragma unroll
        for (int m = 0; m < 4; ++m)
#pragma unroll
            for (int n = 0; n < 4; ++n)
                acc[m][n] = __builtin_amdgcn_mfma_f32_16x16x32_bf16(
                    af[m], bfr[n], acc[m][n], 0, 0, 0);
        __builtin_amdgcn_s_setprio(0);
    };

    const int NT = HID_/32;   // 32
    STAGE(0, 0);
    STAGE(1, 32);
    VMCNT4;
    __builtin_amdgcn_s_barrier();

    int cb = 0;
    for (int t = 0; t < NT-2; ++t) {
        int sb = cb + 2; if (sb >= 3) sb -= 3;
        STAGE(sb, (t+2)*32);
        COMPUTE(cb);
        VMCNT4;                         // tile t+1 landed; t+2 stays in flight
        __builtin_amdgcn_s_barrier();
        if (++cb == 3) cb = 0;
    }
    COMPUTE(cb);                        // t = NT-2
    VMCNT0;
    __builtin_amdgcn_s_barrier();
    if (++cb == 3) cb = 0;
    COMPUTE(cb);                        // t = NT-1

    // Epilogue: fused SiLU(gate)*up -> h (bf16)
    const float* w1be = w1b + e*2*FFN_;
#pragma unroll
    for (int n = 0; n < 2; ++n) {
        int col = n0 + wn*32 + n*16 + (lane & 15);
        float bg = w1be[col];
        float bu = w1be[FFN_ + col];
#pragma unroll
        for (int m = 0; m < 4; ++m) {
            int rb2 = t0 + wm*64 + m*16 + (lane >> 4)*4;
#pragma unroll
            for (int i = 0; i < 4; ++i) {
                int t = rb2 + i;
                if (t < ce) {
                    float g = acc[m][n][i]   + bg;
                    float u = acc[m][n+2][i] + bu;
                    float hv = (g / (1.f + __expf(-g))) * u;
                    h[(size_t)(base + t)*FFN_ + col] = __float2bfloat16(hv);
                }
            }
        }
    }
}

// GEMM2: 128 pairs x 128 hid cols, split-K=2 (z = e + 8*ks). Plain stores
// into dpair[ks] (no init, no atomics); combine sums 4 slices.
__global__ __launch_bounds__(256, 3) void gemm2_kernel(
    const __hip_bfloat16* __restrict__ h, const __hip_bfloat16* __restrict__ w2bf,
    const float* __restrict__ w2b, const float* __restrict__ gwt,
    const int* __restrict__ cnt, const int* __restrict__ off,
    float* __restrict__ dpair)
{
    const int e  = blockIdx.z & 7;
    const int ks = blockIdx.z >> 3;
    const int ce = cnt[e];
    const int t0 = blockIdx.y * 128;
    if (t0 >= ce) return;
    const int n0    = blockIdx.x * 128;
    const int base  = off[e];
    const int kbase = ks * (FFN_/2);
    const __hip_bfloat16* w2e = w2bf + (size_t)e * HID_ * FFN_;

    __shared__ __align__(16) __hip_bfloat16 As[3][128*32];
    __shared__ __align__(16) __hip_bfloat16 Bs[3][128*32];

    const int tid  = threadIdx.x;
    const int lane = tid & 63;
    const int wid  = tid >> 6;
    const int wm   = wid >> 1;
    const int wn   = wid & 1;

    const __hip_bfloat16 *asrc[2], *bsrc[2];
#pragma unroll
    for (int q = 0; q < 2; ++q) {
        int slot = q*256 + tid;
        int r = slot >> 2, p = slot & 3;
        int c = p ^ ((r >> 1) & 3);
        int rr = min(t0 + r, ce - 1);
        asrc[q] = h   + (size_t)(base + rr) * FFN_ + kbase + c*8;
        bsrc[q] = w2e + (size_t)(n0 + r)    * FFN_ + kbase + c*8;
    }

    auto STAGE = [&](int b, int k0) {
#pragma unroll
        for (int q = 0; q < 2; ++q)
            __builtin_amdgcn_global_load_lds((GVOID*)(asrc[q] + k0),
                (LVOID*)(&As[b][(q*256 + wid*64)*8]), 16, 0, 0);
#pragma unroll
        for (int q = 0; q < 2; ++q)
            __builtin_amdgcn_global_load_lds((GVOID*)(bsrc[q] + k0),
                (LVOID*)(&Bs[b][(q*256 + wid*64)*8]), 16, 0, 0);
    };

    f32x4 acc[4][4];
#pragma unroll
    for (int m = 0; m < 4; ++m)
#pragma unroll
        for (int n = 0; n < 4; ++n) acc[m][n] = (f32x4){0.f,0.f,0.f,0.f};

    const int cf = lane >> 4;
    auto COMPUTE = [&](int cb) {
        bf16x8 af[4], bfr[4];
#pragma unroll
        for (int m = 0; m < 4; ++m) {
            int r = wm*64 + m*16 + (lane & 15);
            int sw = cf ^ ((r >> 1) & 3);
            af[m] = *(bf16x8*)&As[cb][r*32 + sw*8];
        }
#pragma unroll
        for (int n = 0; n < 4; ++n) {
            int r = wn*64 + n*16 + (lane & 15);
            int sw = cf ^ ((r >> 1) & 3);
            bfr[n] = *(bf16x8*)&Bs[cb][r*32 + sw*8];
        }
        __builtin_amdgcn_s_setprio(1);
#pragma unroll
        for (int m = 0; m < 4; ++m)
#pragma unroll
            for (int n = 0; n < 4; ++n)
                acc[m][n] = __builtin_amdgcn_mfma_f32_16x16x32_bf16(
                    af[m], bfr[n], acc[m][n], 0, 0, 0);
        __builtin_amdgcn_s_setprio(0);
    };

    const int NT = (FFN_/2)/32;   // 32
    STAGE(0, 0);
    STAGE(1, 32);
    VMCNT4;
    __builtin_amdgcn_s_barrier();

    int cb = 0;
    for (int t = 0; t < NT-2; ++t) {
        int sb = cb + 2; if (sb >= 3) sb -= 3;
        STAGE(sb, (t+2)*32);
        COMPUTE(cb);
        VMCNT4;
        __builtin_amdgcn_s_barrier();
        if (++cb == 3) cb = 0;
    }
    COMPUTE(cb);
    VMCNT0;
    __builtin_amdgcn_s_barrier();
    if (++cb == 3) cb = 0;
    COMPUTE(cb);

    const float* w2be = w2b + e*HID_;
    float* dpk = dpair + (size_t)ks * NP_ * HID_;
#pragma unroll
    for (int n = 0; n < 4; ++n) {
        int col = n0 + wn*64 + n*16 + (lane & 15);
        float bias = (ks == 0) ? w2be[col] : 0.f;
#pragma unroll
        for (int m = 0; m < 4; ++m) {
            int rb2 = t0 + wm*64 + m*16 + (lane >> 4)*4;
#pragma unroll
            for (int i = 0; i < 4; ++i) {
                int t = rb2 + i;
                if (t < ce) {
                    int p   = base + t;
                    float w = gwt[p];
                    dpk[(size_t)p*HID_ + col] = w * (acc[m][n][i] + bias);
                }
            }
        }
    }
}

// out[m][c] = d0[p0][c]+d1[p0][c]+d0[p1][c]+d1[p1][c]   (fixed order)
__global__ __launch_bounds__(256) void combine_kernel(
    const float* __restrict__ dpair, const int* __restrict__ pos,
    float* __restrict__ out)
{
    int idx = blockIdx.x * 256 + threadIdx.x;
    int m   = idx >> 8;
    int c4  = (idx & 255) * 4;
    int p0 = pos[2*m], p1 = pos[2*m+1];
    const float* d0 = dpair;
    const float* d1 = dpair + (size_t)NP_ * HID_;
    float4 a0 = *(const float4*)(d0 + (size_t)p0*HID_ + c4);
    float4 a1 = *(const float4*)(d1 + (size_t)p0*HID_ + c4);
    float4 b0 = *(const float4*)(d0 + (size_t)p1*HID_ + c4);
    float4 b1 = *(const float4*)(d1 + (size_t)p1*HID_ + c4);
    float4 o = make_float4((a0.x+a1.x)+(b0.x+b1.x), (a0.y+a1.y)+(b0.y+b1.y),
                           (a0.z+a1.z)+(b0.z+b1.z), (a0.w+a1.w)+(b0.w+b1.w));
    *(float4*)(out + (size_t)m*HID_ + c4) = o;
}

// ===========================================================================
// FALLBACK (proven round-2 structure) — only if ws_size too small for tier2.
// ===========================================================================
__global__ __launch_bounds__(256) void gemm1_rs_kernel(
    const __hip_bfloat16* __restrict__ xb, const float* __restrict__ w1,
    const float* __restrict__ w1b, const int* __restrict__ gtok,
    const int* __restrict__ cnt, const int* __restrict__ off,
    __hip_bfloat16* __restrict__ h)
{
    const int e  = blockIdx.z;
    const int ce = cnt[e];
    const int t0 = blockIdx.y * 128;
    if (t0 >= ce) return;
    const int n0   = blockIdx.x * 64;
    const int base = off[e];
    const float* w1e = w1 + (size_t)e * (2*FFN_) * HID_;

    __shared__ __align__(16) __hip_bfloat16 As[128*64];
    __shared__ __align__(16) __hip_bfloat16 Bs[128*64];

    const int tid  = threadIdx.x;
    const int lane = tid & 63;
    const int wid  = tid >> 6;
    const int wm   = wid >> 1;
    const int wn   = wid & 1;

    const __hip_bfloat16* asrc[4];
#pragma unroll
    for (int q = 0; q < 4; ++q) {
        int slot = q*256 + tid;
        int r = slot >> 3, p = slot & 7;
        int rr  = min(t0 + r, ce - 1);
        int tok = gtok[base + rr];
        int c = p ^ (r & 7);
        asrc[q] = xb + (size_t)tok * HID_ + c*8;
    }

    const int brow = tid >> 1;
    const int hk   = tid & 1;
    const int q2 = brow >> 5, s = brow & 31;
    const int grow = (q2 & 1) ? (FFN_ + n0 + (q2>>1)*32 + s)
                              : (       n0 + (q2>>1)*32 + s);
    const float* bsrc = w1e + (size_t)grow * HID_ + hk*32;

    f32x4 acc[4][4];
#pragma unroll
    for (int m = 0; m < 4; ++m)
#pragma unroll
        for (int n = 0; n < 4; ++n) acc[m][n] = (f32x4){0.f,0.f,0.f,0.f};

    float4 breg[8];
#pragma unroll
    for (int j = 0; j < 8; ++j) breg[j] = *(const float4*)(bsrc + j*4);

    for (int k0 = 0; k0 < HID_; k0 += 64) {
#pragma unroll
        for (int q = 0; q < 4; ++q) {
            __builtin_amdgcn_global_load_lds(
                (GVOID*)(asrc[q] + k0),
                (LVOID*)(&As[(q*256 + wid*64)*8]), 16, 0, 0);
        }
#pragma unroll
        for (int cc = 0; cc < 4; ++cc) {
            union { bf16x8 v; short s8[8]; } u;
            const float* f0 = (const float*)&breg[2*cc];
#pragma unroll
            for (int j = 0; j < 8; ++j) u.s8[j] = f2bf(f0[j]);
            int c = hk*4 + cc, p = c ^ (brow & 7);
            *(bf16x8*)&Bs[brow*64 + p*8] = u.v;
        }
        __syncthreads();

        if (k0 + 64 < HID_) {
#pragma unroll
            for (int j = 0; j < 8; ++j) breg[j] = *(const float4*)(bsrc + (k0+64) + j*4);
        }

        bf16x8 af[4][2], bfr[4][2];
#pragma unroll
        for (int m = 0; m < 4; ++m)
#pragma unroll
            for (int kk = 0; kk < 2; ++kk) {
                int r = wm*64 + m*16 + (lane & 15);
                int c = kk*4 + (lane >> 4), p = c ^ (r & 7);
                af[m][kk] = *(bf16x8*)&As[r*64 + p*8];
            }
#pragma unroll
        for (int n = 0; n < 4; ++n)
#pragma unroll
            for (int kk = 0; kk < 2; ++kk) {
                int r = wn*64 + n*16 + (lane & 15);
                int c = kk*4 + (lane >> 4), p = c ^ (r & 7);
                bfr[n][kk] = *(bf16x8*)&Bs[r*64 + p*8];
            }
#pragma unroll
        for (int kk = 0; kk < 2; ++kk)
#pragma unroll
            for (int m = 0; m < 4; ++m)
#pragma unroll
                for (int n = 0; n < 4; ++n)
                    acc[m][n] = __builtin_amdgcn_mfma_f32_16x16x32_bf16(
                        af[m][kk], bfr[n][kk], acc[m][n], 0, 0, 0);
        __syncthreads();
    }

    const float* w1be = w1b + e*2*FFN_;
#pragma unroll
    for (int n = 0; n < 2; ++n) {
        int col = n0 + wn*32 + n*16 + (lane & 15);
        float bg = w1be[col];
        float bu = w1be[FFN_ + col];
#pragma unroll
        for (int m = 0; m < 4; ++m) {
            int rb2 = t0 + wm*64 + m*16 + (lane >> 4)*4;
#pragma unroll
            for (int i = 0; i < 4; ++i) {
                int t = rb2 + i;
                if (t < ce) {
                    float g = acc[m][n][i]   + bg;
                    float u = acc[m][n+2][i] + bu;
                    float hv = (g / (1.f + __expf(-g))) * u;
                    h[(size_t)(base + t)*FFN_ + col] = __float2bfloat16(hv);
                }
            }
        }
    }
}

__global__ __launch_bounds__(256) void gemm2_rs_kernel(
    const __hip_bfloat16* __restrict__ h, const float* __restrict__ w2,
    const float* __restrict__ w2b, const int* __restrict__ gtok,
    const float* __restrict__ gwt, const int* __restrict__ cnt,
    const int* __restrict__ off, float* __restrict__ out)
{
    const int e  = blockIdx.z;
    const int ce = cnt[e];
    const int t0 = blockIdx.y * 128;
    if (t0 >= ce) return;
    const int n0   = blockIdx.x * 128;
    const int base = off[e];
    const float* w2e = w2 + (size_t)e * HID_ * FFN_;

    __shared__ __align__(16) __hip_bfloat16 As[128*64];
    __shared__ __align__(16) __hip_bfloat16 Bs[128*64];

    const int tid  = threadIdx.x;
    const int lane = tid & 63;
    const int wid  = tid >> 6;
    const int wm   = wid >> 1;
    const int wn   = wid & 1;

    const __hip_bfloat16* asrc[4];
#pragma unroll
    for (int q = 0; q < 4; ++q) {
        int slot = q*256 + tid;
        int r = slot >> 3, p = slot & 7;
        int rr = min(t0 + r, ce - 1);
        int c = p ^ (r & 7);
        asrc[q] = h + (size_t)(base + rr) * FFN_ + c*8;
    }

    const int brow = tid >> 1;
    const int hk   = tid & 1;
    const float* bsrc = w2e + (size_t)(n0 + brow) * FFN_ + hk*32;

    f32x4 acc[4][4];
#pragma unroll
    for (int m = 0; m < 4; ++m)
#pragma unroll
        for (int n = 0; n < 4; ++n) acc[m][n] = (f32x4){0.f,0.f,0.f,0.f};

    float4 breg[8];
#pragma unroll
    for (int j = 0; j < 8; ++j) breg[j] = *(const float4*)(bsrc + j*4);

    for (int k0 = 0; k0 < FFN_; k0 += 64) {
#pragma unroll
        for (int q = 0; q < 4; ++q) {
            __builtin_amdgcn_global_load_lds(
                (GVOID*)(asrc[q] + k0),
                (LVOID*)(&As[(q*256 + wid*64)*8]), 16, 0, 0);
        }
#pragma unroll
        for (int cc = 0; cc < 4; ++cc) {
            union { bf16x8 v; short s8[8]; } u;
            const float* f0 = (const float*)&breg[2*cc];
#pragma unroll
            for (int j = 0; j < 8; ++j) u.s8[j] = f2bf(f0[j]);
            int c = hk*4 + cc, p = c ^ (brow & 7);
            *(bf16x8*)&Bs[brow*64 + p*8] = u.v;
        }
        __syncthreads();

        if (k0 + 64 < FFN_) {
#pragma unroll
            for (int j = 0; j < 8; ++j) breg[j] = *(const float4*)(bsrc + (k0+64) + j*4);
        }

        bf16x8 af[4][2], bfr[4][2];
#pragma unroll
        for (int m = 0; m < 4; ++m)
#pragma unroll
            for (int kk = 0; kk < 2; ++kk) {
                int r = wm*64 + m*16 + (lane & 15);
                int c = kk*4 + (lane >> 4), p = c ^ (r & 7);
                af[m][kk] = *(bf16x8*)&As[r*64 + p*8];
            }
#pragma unroll
        for (int n = 0; n < 4; ++n)
#pragma unroll
            for (int kk = 0; kk < 2; ++kk) {
                int r = wn*64 + n*16 + (lane & 15);
                int c = kk*4 + (lane >> 4), p = c ^ (r & 7);
                bfr[n][kk] = *(bf16x8*)&Bs[r*64 + p*8];
            }
#pragma unroll
        for (int kk = 0; kk < 2; ++kk)
#pragma unroll
            for (int m = 0; m < 4; ++m)
#pragma unroll
                for (int n = 0; n < 4; ++n)
                    acc[m][n] = __builtin_amdgcn_mfma_f32_16x16x32_bf16(
                        af[m][kk], bfr[n][kk], acc[m][n], 0, 0, 0);
        __syncthreads();
    }

    const float* w2be = w2b + e*HID_;
#pragma unroll
    for (int n = 0; n < 4; ++n) {
        int col = n0 + wn*64 + n*16 + (lane & 15);
        float bias = w2be[col];
#pragma unroll
        for (int m = 0; m < 4; ++m) {
            int rb2 = t0 + wm*64 + m*16 + (lane >> 4)*4;
#pragma unroll
            for (int i = 0; i < 4; ++i) {
                int t = rb2 + i;
                if (t < ce) {
                    int p   = base + t;
                    float w = gwt[p];
                    atomicAdd(&out[(size_t)gtok[p]*HID_ + col], w * (acc[m][n][i] + bias));
                }
            }
        }
    }
}

// ---------------------------------------------------------------------------
extern "C" void kernel_launch(void* const* d_in, const int* in_sizes, int n_in,
                              void* d_out, int out_size, void* d_ws, size_t ws_size,
                              hipStream_t stream)
{
    const float* x   = (const float*)d_in[0];
    const float* rw  = (const float*)d_in[1];
    const float* rb  = (const float*)d_in[2];
    const float* w1  = (const float*)d_in[3];
    const float* w1b = (const float*)d_in[4];
    const float* w2  = (const float*)d_in[5];
    const float* w2b = (const float*)d_in[6];

    float* out      = (float*)d_out;
    float* topk_out = out + (size_t)M_ * HID_;

    char*  ws   = (char*)d_ws;
    int*   ids  = (int*)  (ws);
    float* wts  = (float*)(ws + 16384);
    int*   gtok = (int*)  (ws + 32768);
    float* gwt  = (float*)(ws + 49152);
    int*   cnt  = (int*)  (ws + 65536);
    int*   off  = (int*)  (ws + 65536 + 128);
    int*   fill = (int*)  (ws + 65536 + 256);
    int*   pos  = (int*)  (ws + 98304);

    const size_t MB = 1024*1024;
    __hip_bfloat16* xb    = (__hip_bfloat16*)(ws + 131072);            // 4 MB
    __hip_bfloat16* h     = (__hip_bfloat16*)(ws + 131072 + 4*MB);     // 16 MB
    float*          dpair = (float*)         (ws + 131072 + 20*MB);    // 32 MB (2 slices)
    __hip_bfloat16* w1bf  = (__hip_bfloat16*)(ws + 131072 + 52*MB);    // 64 MB
    __hip_bfloat16* w2bf  = (__hip_bfloat16*)(ws + 131072 + 116*MB);   // 32 MB
    const bool tier2 = (ws_size >= 131072 + 148*MB);

    hipMemsetAsync(cnt, 0, E_ * sizeof(int), stream);

    router_kernel<<<M_, 64, 0, stream>>>(x, rw, rb, ids, wts, cnt, topk_out, xb);
    offsets_kernel<<<1, 64, 0, stream>>>(cnt, off, fill);
    scatter_kernel<<<M_/256, 256, 0, stream>>>(ids, wts, fill, gtok, gwt, pos);

    if (tier2) {
        cvt_w_kernel<<<4096, 256, 0, stream>>>(w1, w2, w1bf, w2bf);

        dim3 g1(FFN_/64, M_/128, E_);        // (32, 16, 8)
        gemm1_kernel<<<g1, 256, 0, stream>>>(xb, w1bf, w1b, gtok, cnt, off, h);

        dim3 g2(HID_/128, M_/128, 2*E_);     // (8, 16, 16) split-K=2
        gemm2_kernel<<<g2, 256, 0, stream>>>(h, w2bf, w2b, gwt, cnt, off, dpair);

        combine_kernel<<<(M_*HID_)/(256*4), 256, 0, stream>>>(dpair, pos, out);
    } else {
        hipMemsetAsync(out, 0, (size_t)M_ * HID_ * sizeof(float), stream);

        dim3 g1(FFN_/64, M_/128, E_);
        gemm1_rs_kernel<<<g1, 256, 0, stream>>>(xb, w1, w1b, gtok, cnt, off, h);

        dim3 g2(HID_/128, M_/128, E_);
        gemm2_rs_kernel<<<g2, 256, 0, stream>>>(h, w2, w2b, gtok, gwt, cnt, off, out);
    }
}

// Round 11
// 242.962 us; speedup vs baseline: 1.2854x; 1.0379x over previous
//
#include <hip/hip_runtime.h>
#include <hip/hip_bf16.h>
#include <math.h>

#define E_    8
#define HID_  1024
#define FFN_  2048
#define M_    2048     // B*S
#define NP_   (M_*2)   // total (token, expert) pairs

typedef __attribute__((ext_vector_type(8))) short bf16x8;
typedef __attribute__((ext_vector_type(8))) short short8v;
typedef __attribute__((ext_vector_type(4))) float f32x4;

typedef const __attribute__((address_space(1))) void GVOID;
typedef __attribute__((address_space(3))) void LVOID;

#define VMCNT4 asm volatile("s_waitcnt vmcnt(4)" ::: "memory")
#define VMCNT0 asm volatile("s_waitcnt vmcnt(0)" ::: "memory")

__device__ __forceinline__ short f2bf(float f) {
    union { __hip_bfloat16 b; short s; } u;
    u.b = __float2bfloat16(f);
    return u.s;
}

// ---------------------------------------------------------------------------
// w1 + w2 fp32 -> bf16, 8 elems/thread: 2x float4 load + 1x 16B short8 store
// ---------------------------------------------------------------------------
__global__ __launch_bounds__(256) void cvt_w_kernel(
    const float* __restrict__ w1, const float* __restrict__ w2,
    __hip_bfloat16* __restrict__ w1bf, __hip_bfloat16* __restrict__ w2bf)
{
    const int n1 = (E_*2*FFN_*HID_)/8;    // 8-elem chunks in w1
    const int n2 = (E_*HID_*FFN_)/8;      // 8-elem chunks in w2
    int stride = gridDim.x * 256;
    for (int i = blockIdx.x * 256 + threadIdx.x; i < n1 + n2; i += stride) {
        const float4* s4;
        short8v* d8;
        if (i < n1) { s4 = (const float4*)w1 + 2*(size_t)i;      d8 = (short8v*)w1bf + i; }
        else        { int j = i - n1;
                      s4 = (const float4*)w2 + 2*(size_t)j;      d8 = (short8v*)w2bf + j; }
        float4 a = s4[0];
        float4 b = s4[1];
        short8v o;
        o[0] = f2bf(a.x); o[1] = f2bf(a.y); o[2] = f2bf(a.z); o[3] = f2bf(a.w);
        o[4] = f2bf(b.x); o[5] = f2bf(b.y); o[6] = f2bf(b.z); o[7] = f2bf(b.w);
        *d8 = o;
    }
}

// ---------------------------------------------------------------------------
// Router (+ fused x->bf16 conversion): one wave per token.  [proven]
// ---------------------------------------------------------------------------
__global__ __launch_bounds__(64) void router_kernel(
    const float* __restrict__ x, const float* __restrict__ rw,
    const float* __restrict__ rb, int* __restrict__ ids,
    float* __restrict__ wts, int* __restrict__ cnt,
    float* __restrict__ topk_out, __hip_bfloat16* __restrict__ xb)
{
    const int m    = blockIdx.x;
    const int lane = threadIdx.x;
    const float4* xm4 = (const float4*)(x + (size_t)m * HID_);

    float4 xv[4];
#pragma unroll
    for (int j = 0; j < 4; ++j) xv[j] = xm4[j*64 + lane];

    short4* xbr = (short4*)(xb + (size_t)m * HID_);
#pragma unroll
    for (int j = 0; j < 4; ++j) {
        short4 o;
        o.x = f2bf(xv[j].x); o.y = f2bf(xv[j].y);
        o.z = f2bf(xv[j].z); o.w = f2bf(xv[j].w);
        xbr[j*64 + lane] = o;
    }

    float lg[E_];
#pragma unroll
    for (int e = 0; e < E_; ++e) {
        const float4* we4 = (const float4*)(rw + e * HID_);
        float s = 0.f;
#pragma unroll
        for (int j = 0; j < 4; ++j) {
            float4 w = we4[j*64 + lane];
            s = fmaf(xv[j].x, w.x, s);
            s = fmaf(xv[j].y, w.y, s);
            s = fmaf(xv[j].z, w.z, s);
            s = fmaf(xv[j].w, w.w, s);
        }
        lg[e] = s;
    }
#pragma unroll
    for (int off = 32; off; off >>= 1)
#pragma unroll
        for (int e = 0; e < E_; ++e) lg[e] += __shfl_xor(lg[e], off);

    if (lane == 0) {
        float l2[E_], p[E_];
        float mx = -1e30f;
#pragma unroll
        for (int e = 0; e < E_; ++e) { l2[e] = lg[e] + rb[e]; mx = fmaxf(mx, l2[e]); }
        float sum = 0.f;
#pragma unroll
        for (int e = 0; e < E_; ++e) { p[e] = expf(l2[e] - mx); sum += p[e]; }
        float inv = 1.f / sum;
#pragma unroll
        for (int e = 0; e < E_; ++e) p[e] *= inv;

        int   i1 = -1, i2 = -1;
        float v1 = -1e30f, v2 = -1e30f;
#pragma unroll
        for (int e = 0; e < E_; ++e) {
            float pe = p[e];
            if (pe > v1)      { v2 = v1; i2 = i1; v1 = pe; i1 = e; }
            else if (pe > v2) { v2 = pe; i2 = e; }
        }
        ids[2*m]   = i1;  ids[2*m+1]   = i2;
        wts[2*m]   = v1;  wts[2*m+1]   = v2;
        topk_out[2*m]   = v1;
        topk_out[2*m+1] = v2;
        atomicAdd(&cnt[i1], 1);
        atomicAdd(&cnt[i2], 1);
    }
}

__global__ void offsets_kernel(const int* __restrict__ cnt,
                               int* __restrict__ off, int* __restrict__ fill)
{
    if (threadIdx.x == 0 && blockIdx.x == 0) {
        int acc = 0;
        for (int e = 0; e < E_; ++e) { off[e] = acc; fill[e] = acc; acc += cnt[e]; }
    }
}

__global__ __launch_bounds__(256) void scatter_kernel(
    const int* __restrict__ ids, const float* __restrict__ wts,
    int* __restrict__ fill, int* __restrict__ gtok, float* __restrict__ gwt,
    int* __restrict__ pos)
{
    int m = blockIdx.x * 256 + threadIdx.x;
    if (m >= M_) return;
#pragma unroll
    for (int s = 0; s < 2; ++s) {
        int e = ids[2*m + s];
        int p = atomicAdd(&fill[e], 1);
        gtok[p] = m;
        gwt[p]  = wts[2*m + s];
        pos[2*m + s] = p;
    }
}

// ===========================================================================
// TIER-2 GEMMs [measured optimum, 252us config]: 128x128 block, 4 waves of
// 64x64, BK=32, TRIPLE-buffered LDS (48KB), depth-2 prefetch, counted
// vmcnt(4) at barriers (only newest tile's 4 loads stay in flight).
// LDS swizzle: 16B chunk p of row r holds global chunk p ^ ((r>>1)&3).
// ===========================================================================

// GEMM1: 128 gathered tokens x 64 h-cols. K = HID = 1024, NT = 32 steps.
__global__ __launch_bounds__(256, 3) void gemm1_kernel(
    const __hip_bfloat16* __restrict__ xb, const __hip_bfloat16* __restrict__ w1bf,
    const float* __restrict__ w1b, const int* __restrict__ gtok,
    const int* __restrict__ cnt, const int* __restrict__ off,
    __hip_bfloat16* __restrict__ h)
{
    const int e  = blockIdx.z;
    const int ce = cnt[e];
    const int t0 = blockIdx.y * 128;
    if (t0 >= ce) return;
    const int n0   = blockIdx.x * 64;
    const int base = off[e];
    const __hip_bfloat16* w1e = w1bf + (size_t)e * (2*FFN_) * HID_;

    __shared__ __align__(16) __hip_bfloat16 As[3][128*32];
    __shared__ __align__(16) __hip_bfloat16 Bs[3][128*32];

    const int tid  = threadIdx.x;
    const int lane = tid & 63;
    const int wid  = tid >> 6;
    const int wm   = wid >> 1;
    const int wn   = wid & 1;

    const __hip_bfloat16 *asrc[2], *bsrc[2];
#pragma unroll
    for (int q = 0; q < 2; ++q) {
        int slot = q*256 + tid;
        int r = slot >> 2, p = slot & 3;
        int c = p ^ ((r >> 1) & 3);
        int rr  = min(t0 + r, ce - 1);
        asrc[q] = xb + (size_t)gtok[base + rr] * HID_ + c*8;
        int q2 = r >> 5, s = r & 31;
        int grow = (q2 & 1) ? (FFN_ + n0 + (q2>>1)*32 + s)
                            : (       n0 + (q2>>1)*32 + s);
        bsrc[q] = w1e + (size_t)grow * HID_ + c*8;
    }

    auto STAGE = [&](int b, int k0) {
#pragma unroll
        for (int q = 0; q < 2; ++q)
            __builtin_amdgcn_global_load_lds((GVOID*)(asrc[q] + k0),
                (LVOID*)(&As[b][(q*256 + wid*64)*8]), 16, 0, 0);
#pragma unroll
        for (int q = 0; q < 2; ++q)
            __builtin_amdgcn_global_load_lds((GVOID*)(bsrc[q] + k0),
                (LVOID*)(&Bs[b][(q*256 + wid*64)*8]), 16, 0, 0);
    };

    f32x4 acc[4][4];
#pragma unroll
    for (int m = 0; m < 4; ++m)
#pragma unroll
        for (int n = 0; n < 4; ++n) acc[m][n] = (f32x4){0.f,0.f,0.f,0.f};

    const int cf = lane >> 4;
    auto COMPUTE = [&](int cb) {
        bf16x8 af[4], bfr[4];
#pragma unroll
        for (int m = 0; m < 4; ++m) {
            int r = wm*64 + m*16 + (lane & 15);
            int sw = cf ^ ((r >> 1) & 3);
            af[m] = *(bf16x8*)&As[cb][r*32 + sw*8];
        }
#pragma unroll
        for (int n = 0; n < 4; ++n) {
            int r = wn*64 + n*16 + (lane & 15);
            int sw = cf ^ ((r >> 1) & 3);
            bfr[n] = *(bf16x8*)&Bs[cb][r*32 + sw*8];
        }
        __builtin_amdgcn_s_setprio(1);
#pragma unroll
        for (int m = 0; m < 4; ++m)
#pragma unroll
            for (int n = 0; n < 4; ++n)
                acc[m][n] = __builtin_amdgcn_mfma_f32_16x16x32_bf16(
                    af[m], bfr[n], acc[m][n], 0, 0, 0);
        __builtin_amdgcn_s_setprio(0);
    };

    const int NT = HID_/32;   // 32
    STAGE(0, 0);
    STAGE(1, 32);
    VMCNT4;
    __builtin_amdgcn_s_barrier();

    int cb = 0;
    for (int t = 0; t < NT-2; ++t) {
        int sb = cb + 2; if (sb >= 3) sb -= 3;
        STAGE(sb, (t+2)*32);
        COMPUTE(cb);
        VMCNT4;                         // tile t+1 landed; t+2 stays in flight
        __builtin_amdgcn_s_barrier();
        if (++cb == 3) cb = 0;
    }
    COMPUTE(cb);                        // t = NT-2
    VMCNT0;
    __builtin_amdgcn_s_barrier();
    if (++cb == 3) cb = 0;
    COMPUTE(cb);                        // t = NT-1

    // Epilogue: fused SiLU(gate)*up -> h (bf16)
    const float* w1be = w1b + e*2*FFN_;
#pragma unroll
    for (int n = 0; n < 2; ++n) {
        int col = n0 + wn*32 + n*16 + (lane & 15);
        float bg = w1be[col];
        float bu = w1be[FFN_ + col];
#pragma unroll
        for (int m = 0; m < 4; ++m) {
            int rb2 = t0 + wm*64 + m*16 + (lane >> 4)*4;
#pragma unroll
            for (int i = 0; i < 4; ++i) {
                int t = rb2 + i;
                if (t < ce) {
                    float g = acc[m][n][i]   + bg;
                    float u = acc[m][n+2][i] + bu;
                    float hv = (g / (1.f + __expf(-g))) * u;
                    h[(size_t)(base + t)*FFN_ + col] = __float2bfloat16(hv);
                }
            }
        }
    }
}

// GEMM2: 128 pairs x 128 hid cols, split-K=2 (z = e + 8*ks). Plain stores
// into dpair[ks] (no init, no atomics); combine sums 4 slices.
__global__ __launch_bounds__(256, 3) void gemm2_kernel(
    const __hip_bfloat16* __restrict__ h, const __hip_bfloat16* __restrict__ w2bf,
    const float* __restrict__ w2b, const float* __restrict__ gwt,
    const int* __restrict__ cnt, const int* __restrict__ off,
    float* __restrict__ dpair)
{
    const int e  = blockIdx.z & 7;
    const int ks = blockIdx.z >> 3;
    const int ce = cnt[e];
    const int t0 = blockIdx.y * 128;
    if (t0 >= ce) return;
    const int n0    = blockIdx.x * 128;
    const int base  = off[e];
    const int kbase = ks * (FFN_/2);
    const __hip_bfloat16* w2e = w2bf + (size_t)e * HID_ * FFN_;

    __shared__ __align__(16) __hip_bfloat16 As[3][128*32];
    __shared__ __align__(16) __hip_bfloat16 Bs[3][128*32];

    const int tid  = threadIdx.x;
    const int lane = tid & 63;
    const int wid  = tid >> 6;
    const int wm   = wid >> 1;
    const int wn   = wid & 1;

    const __hip_bfloat16 *asrc[2], *bsrc[2];
#pragma unroll
    for (int q = 0; q < 2; ++q) {
        int slot = q*256 + tid;
        int r = slot >> 2, p = slot & 3;
        int c = p ^ ((r >> 1) & 3);
        int rr = min(t0 + r, ce - 1);
        asrc[q] = h   + (size_t)(base + rr) * FFN_ + kbase + c*8;
        bsrc[q] = w2e + (size_t)(n0 + r)    * FFN_ + kbase + c*8;
    }

    auto STAGE = [&](int b, int k0) {
#pragma unroll
        for (int q = 0; q < 2; ++q)
            __builtin_amdgcn_global_load_lds((GVOID*)(asrc[q] + k0),
                (LVOID*)(&As[b][(q*256 + wid*64)*8]), 16, 0, 0);
#pragma unroll
        for (int q = 0; q < 2; ++q)
            __builtin_amdgcn_global_load_lds((GVOID*)(bsrc[q] + k0),
                (LVOID*)(&Bs[b][(q*256 + wid*64)*8]), 16, 0, 0);
    };

    f32x4 acc[4][4];
#pragma unroll
    for (int m = 0; m < 4; ++m)
#pragma unroll
        for (int n = 0; n < 4; ++n) acc[m][n] = (f32x4){0.f,0.f,0.f,0.f};

    const int cf = lane >> 4;
    auto COMPUTE = [&](int cb) {
        bf16x8 af[4], bfr[4];
#pragma unroll
        for (int m = 0; m < 4; ++m) {
            int r = wm*64 + m*16 + (lane & 15);
            int sw = cf ^ ((r >> 1) & 3);
            af[m] = *(bf16x8*)&As[cb][r*32 + sw*8];
        }
#pragma unroll
        for (int n = 0; n < 4; ++n) {
            int r = wn*64 + n*16 + (lane & 15);
            int sw = cf ^ ((r >> 1) & 3);
            bfr[n] = *(bf16x8*)&Bs[cb][r*32 + sw*8];
        }
        __builtin_amdgcn_s_setprio(1);
#pragma unroll
        for (int m = 0; m < 4; ++m)
#pragma unroll
            for (int n = 0; n < 4; ++n)
                acc[m][n] = __builtin_amdgcn_mfma_f32_16x16x32_bf16(
                    af[m], bfr[n], acc[m][n], 0, 0, 0);
        __builtin_amdgcn_s_setprio(0);
    };

    const int NT = (FFN_/2)/32;   // 32
    STAGE(0, 0);
    STAGE(1, 32);
    VMCNT4;
    __builtin_amdgcn_s_barrier();

    int cb = 0;
    for (int t = 0; t < NT-2; ++t) {
        int sb = cb + 2; if (sb >= 3) sb -= 3;
        STAGE(sb, (t+2)*32);
        COMPUTE(cb);
        VMCNT4;
        __builtin_amdgcn_s_barrier();
        if (++cb == 3) cb = 0;
    }
    COMPUTE(cb);
    VMCNT0;
    __builtin_amdgcn_s_barrier();
    if (++cb == 3) cb = 0;
    COMPUTE(cb);

    const float* w2be = w2b + e*HID_;
    float* dpk = dpair + (size_t)ks * NP_ * HID_;
#pragma unroll
    for (int n = 0; n < 4; ++n) {
        int col = n0 + wn*64 + n*16 + (lane & 15);
        float bias = (ks == 0) ? w2be[col] : 0.f;
#pragma unroll
        for (int m = 0; m < 4; ++m) {
            int rb2 = t0 + wm*64 + m*16 + (lane >> 4)*4;
#pragma unroll
            for (int i = 0; i < 4; ++i) {
                int t = rb2 + i;
                if (t < ce) {
                    int p   = base + t;
                    float w = gwt[p];
                    dpk[(size_t)p*HID_ + col] = w * (acc[m][n][i] + bias);
                }
            }
        }
    }
}

// out[m][c] = d0[p0][c]+d1[p0][c]+d0[p1][c]+d1[p1][c]   (fixed order)
__global__ __launch_bounds__(256) void combine_kernel(
    const float* __restrict__ dpair, const int* __restrict__ pos,
    float* __restrict__ out)
{
    int idx = blockIdx.x * 256 + threadIdx.x;
    int m   = idx >> 8;
    int c4  = (idx & 255) * 4;
    int p0 = pos[2*m], p1 = pos[2*m+1];
    const float* d0 = dpair;
    const float* d1 = dpair + (size_t)NP_ * HID_;
    float4 a0 = *(const float4*)(d0 + (size_t)p0*HID_ + c4);
    float4 a1 = *(const float4*)(d1 + (size_t)p0*HID_ + c4);
    float4 b0 = *(const float4*)(d0 + (size_t)p1*HID_ + c4);
    float4 b1 = *(const float4*)(d1 + (size_t)p1*HID_ + c4);
    float4 o = make_float4((a0.x+a1.x)+(b0.x+b1.x), (a0.y+a1.y)+(b0.y+b1.y),
                           (a0.z+a1.z)+(b0.z+b1.z), (a0.w+a1.w)+(b0.w+b1.w));
    *(float4*)(out + (size_t)m*HID_ + c4) = o;
}

// ===========================================================================
// FALLBACK (proven round-2 structure) — only if ws_size too small for tier2.
// ===========================================================================
__global__ __launch_bounds__(256) void gemm1_rs_kernel(
    const __hip_bfloat16* __restrict__ xb, const float* __restrict__ w1,
    const float* __restrict__ w1b, const int* __restrict__ gtok,
    const int* __restrict__ cnt, const int* __restrict__ off,
    __hip_bfloat16* __restrict__ h)
{
    const int e  = blockIdx.z;
    const int ce = cnt[e];
    const int t0 = blockIdx.y * 128;
    if (t0 >= ce) return;
    const int n0   = blockIdx.x * 64;
    const int base = off[e];
    const float* w1e = w1 + (size_t)e * (2*FFN_) * HID_;

    __shared__ __align__(16) __hip_bfloat16 As[128*64];
    __shared__ __align__(16) __hip_bfloat16 Bs[128*64];

    const int tid  = threadIdx.x;
    const int lane = tid & 63;
    const int wid  = tid >> 6;
    const int wm   = wid >> 1;
    const int wn   = wid & 1;

    const __hip_bfloat16* asrc[4];
#pragma unroll
    for (int q = 0; q < 4; ++q) {
        int slot = q*256 + tid;
        int r = slot >> 3, p = slot & 7;
        int rr  = min(t0 + r, ce - 1);
        int tok = gtok[base + rr];
        int c = p ^ (r & 7);
        asrc[q] = xb + (size_t)tok * HID_ + c*8;
    }

    const int brow = tid >> 1;
    const int hk   = tid & 1;
    const int q2 = brow >> 5, s = brow & 31;
    const int grow = (q2 & 1) ? (FFN_ + n0 + (q2>>1)*32 + s)
                              : (       n0 + (q2>>1)*32 + s);
    const float* bsrc = w1e + (size_t)grow * HID_ + hk*32;

    f32x4 acc[4][4];
#pragma unroll
    for (int m = 0; m < 4; ++m)
#pragma unroll
        for (int n = 0; n < 4; ++n) acc[m][n] = (f32x4){0.f,0.f,0.f,0.f};

    float4 breg[8];
#pragma unroll
    for (int j = 0; j < 8; ++j) breg[j] = *(const float4*)(bsrc + j*4);

    for (int k0 = 0; k0 < HID_; k0 += 64) {
#pragma unroll
        for (int q = 0; q < 4; ++q) {
            __builtin_amdgcn_global_load_lds(
                (GVOID*)(asrc[q] + k0),
                (LVOID*)(&As[(q*256 + wid*64)*8]), 16, 0, 0);
        }
#pragma unroll
        for (int cc = 0; cc < 4; ++cc) {
            union { bf16x8 v; short s8[8]; } u;
            const float* f0 = (const float*)&breg[2*cc];
#pragma unroll
            for (int j = 0; j < 8; ++j) u.s8[j] = f2bf(f0[j]);
            int c = hk*4 + cc, p = c ^ (brow & 7);
            *(bf16x8*)&Bs[brow*64 + p*8] = u.v;
        }
        __syncthreads();

        if (k0 + 64 < HID_) {
#pragma unroll
            for (int j = 0; j < 8; ++j) breg[j] = *(const float4*)(bsrc + (k0+64) + j*4);
        }

        bf16x8 af[4][2], bfr[4][2];
#pragma unroll
        for (int m = 0; m < 4; ++m)
#pragma unroll
            for (int kk = 0; kk < 2; ++kk) {
                int r = wm*64 + m*16 + (lane & 15);
                int c = kk*4 + (lane >> 4), p = c ^ (r & 7);
                af[m][kk] = *(bf16x8*)&As[r*64 + p*8];
            }
#pragma unroll
        for (int n = 0; n < 4; ++n)
#pragma unroll
            for (int kk = 0; kk < 2; ++kk) {
                int r = wn*64 + n*16 + (lane & 15);
                int c = kk*4 + (lane >> 4), p = c ^ (r & 7);
                bfr[n][kk] = *(bf16x8*)&Bs[r*64 + p*8];
            }
#pragma unroll
        for (int kk = 0; kk < 2; ++kk)
#pragma unroll
            for (int m = 0; m < 4; ++m)
#pragma unroll
                for (int n = 0; n < 4; ++n)
                    acc[m][n] = __builtin_amdgcn_mfma_f32_16x16x32_bf16(
                        af[m][kk], bfr[n][kk], acc[m][n], 0, 0, 0);
        __syncthreads();
    }

    const float* w1be = w1b + e*2*FFN_;
#pragma unroll
    for (int n = 0; n < 2; ++n) {
        int col = n0 + wn*32 + n*16 + (lane & 15);
        float bg = w1be[col];
        float bu = w1be[FFN_ + col];
#pragma unroll
        for (int m = 0; m < 4; ++m) {
            int rb2 = t0 + wm*64 + m*16 + (lane >> 4)*4;
#pragma unroll
            for (int i = 0; i < 4; ++i) {
                int t = rb2 + i;
                if (t < ce) {
                    float g = acc[m][n][i]   + bg;
                    float u = acc[m][n+2][i] + bu;
                    float hv = (g / (1.f + __expf(-g))) * u;
                    h[(size_t)(base + t)*FFN_ + col] = __float2bfloat16(hv);
                }
            }
        }
    }
}

__global__ __launch_bounds__(256) void gemm2_rs_kernel(
    const __hip_bfloat16* __restrict__ h, const float* __restrict__ w2,
    const float* __restrict__ w2b, const int* __restrict__ gtok,
    const float* __restrict__ gwt, const int* __restrict__ cnt,
    const int* __restrict__ off, float* __restrict__ out)
{
    const int e  = blockIdx.z;
    const int ce = cnt[e];
    const int t0 = blockIdx.y * 128;
    if (t0 >= ce) return;
    const int n0   = blockIdx.x * 128;
    const int base = off[e];
    const float* w2e = w2 + (size_t)e * HID_ * FFN_;

    __shared__ __align__(16) __hip_bfloat16 As[128*64];
    __shared__ __align__(16) __hip_bfloat16 Bs[128*64];

    const int tid  = threadIdx.x;
    const int lane = tid & 63;
    const int wid  = tid >> 6;
    const int wm   = wid >> 1;
    const int wn   = wid & 1;

    const __hip_bfloat16* asrc[4];
#pragma unroll
    for (int q = 0; q < 4; ++q) {
        int slot = q*256 + tid;
        int r = slot >> 3, p = slot & 7;
        int rr = min(t0 + r, ce - 1);
        int c = p ^ (r & 7);
        asrc[q] = h + (size_t)(base + rr) * FFN_ + c*8;
    }

    const int brow = tid >> 1;
    const int hk   = tid & 1;
    const float* bsrc = w2e + (size_t)(n0 + brow) * FFN_ + hk*32;

    f32x4 acc[4][4];
#pragma unroll
    for (int m = 0; m < 4; ++m)
#pragma unroll
        for (int n = 0; n < 4; ++n) acc[m][n] = (f32x4){0.f,0.f,0.f,0.f};

    float4 breg[8];
#pragma unroll
    for (int j = 0; j < 8; ++j) breg[j] = *(const float4*)(bsrc + j*4);

    for (int k0 = 0; k0 < FFN_; k0 += 64) {
#pragma unroll
        for (int q = 0; q < 4; ++q) {
            __builtin_amdgcn_global_load_lds(
                (GVOID*)(asrc[q] + k0),
                (LVOID*)(&As[(q*256 + wid*64)*8]), 16, 0, 0);
        }
#pragma unroll
        for (int cc = 0; cc < 4; ++cc) {
            union { bf16x8 v; short s8[8]; } u;
            const float* f0 = (const float*)&breg[2*cc];
#pragma unroll
            for (int j = 0; j < 8; ++j) u.s8[j] = f2bf(f0[j]);
            int c = hk*4 + cc, p = c ^ (brow & 7);
            *(bf16x8*)&Bs[brow*64 + p*8] = u.v;
        }
        __syncthreads();

        if (k0 + 64 < FFN_) {
#pragma unroll
            for (int j = 0; j < 8; ++j) breg[j] = *(const float4*)(bsrc + (k0+64) + j*4);
        }

        bf16x8 af[4][2], bfr[4][2];
#pragma unroll
        for (int m = 0; m < 4; ++m)
#pragma unroll
            for (int kk = 0; kk < 2; ++kk) {
                int r = wm*64 + m*16 + (lane & 15);
                int c = kk*4 + (lane >> 4), p = c ^ (r & 7);
                af[m][kk] = *(bf16x8*)&As[r*64 + p*8];
            }
#pragma unroll
        for (int n = 0; n < 4; ++n)
#pragma unroll
            for (int kk = 0; kk < 2; ++kk) {
                int r = wn*64 + n*16 + (lane & 15);
                int c = kk*4 + (lane >> 4), p = c ^ (r & 7);
                bfr[n][kk] = *(bf16x8*)&Bs[r*64 + p*8];
            }
#pragma unroll
        for (int kk = 0; kk < 2; ++kk)
#pragma unroll
            for (int m = 0; m < 4; ++m)
#pragma unroll
                for (int n = 0; n < 4; ++n)
                    acc[m][n] = __builtin_amdgcn_mfma_f32_16x16x32_bf16(
                        af[m][kk], bfr[n][kk], acc[m][n], 0, 0, 0);
        __syncthreads();
    }

    const float* w2be = w2b + e*HID_;
#pragma unroll
    for (int n = 0; n < 4; ++n) {
        int col = n0 + wn*64 + n*16 + (lane & 15);
        float bias = w2be[col];
#pragma unroll
        for (int m = 0; m < 4; ++m) {
            int rb2 = t0 + wm*64 + m*16 + (lane >> 4)*4;
#pragma unroll
            for (int i = 0; i < 4; ++i) {
                int t = rb2 + i;
                if (t < ce) {
                    int p   = base + t;
                    float w = gwt[p];
                    atomicAdd(&out[(size_t)gtok[p]*HID_ + col], w * (acc[m][n][i] + bias));
                }
            }
        }
    }
}

// ---------------------------------------------------------------------------
extern "C" void kernel_launch(void* const* d_in, const int* in_sizes, int n_in,
                              void* d_out, int out_size, void* d_ws, size_t ws_size,
                              hipStream_t stream)
{
    const float* x   = (const float*)d_in[0];
    const float* rw  = (const float*)d_in[1];
    const float* rb  = (const float*)d_in[2];
    const float* w1  = (const float*)d_in[3];
    const float* w1b = (const float*)d_in[4];
    const float* w2  = (const float*)d_in[5];
    const float* w2b = (const float*)d_in[6];

    float* out      = (float*)d_out;
    float* topk_out = out + (size_t)M_ * HID_;

    char*  ws   = (char*)d_ws;
    int*   ids  = (int*)  (ws);
    float* wts  = (float*)(ws + 16384);
    int*   gtok = (int*)  (ws + 32768);
    float* gwt  = (float*)(ws + 49152);
    int*   cnt  = (int*)  (ws + 65536);
    int*   off  = (int*)  (ws + 65536 + 128);
    int*   fill = (int*)  (ws + 65536 + 256);
    int*   pos  = (int*)  (ws + 98304);

    const size_t MB = 1024*1024;
    __hip_bfloat16* xb    = (__hip_bfloat16*)(ws + 131072);            // 4 MB
    __hip_bfloat16* h     = (__hip_bfloat16*)(ws + 131072 + 4*MB);     // 16 MB
    float*          dpair = (float*)         (ws + 131072 + 20*MB);    // 32 MB (2 slices)
    __hip_bfloat16* w1bf  = (__hip_bfloat16*)(ws + 131072 + 52*MB);    // 64 MB
    __hip_bfloat16* w2bf  = (__hip_bfloat16*)(ws + 131072 + 116*MB);   // 32 MB
    const bool tier2 = (ws_size >= 131072 + 148*MB);

    hipMemsetAsync(cnt, 0, E_ * sizeof(int), stream);

    router_kernel<<<M_, 64, 0, stream>>>(x, rw, rb, ids, wts, cnt, topk_out, xb);
    offsets_kernel<<<1, 64, 0, stream>>>(cnt, off, fill);
    scatter_kernel<<<M_/256, 256, 0, stream>>>(ids, wts, fill, gtok, gwt, pos);

    if (tier2) {
        cvt_w_kernel<<<2048, 256, 0, stream>>>(w1, w2, w1bf, w2bf);

        dim3 g1(FFN_/64, M_/128, E_);        // (32, 16, 8)
        gemm1_kernel<<<g1, 256, 0, stream>>>(xb, w1bf, w1b, gtok, cnt, off, h);

        dim3 g2(HID_/128, M_/128, 2*E_);     // (8, 16, 16) split-K=2
        gemm2_kernel<<<g2, 256, 0, stream>>>(h, w2bf, w2b, gwt, cnt, off, dpair);

        combine_kernel<<<(M_*HID_)/(256*4), 256, 0, stream>>>(dpair, pos, out);
    } else {
        hipMemsetAsync(out, 0, (size_t)M_ * HID_ * sizeof(float), stream);

        dim3 g1(FFN_/64, M_/128, E_);
        gemm1_rs_kernel<<<g1, 256, 0, stream>>>(xb, w1, w1b, gtok, cnt, off, h);

        dim3 g2(HID_/128, M_/128, E_);
        gemm2_rs_kernel<<<g2, 256, 0, stream>>>(h, w2, w2b, gtok, gwt, cnt, off, out);
    }
}

// Round 12
// 240.410 us; speedup vs baseline: 1.2991x; 1.0106x over previous
//
#include <hip/hip_runtime.h>
#include <hip/hip_bf16.h>
#include <math.h>

#define E_    8
#define HID_  1024
#define FFN_  2048
#define M_    2048     // B*S
#define NP_   (M_*2)   // total (token, expert) pairs

typedef __attribute__((ext_vector_type(8))) short bf16x8;
typedef __attribute__((ext_vector_type(8))) short short8v;
typedef __attribute__((ext_vector_type(4))) float f32x4;

typedef const __attribute__((address_space(1))) void GVOID;
typedef __attribute__((address_space(3))) void LVOID;

#define VMCNT4 asm volatile("s_waitcnt vmcnt(4)" ::: "memory")
#define VMCNT0 asm volatile("s_waitcnt vmcnt(0)" ::: "memory")

__device__ __forceinline__ short f2bf(float f) {
    union { __hip_bfloat16 b; short s; } u;
    u.b = __float2bfloat16(f);
    return u.s;
}

// ---------------------------------------------------------------------------
// w1 + w2 fp32 -> bf16. Fully unrolled: 4 chunks (32 elems) per thread,
// 8 independent float4 loads in flight, then 4x16B stores. Grid = 6144:
// blocks [0,4096) cover w1 (4.19M chunks), [4096,6144) cover w2.
// ---------------------------------------------------------------------------
__global__ __launch_bounds__(256) void cvt_w_kernel(
    const float* __restrict__ w1, const float* __restrict__ w2,
    __hip_bfloat16* __restrict__ w1bf, __hip_bfloat16* __restrict__ w2bf)
{
    const float4* src;
    short8v* dst;
    size_t cbase;
    if (blockIdx.x < 4096) {
        src = (const float4*)w1;  dst = (short8v*)w1bf;
        cbase = (size_t)blockIdx.x * 1024;
    } else {
        src = (const float4*)w2;  dst = (short8v*)w2bf;
        cbase = (size_t)(blockIdx.x - 4096) * 1024;
    }

    float4 a[4], b[4];
#pragma unroll
    for (int u = 0; u < 4; ++u) {
        size_t c = cbase + u*256 + threadIdx.x;
        a[u] = src[2*c];
        b[u] = src[2*c + 1];
    }
#pragma unroll
    for (int u = 0; u < 4; ++u) {
        size_t c = cbase + u*256 + threadIdx.x;
        short8v o;
        o[0] = f2bf(a[u].x); o[1] = f2bf(a[u].y);
        o[2] = f2bf(a[u].z); o[3] = f2bf(a[u].w);
        o[4] = f2bf(b[u].x); o[5] = f2bf(b[u].y);
        o[6] = f2bf(b[u].z); o[7] = f2bf(b[u].w);
        dst[c] = o;
    }
}

// ---------------------------------------------------------------------------
// Router (+ fused x->bf16 conversion): one wave per token.  [proven]
// ---------------------------------------------------------------------------
__global__ __launch_bounds__(64) void router_kernel(
    const float* __restrict__ x, const float* __restrict__ rw,
    const float* __restrict__ rb, int* __restrict__ ids,
    float* __restrict__ wts, int* __restrict__ cnt,
    float* __restrict__ topk_out, __hip_bfloat16* __restrict__ xb)
{
    const int m    = blockIdx.x;
    const int lane = threadIdx.x;
    const float4* xm4 = (const float4*)(x + (size_t)m * HID_);

    float4 xv[4];
#pragma unroll
    for (int j = 0; j < 4; ++j) xv[j] = xm4[j*64 + lane];

    short4* xbr = (short4*)(xb + (size_t)m * HID_);
#pragma unroll
    for (int j = 0; j < 4; ++j) {
        short4 o;
        o.x = f2bf(xv[j].x); o.y = f2bf(xv[j].y);
        o.z = f2bf(xv[j].z); o.w = f2bf(xv[j].w);
        xbr[j*64 + lane] = o;
    }

    float lg[E_];
#pragma unroll
    for (int e = 0; e < E_; ++e) {
        const float4* we4 = (const float4*)(rw + e * HID_);
        float s = 0.f;
#pragma unroll
        for (int j = 0; j < 4; ++j) {
            float4 w = we4[j*64 + lane];
            s = fmaf(xv[j].x, w.x, s);
            s = fmaf(xv[j].y, w.y, s);
            s = fmaf(xv[j].z, w.z, s);
            s = fmaf(xv[j].w, w.w, s);
        }
        lg[e] = s;
    }
#pragma unroll
    for (int off = 32; off; off >>= 1)
#pragma unroll
        for (int e = 0; e < E_; ++e) lg[e] += __shfl_xor(lg[e], off);

    if (lane == 0) {
        float l2[E_], p[E_];
        float mx = -1e30f;
#pragma unroll
        for (int e = 0; e < E_; ++e) { l2[e] = lg[e] + rb[e]; mx = fmaxf(mx, l2[e]); }
        float sum = 0.f;
#pragma unroll
        for (int e = 0; e < E_; ++e) { p[e] = expf(l2[e] - mx); sum += p[e]; }
        float inv = 1.f / sum;
#pragma unroll
        for (int e = 0; e < E_; ++e) p[e] *= inv;

        int   i1 = -1, i2 = -1;
        float v1 = -1e30f, v2 = -1e30f;
#pragma unroll
        for (int e = 0; e < E_; ++e) {
            float pe = p[e];
            if (pe > v1)      { v2 = v1; i2 = i1; v1 = pe; i1 = e; }
            else if (pe > v2) { v2 = pe; i2 = e; }
        }
        ids[2*m]   = i1;  ids[2*m+1]   = i2;
        wts[2*m]   = v1;  wts[2*m+1]   = v2;
        topk_out[2*m]   = v1;
        topk_out[2*m+1] = v2;
        atomicAdd(&cnt[i1], 1);
        atomicAdd(&cnt[i2], 1);
    }
}

__global__ void offsets_kernel(const int* __restrict__ cnt,
                               int* __restrict__ off, int* __restrict__ fill)
{
    if (threadIdx.x == 0 && blockIdx.x == 0) {
        int acc = 0;
        for (int e = 0; e < E_; ++e) { off[e] = acc; fill[e] = acc; acc += cnt[e]; }
    }
}

__global__ __launch_bounds__(256) void scatter_kernel(
    const int* __restrict__ ids, const float* __restrict__ wts,
    int* __restrict__ fill, int* __restrict__ gtok, float* __restrict__ gwt,
    int* __restrict__ pos)
{
    int m = blockIdx.x * 256 + threadIdx.x;
    if (m >= M_) return;
#pragma unroll
    for (int s = 0; s < 2; ++s) {
        int e = ids[2*m + s];
        int p = atomicAdd(&fill[e], 1);
        gtok[p] = m;
        gwt[p]  = wts[2*m + s];
        pos[2*m + s] = p;
    }
}

// ===========================================================================
// TIER-2 GEMMs [measured optimum, 252us config]: 128x128 block, 4 waves of
// 64x64, BK=32, TRIPLE-buffered LDS (48KB), depth-2 prefetch, counted
// vmcnt(4) at barriers (only newest tile's 4 loads stay in flight).
// LDS swizzle: 16B chunk p of row r holds global chunk p ^ ((r>>1)&3).
// ===========================================================================

// GEMM1: 128 gathered tokens x 64 h-cols. K = HID = 1024, NT = 32 steps.
__global__ __launch_bounds__(256, 3) void gemm1_kernel(
    const __hip_bfloat16* __restrict__ xb, const __hip_bfloat16* __restrict__ w1bf,
    const float* __restrict__ w1b, const int* __restrict__ gtok,
    const int* __restrict__ cnt, const int* __restrict__ off,
    __hip_bfloat16* __restrict__ h)
{
    const int e  = blockIdx.z;
    const int ce = cnt[e];
    const int t0 = blockIdx.y * 128;
    if (t0 >= ce) return;
    const int n0   = blockIdx.x * 64;
    const int base = off[e];
    const __hip_bfloat16* w1e = w1bf + (size_t)e * (2*FFN_) * HID_;

    __shared__ __align__(16) __hip_bfloat16 As[3][128*32];
    __shared__ __align__(16) __hip_bfloat16 Bs[3][128*32];

    const int tid  = threadIdx.x;
    const int lane = tid & 63;
    const int wid  = tid >> 6;
    const int wm   = wid >> 1;
    const int wn   = wid & 1;

    const __hip_bfloat16 *asrc[2], *bsrc[2];
#pragma unroll
    for (int q = 0; q < 2; ++q) {
        int slot = q*256 + tid;
        int r = slot >> 2, p = slot & 3;
        int c = p ^ ((r >> 1) & 3);
        int rr  = min(t0 + r, ce - 1);
        asrc[q] = xb + (size_t)gtok[base + rr] * HID_ + c*8;
        int q2 = r >> 5, s = r & 31;
        int grow = (q2 & 1) ? (FFN_ + n0 + (q2>>1)*32 + s)
                            : (       n0 + (q2>>1)*32 + s);
        bsrc[q] = w1e + (size_t)grow * HID_ + c*8;
    }

    auto STAGE = [&](int b, int k0) {
#pragma unroll
        for (int q = 0; q < 2; ++q)
            __builtin_amdgcn_global_load_lds((GVOID*)(asrc[q] + k0),
                (LVOID*)(&As[b][(q*256 + wid*64)*8]), 16, 0, 0);
#pragma unroll
        for (int q = 0; q < 2; ++q)
            __builtin_amdgcn_global_load_lds((GVOID*)(bsrc[q] + k0),
                (LVOID*)(&Bs[b][(q*256 + wid*64)*8]), 16, 0, 0);
    };

    f32x4 acc[4][4];
#pragma unroll
    for (int m = 0; m < 4; ++m)
#pragma unroll
        for (int n = 0; n < 4; ++n) acc[m][n] = (f32x4){0.f,0.f,0.f,0.f};

    const int cf = lane >> 4;
    auto COMPUTE = [&](int cb) {
        bf16x8 af[4], bfr[4];
#pragma unroll
        for (int m = 0; m < 4; ++m) {
            int r = wm*64 + m*16 + (lane & 15);
            int sw = cf ^ ((r >> 1) & 3);
            af[m] = *(bf16x8*)&As[cb][r*32 + sw*8];
        }
#pragma unroll
        for (int n = 0; n < 4; ++n) {
            int r = wn*64 + n*16 + (lane & 15);
            int sw = cf ^ ((r >> 1) & 3);
            bfr[n] = *(bf16x8*)&Bs[cb][r*32 + sw*8];
        }
        __builtin_amdgcn_s_setprio(1);
#pragma unroll
        for (int m = 0; m < 4; ++m)
#pragma unroll
            for (int n = 0; n < 4; ++n)
                acc[m][n] = __builtin_amdgcn_mfma_f32_16x16x32_bf16(
                    af[m], bfr[n], acc[m][n], 0, 0, 0);
        __builtin_amdgcn_s_setprio(0);
    };

    const int NT = HID_/32;   // 32
    STAGE(0, 0);
    STAGE(1, 32);
    VMCNT4;
    __builtin_amdgcn_s_barrier();

    int cb = 0;
    for (int t = 0; t < NT-2; ++t) {
        int sb = cb + 2; if (sb >= 3) sb -= 3;
        STAGE(sb, (t+2)*32);
        COMPUTE(cb);
        VMCNT4;                         // tile t+1 landed; t+2 stays in flight
        __builtin_amdgcn_s_barrier();
        if (++cb == 3) cb = 0;
    }
    COMPUTE(cb);                        // t = NT-2
    VMCNT0;
    __builtin_amdgcn_s_barrier();
    if (++cb == 3) cb = 0;
    COMPUTE(cb);                        // t = NT-1

    // Epilogue: fused SiLU(gate)*up -> h (bf16)
    const float* w1be = w1b + e*2*FFN_;
#pragma unroll
    for (int n = 0; n < 2; ++n) {
        int col = n0 + wn*32 + n*16 + (lane & 15);
        float bg = w1be[col];
        float bu = w1be[FFN_ + col];
#pragma unroll
        for (int m = 0; m < 4; ++m) {
            int rb2 = t0 + wm*64 + m*16 + (lane >> 4)*4;
#pragma unroll
            for (int i = 0; i < 4; ++i) {
                int t = rb2 + i;
                if (t < ce) {
                    float g = acc[m][n][i]   + bg;
                    float u = acc[m][n+2][i] + bu;
                    float hv = (g / (1.f + __expf(-g))) * u;
                    h[(size_t)(base + t)*FFN_ + col] = __float2bfloat16(hv);
                }
            }
        }
    }
}

// GEMM2: 128 pairs x 128 hid cols, split-K=2 (z = e + 8*ks). Plain stores
// into dpair[ks] (no init, no atomics); combine sums 4 slices.
__global__ __launch_bounds__(256, 3) void gemm2_kernel(
    const __hip_bfloat16* __restrict__ h, const __hip_bfloat16* __restrict__ w2bf,
    const float* __restrict__ w2b, const float* __restrict__ gwt,
    const int* __restrict__ cnt, const int* __restrict__ off,
    float* __restrict__ dpair)
{
    const int e  = blockIdx.z & 7;
    const int ks = blockIdx.z >> 3;
    const int ce = cnt[e];
    const int t0 = blockIdx.y * 128;
    if (t0 >= ce) return;
    const int n0    = blockIdx.x * 128;
    const int base  = off[e];
    const int kbase = ks * (FFN_/2);
    const __hip_bfloat16* w2e = w2bf + (size_t)e * HID_ * FFN_;

    __shared__ __align__(16) __hip_bfloat16 As[3][128*32];
    __shared__ __align__(16) __hip_bfloat16 Bs[3][128*32];

    const int tid  = threadIdx.x;
    const int lane = tid & 63;
    const int wid  = tid >> 6;
    const int wm   = wid >> 1;
    const int wn   = wid & 1;

    const __hip_bfloat16 *asrc[2], *bsrc[2];
#pragma unroll
    for (int q = 0; q < 2; ++q) {
        int slot = q*256 + tid;
        int r = slot >> 2, p = slot & 3;
        int c = p ^ ((r >> 1) & 3);
        int rr = min(t0 + r, ce - 1);
        asrc[q] = h   + (size_t)(base + rr) * FFN_ + kbase + c*8;
        bsrc[q] = w2e + (size_t)(n0 + r)    * FFN_ + kbase + c*8;
    }

    auto STAGE = [&](int b, int k0) {
#pragma unroll
        for (int q = 0; q < 2; ++q)
            __builtin_amdgcn_global_load_lds((GVOID*)(asrc[q] + k0),
                (LVOID*)(&As[b][(q*256 + wid*64)*8]), 16, 0, 0);
#pragma unroll
        for (int q = 0; q < 2; ++q)
            __builtin_amdgcn_global_load_lds((GVOID*)(bsrc[q] + k0),
                (LVOID*)(&Bs[b][(q*256 + wid*64)*8]), 16, 0, 0);
    };

    f32x4 acc[4][4];
#pragma unroll
    for (int m = 0; m < 4; ++m)
#pragma unroll
        for (int n = 0; n < 4; ++n) acc[m][n] = (f32x4){0.f,0.f,0.f,0.f};

    const int cf = lane >> 4;
    auto COMPUTE = [&](int cb) {
        bf16x8 af[4], bfr[4];
#pragma unroll
        for (int m = 0; m < 4; ++m) {
            int r = wm*64 + m*16 + (lane & 15);
            int sw = cf ^ ((r >> 1) & 3);
            af[m] = *(bf16x8*)&As[cb][r*32 + sw*8];
        }
#pragma unroll
        for (int n = 0; n < 4; ++n) {
            int r = wn*64 + n*16 + (lane & 15);
            int sw = cf ^ ((r >> 1) & 3);
            bfr[n] = *(bf16x8*)&Bs[cb][r*32 + sw*8];
        }
        __builtin_amdgcn_s_setprio(1);
#pragma unroll
        for (int m = 0; m < 4; ++m)
#pragma unroll
            for (int n = 0; n < 4; ++n)
                acc[m][n] = __builtin_amdgcn_mfma_f32_16x16x32_bf16(
                    af[m], bfr[n], acc[m][n], 0, 0, 0);
        __builtin_amdgcn_s_setprio(0);
    };

    const int NT = (FFN_/2)/32;   // 32
    STAGE(0, 0);
    STAGE(1, 32);
    VMCNT4;
    __builtin_amdgcn_s_barrier();

    int cb = 0;
    for (int t = 0; t < NT-2; ++t) {
        int sb = cb + 2; if (sb >= 3) sb -= 3;
        STAGE(sb, (t+2)*32);
        COMPUTE(cb);
        VMCNT4;
        __builtin_amdgcn_s_barrier();
        if (++cb == 3) cb = 0;
    }
    COMPUTE(cb);
    VMCNT0;
    __builtin_amdgcn_s_barrier();
    if (++cb == 3) cb = 0;
    COMPUTE(cb);

    const float* w2be = w2b + e*HID_;
    float* dpk = dpair + (size_t)ks * NP_ * HID_;
#pragma unroll
    for (int n = 0; n < 4; ++n) {
        int col = n0 + wn*64 + n*16 + (lane & 15);
        float bias = (ks == 0) ? w2be[col] : 0.f;
#pragma unroll
        for (int m = 0; m < 4; ++m) {
            int rb2 = t0 + wm*64 + m*16 + (lane >> 4)*4;
#pragma unroll
            for (int i = 0; i < 4; ++i) {
                int t = rb2 + i;
                if (t < ce) {
                    int p   = base + t;
                    float w = gwt[p];
                    dpk[(size_t)p*HID_ + col] = w * (acc[m][n][i] + bias);
                }
            }
        }
    }
}

// out[m][c] = d0[p0][c]+d1[p0][c]+d0[p1][c]+d1[p1][c]   (fixed order)
__global__ __launch_bounds__(256) void combine_kernel(
    const float* __restrict__ dpair, const int* __restrict__ pos,
    float* __restrict__ out)
{
    int idx = blockIdx.x * 256 + threadIdx.x;
    int m   = idx >> 8;
    int c4  = (idx & 255) * 4;
    int p0 = pos[2*m], p1 = pos[2*m+1];
    const float* d0 = dpair;
    const float* d1 = dpair + (size_t)NP_ * HID_;
    float4 a0 = *(const float4*)(d0 + (size_t)p0*HID_ + c4);
    float4 a1 = *(const float4*)(d1 + (size_t)p0*HID_ + c4);
    float4 b0 = *(const float4*)(d0 + (size_t)p1*HID_ + c4);
    float4 b1 = *(const float4*)(d1 + (size_t)p1*HID_ + c4);
    float4 o = make_float4((a0.x+a1.x)+(b0.x+b1.x), (a0.y+a1.y)+(b0.y+b1.y),
                           (a0.z+a1.z)+(b0.z+b1.z), (a0.w+a1.w)+(b0.w+b1.w));
    *(float4*)(out + (size_t)m*HID_ + c4) = o;
}

// ===========================================================================
// FALLBACK (proven round-2 structure) — only if ws_size too small for tier2.
// ===========================================================================
__global__ __launch_bounds__(256) void gemm1_rs_kernel(
    const __hip_bfloat16* __restrict__ xb, const float* __restrict__ w1,
    const float* __restrict__ w1b, const int* __restrict__ gtok,
    const int* __restrict__ cnt, const int* __restrict__ off,
    __hip_bfloat16* __restrict__ h)
{
    const int e  = blockIdx.z;
    const int ce = cnt[e];
    const int t0 = blockIdx.y * 128;
    if (t0 >= ce) return;
    const int n0   = blockIdx.x * 64;
    const int base = off[e];
    const float* w1e = w1 + (size_t)e * (2*FFN_) * HID_;

    __shared__ __align__(16) __hip_bfloat16 As[128*64];
    __shared__ __align__(16) __hip_bfloat16 Bs[128*64];

    const int tid  = threadIdx.x;
    const int lane = tid & 63;
    const int wid  = tid >> 6;
    const int wm   = wid >> 1;
    const int wn   = wid & 1;

    const __hip_bfloat16* asrc[4];
#pragma unroll
    for (int q = 0; q < 4; ++q) {
        int slot = q*256 + tid;
        int r = slot >> 3, p = slot & 7;
        int rr  = min(t0 + r, ce - 1);
        int tok = gtok[base + rr];
        int c = p ^ (r & 7);
        asrc[q] = xb + (size_t)tok * HID_ + c*8;
    }

    const int brow = tid >> 1;
    const int hk   = tid & 1;
    const int q2 = brow >> 5, s = brow & 31;
    const int grow = (q2 & 1) ? (FFN_ + n0 + (q2>>1)*32 + s)
                              : (       n0 + (q2>>1)*32 + s);
    const float* bsrc = w1e + (size_t)grow * HID_ + hk*32;

    f32x4 acc[4][4];
#pragma unroll
    for (int m = 0; m < 4; ++m)
#pragma unroll
        for (int n = 0; n < 4; ++n) acc[m][n] = (f32x4){0.f,0.f,0.f,0.f};

    float4 breg[8];
#pragma unroll
    for (int j = 0; j < 8; ++j) breg[j] = *(const float4*)(bsrc + j*4);

    for (int k0 = 0; k0 < HID_; k0 += 64) {
#pragma unroll
        for (int q = 0; q < 4; ++q) {
            __builtin_amdgcn_global_load_lds(
                (GVOID*)(asrc[q] + k0),
                (LVOID*)(&As[(q*256 + wid*64)*8]), 16, 0, 0);
        }
#pragma unroll
        for (int cc = 0; cc < 4; ++cc) {
            union { bf16x8 v; short s8[8]; } u;
            const float* f0 = (const float*)&breg[2*cc];
#pragma unroll
            for (int j = 0; j < 8; ++j) u.s8[j] = f2bf(f0[j]);
            int c = hk*4 + cc, p = c ^ (brow & 7);
            *(bf16x8*)&Bs[brow*64 + p*8] = u.v;
        }
        __syncthreads();

        if (k0 + 64 < HID_) {
#pragma unroll
            for (int j = 0; j < 8; ++j) breg[j] = *(const float4*)(bsrc + (k0+64) + j*4);
        }

        bf16x8 af[4][2], bfr[4][2];
#pragma unroll
        for (int m = 0; m < 4; ++m)
#pragma unroll
            for (int kk = 0; kk < 2; ++kk) {
                int r = wm*64 + m*16 + (lane & 15);
                int c = kk*4 + (lane >> 4), p = c ^ (r & 7);
                af[m][kk] = *(bf16x8*)&As[r*64 + p*8];
            }
#pragma unroll
        for (int n = 0; n < 4; ++n)
#pragma unroll
            for (int kk = 0; kk < 2; ++kk) {
                int r = wn*64 + n*16 + (lane & 15);
                int c = kk*4 + (lane >> 4), p = c ^ (r & 7);
                bfr[n][kk] = *(bf16x8*)&Bs[r*64 + p*8];
            }
#pragma unroll
        for (int kk = 0; kk < 2; ++kk)
#pragma unroll
            for (int m = 0; m < 4; ++m)
#pragma unroll
                for (int n = 0; n < 4; ++n)
                    acc[m][n] = __builtin_amdgcn_mfma_f32_16x16x32_bf16(
                        af[m][kk], bfr[n][kk], acc[m][n], 0, 0, 0);
        __syncthreads();
    }

    const float* w1be = w1b + e*2*FFN_;
#pragma unroll
    for (int n = 0; n < 2; ++n) {
        int col = n0 + wn*32 + n*16 + (lane & 15);
        float bg = w1be[col];
        float bu = w1be[FFN_ + col];
#pragma unroll
        for (int m = 0; m < 4; ++m) {
            int rb2 = t0 + wm*64 + m*16 + (lane >> 4)*4;
#pragma unroll
            for (int i = 0; i < 4; ++i) {
                int t = rb2 + i;
                if (t < ce) {
                    float g = acc[m][n][i]   + bg;
                    float u = acc[m][n+2][i] + bu;
                    float hv = (g / (1.f + __expf(-g))) * u;
                    h[(size_t)(base + t)*FFN_ + col] = __float2bfloat16(hv);
                }
            }
        }
    }
}

__global__ __launch_bounds__(256) void gemm2_rs_kernel(
    const __hip_bfloat16* __restrict__ h, const float* __restrict__ w2,
    const float* __restrict__ w2b, const int* __restrict__ gtok,
    const float* __restrict__ gwt, const int* __restrict__ cnt,
    const int* __restrict__ off, float* __restrict__ out)
{
    const int e  = blockIdx.z;
    const int ce = cnt[e];
    const int t0 = blockIdx.y * 128;
    if (t0 >= ce) return;
    const int n0   = blockIdx.x * 128;
    const int base = off[e];
    const float* w2e = w2 + (size_t)e * HID_ * FFN_;

    __shared__ __align__(16) __hip_bfloat16 As[128*64];
    __shared__ __align__(16) __hip_bfloat16 Bs[128*64];

    const int tid  = threadIdx.x;
    const int lane = tid & 63;
    const int wid  = tid >> 6;
    const int wm   = wid >> 1;
    const int wn   = wid & 1;

    const __hip_bfloat16* asrc[4];
#pragma unroll
    for (int q = 0; q < 4; ++q) {
        int slot = q*256 + tid;
        int r = slot >> 3, p = slot & 7;
        int rr = min(t0 + r, ce - 1);
        int c = p ^ (r & 7);
        asrc[q] = h + (size_t)(base + rr) * FFN_ + c*8;
    }

    const int brow = tid >> 1;
    const int hk   = tid & 1;
    const float* bsrc = w2e + (size_t)(n0 + brow) * FFN_ + hk*32;

    f32x4 acc[4][4];
#pragma unroll
    for (int m = 0; m < 4; ++m)
#pragma unroll
        for (int n = 0; n < 4; ++n) acc[m][n] = (f32x4){0.f,0.f,0.f,0.f};

    float4 breg[8];
#pragma unroll
    for (int j = 0; j < 8; ++j) breg[j] = *(const float4*)(bsrc + j*4);

    for (int k0 = 0; k0 < FFN_; k0 += 64) {
#pragma unroll
        for (int q = 0; q < 4; ++q) {
            __builtin_amdgcn_global_load_lds(
                (GVOID*)(asrc[q] + k0),
                (LVOID*)(&As[(q*256 + wid*64)*8]), 16, 0, 0);
        }
#pragma unroll
        for (int cc = 0; cc < 4; ++cc) {
            union { bf16x8 v; short s8[8]; } u;
            const float* f0 = (const float*)&breg[2*cc];
#pragma unroll
            for (int j = 0; j < 8; ++j) u.s8[j] = f2bf(f0[j]);
            int c = hk*4 + cc, p = c ^ (brow & 7);
            *(bf16x8*)&Bs[brow*64 + p*8] = u.v;
        }
        __syncthreads();

        if (k0 + 64 < FFN_) {
#pragma unroll
            for (int j = 0; j < 8; ++j) breg[j] = *(const float4*)(bsrc + (k0+64) + j*4);
        }

        bf16x8 af[4][2], bfr[4][2];
#pragma unroll
        for (int m = 0; m < 4; ++m)
#pragma unroll
            for (int kk = 0; kk < 2; ++kk) {
                int r = wm*64 + m*16 + (lane & 15);
                int c = kk*4 + (lane >> 4), p = c ^ (r & 7);
                af[m][kk] = *(bf16x8*)&As[r*64 + p*8];
            }
#pragma unroll
        for (int n = 0; n < 4; ++n)
#pragma unroll
            for (int kk = 0; kk < 2; ++kk) {
                int r = wn*64 + n*16 + (lane & 15);
                int c = kk*4 + (lane >> 4), p = c ^ (r & 7);
                bfr[n][kk] = *(bf16x8*)&Bs[r*64 + p*8];
            }
#pragma unroll
        for (int kk = 0; kk < 2; ++kk)
#pragma unroll
            for (int m = 0; m < 4; ++m)
#pragma unroll
                for (int n = 0; n < 4; ++n)
                    acc[m][n] = __builtin_amdgcn_mfma_f32_16x16x32_bf16(
                        af[m][kk], bfr[n][kk], acc[m][n], 0, 0, 0);
        __syncthreads();
    }

    const float* w2be = w2b + e*HID_;
#pragma unroll
    for (int n = 0; n < 4; ++n) {
        int col = n0 + wn*64 + n*16 + (lane & 15);
        float bias = w2be[col];
#pragma unroll
        for (int m = 0; m < 4; ++m) {
            int rb2 = t0 + wm*64 + m*16 + (lane >> 4)*4;
#pragma unroll
            for (int i = 0; i < 4; ++i) {
                int t = rb2 + i;
                if (t < ce) {
                    int p   = base + t;
                    float w = gwt[p];
                    atomicAdd(&out[(size_t)gtok[p]*HID_ + col], w * (acc[m][n][i] + bias));
                }
            }
        }
    }
}

// ---------------------------------------------------------------------------
extern "C" void kernel_launch(void* const* d_in, const int* in_sizes, int n_in,
                              void* d_out, int out_size, void* d_ws, size_t ws_size,
                              hipStream_t stream)
{
    const float* x   = (const float*)d_in[0];
    const float* rw  = (const float*)d_in[1];
    const float* rb  = (const float*)d_in[2];
    const float* w1  = (const float*)d_in[3];
    const float* w1b = (const float*)d_in[4];
    const float* w2  = (const float*)d_in[5];
    const float* w2b = (const float*)d_in[6];

    float* out      = (float*)d_out;
    float* topk_out = out + (size_t)M_ * HID_;

    char*  ws   = (char*)d_ws;
    int*   ids  = (int*)  (ws);
    float* wts  = (float*)(ws + 16384);
    int*   gtok = (int*)  (ws + 32768);
    float* gwt  = (float*)(ws + 49152);
    int*   cnt  = (int*)  (ws + 65536);
    int*   off  = (int*)  (ws + 65536 + 128);
    int*   fill = (int*)  (ws + 65536 + 256);
    int*   pos  = (int*)  (ws + 98304);

    const size_t MB = 1024*1024;
    __hip_bfloat16* xb    = (__hip_bfloat16*)(ws + 131072);            // 4 MB
    __hip_bfloat16* h     = (__hip_bfloat16*)(ws + 131072 + 4*MB);     // 16 MB
    float*          dpair = (float*)         (ws + 131072 + 20*MB);    // 32 MB (2 slices)
    __hip_bfloat16* w1bf  = (__hip_bfloat16*)(ws + 131072 + 52*MB);    // 64 MB
    __hip_bfloat16* w2bf  = (__hip_bfloat16*)(ws + 131072 + 116*MB);   // 32 MB
    const bool tier2 = (ws_size >= 131072 + 148*MB);

    hipMemsetAsync(cnt, 0, E_ * sizeof(int), stream);

    router_kernel<<<M_, 64, 0, stream>>>(x, rw, rb, ids, wts, cnt, topk_out, xb);
    offsets_kernel<<<1, 64, 0, stream>>>(cnt, off, fill);
    scatter_kernel<<<M_/256, 256, 0, stream>>>(ids, wts, fill, gtok, gwt, pos);

    if (tier2) {
        cvt_w_kernel<<<6144, 256, 0, stream>>>(w1, w2, w1bf, w2bf);

        dim3 g1(FFN_/64, M_/128, E_);        // (32, 16, 8)
        gemm1_kernel<<<g1, 256, 0, stream>>>(xb, w1bf, w1b, gtok, cnt, off, h);

        dim3 g2(HID_/128, M_/128, 2*E_);     // (8, 16, 16) split-K=2
        gemm2_kernel<<<g2, 256, 0, stream>>>(h, w2bf, w2b, gwt, cnt, off, dpair);

        combine_kernel<<<(M_*HID_)/(256*4), 256, 0, stream>>>(dpair, pos, out);
    } else {
        hipMemsetAsync(out, 0, (size_t)M_ * HID_ * sizeof(float), stream);

        dim3 g1(FFN_/64, M_/128, E_);
        gemm1_rs_kernel<<<g1, 256, 0, stream>>>(xb, w1, w1b, gtok, cnt, off, h);

        dim3 g2(HID_/128, M_/128, E_);
        gemm2_rs_kernel<<<g2, 256, 0, stream>>>(h, w2, w2b, gtok, gwt, cnt, off, out);
    }
}

// Round 13
// 237.739 us; speedup vs baseline: 1.3136x; 1.0112x over previous
//
#include <hip/hip_runtime.h>
#include <hip/hip_bf16.h>
#include <math.h>

#define E_    8
#define HID_  1024
#define FFN_  2048
#define M_    2048     // B*S
#define NP_   (M_*2)   // total (token, expert) pairs

typedef __attribute__((ext_vector_type(8))) short bf16x8;
typedef __attribute__((ext_vector_type(8))) short short8v;
typedef __attribute__((ext_vector_type(4))) float f32x4;

typedef const __attribute__((address_space(1))) void GVOID;
typedef __attribute__((address_space(3))) void LVOID;

#define VMCNT4 asm volatile("s_waitcnt vmcnt(4)" ::: "memory")
#define VMCNT0 asm volatile("s_waitcnt vmcnt(0)" ::: "memory")

__device__ __forceinline__ short f2bf(float f) {
    union { __hip_bfloat16 b; short s; } u;
    u.b = __float2bfloat16(f);
    return u.s;
}

// ---------------------------------------------------------------------------
// w1 fp32 -> bf16 only (w2 is converted by gemm1's parasitic blocks).
// 4096 blocks x 1024 chunks (4 chunks of 8 elems per thread, unrolled).
// ---------------------------------------------------------------------------
__global__ __launch_bounds__(256) void cvt_w1_kernel(
    const float* __restrict__ w1, __hip_bfloat16* __restrict__ w1bf)
{
    const float4* src = (const float4*)w1;
    short8v* dst = (short8v*)w1bf;
    size_t cbase = (size_t)blockIdx.x * 1024;

    float4 a[4], b[4];
#pragma unroll
    for (int u = 0; u < 4; ++u) {
        size_t c = cbase + u*256 + threadIdx.x;
        a[u] = src[2*c];
        b[u] = src[2*c + 1];
    }
#pragma unroll
    for (int u = 0; u < 4; ++u) {
        size_t c = cbase + u*256 + threadIdx.x;
        short8v o;
        o[0] = f2bf(a[u].x); o[1] = f2bf(a[u].y);
        o[2] = f2bf(a[u].z); o[3] = f2bf(a[u].w);
        o[4] = f2bf(b[u].x); o[5] = f2bf(b[u].y);
        o[6] = f2bf(b[u].z); o[7] = f2bf(b[u].w);
        dst[c] = o;
    }
}

// ---------------------------------------------------------------------------
// Router (+ fused x->bf16 conversion): one wave per token.  [proven]
// ---------------------------------------------------------------------------
__global__ __launch_bounds__(64) void router_kernel(
    const float* __restrict__ x, const float* __restrict__ rw,
    const float* __restrict__ rb, int* __restrict__ ids,
    float* __restrict__ wts, int* __restrict__ cnt,
    float* __restrict__ topk_out, __hip_bfloat16* __restrict__ xb)
{
    const int m    = blockIdx.x;
    const int lane = threadIdx.x;
    const float4* xm4 = (const float4*)(x + (size_t)m * HID_);

    float4 xv[4];
#pragma unroll
    for (int j = 0; j < 4; ++j) xv[j] = xm4[j*64 + lane];

    short4* xbr = (short4*)(xb + (size_t)m * HID_);
#pragma unroll
    for (int j = 0; j < 4; ++j) {
        short4 o;
        o.x = f2bf(xv[j].x); o.y = f2bf(xv[j].y);
        o.z = f2bf(xv[j].z); o.w = f2bf(xv[j].w);
        xbr[j*64 + lane] = o;
    }

    float lg[E_];
#pragma unroll
    for (int e = 0; e < E_; ++e) {
        const float4* we4 = (const float4*)(rw + e * HID_);
        float s = 0.f;
#pragma unroll
        for (int j = 0; j < 4; ++j) {
            float4 w = we4[j*64 + lane];
            s = fmaf(xv[j].x, w.x, s);
            s = fmaf(xv[j].y, w.y, s);
            s = fmaf(xv[j].z, w.z, s);
            s = fmaf(xv[j].w, w.w, s);
        }
        lg[e] = s;
    }
#pragma unroll
    for (int off = 32; off; off >>= 1)
#pragma unroll
        for (int e = 0; e < E_; ++e) lg[e] += __shfl_xor(lg[e], off);

    if (lane == 0) {
        float l2[E_], p[E_];
        float mx = -1e30f;
#pragma unroll
        for (int e = 0; e < E_; ++e) { l2[e] = lg[e] + rb[e]; mx = fmaxf(mx, l2[e]); }
        float sum = 0.f;
#pragma unroll
        for (int e = 0; e < E_; ++e) { p[e] = expf(l2[e] - mx); sum += p[e]; }
        float inv = 1.f / sum;
#pragma unroll
        for (int e = 0; e < E_; ++e) p[e] *= inv;

        int   i1 = -1, i2 = -1;
        float v1 = -1e30f, v2 = -1e30f;
#pragma unroll
        for (int e = 0; e < E_; ++e) {
            float pe = p[e];
            if (pe > v1)      { v2 = v1; i2 = i1; v1 = pe; i1 = e; }
            else if (pe > v2) { v2 = pe; i2 = e; }
        }
        ids[2*m]   = i1;  ids[2*m+1]   = i2;
        wts[2*m]   = v1;  wts[2*m+1]   = v2;
        topk_out[2*m]   = v1;
        topk_out[2*m+1] = v2;
        atomicAdd(&cnt[i1], 1);
        atomicAdd(&cnt[i2], 1);
    }
}

__global__ void offsets_kernel(const int* __restrict__ cnt,
                               int* __restrict__ off, int* __restrict__ fill)
{
    if (threadIdx.x == 0 && blockIdx.x == 0) {
        int acc = 0;
        for (int e = 0; e < E_; ++e) { off[e] = acc; fill[e] = acc; acc += cnt[e]; }
    }
}

__global__ __launch_bounds__(256) void scatter_kernel(
    const int* __restrict__ ids, const float* __restrict__ wts,
    int* __restrict__ fill, int* __restrict__ gtok, float* __restrict__ gwt,
    int* __restrict__ pos)
{
    int m = blockIdx.x * 256 + threadIdx.x;
    if (m >= M_) return;
#pragma unroll
    for (int s = 0; s < 2; ++s) {
        int e = ids[2*m + s];
        int p = atomicAdd(&fill[e], 1);
        gtok[p] = m;
        gwt[p]  = wts[2*m + s];
        pos[2*m + s] = p;
    }
}

// ===========================================================================
// TIER-2 GEMMs [measured optimum]: 128x128 block, 4 waves of 64x64, BK=32,
// TRIPLE-buffered LDS (48KB), depth-2 prefetch, counted vmcnt(4).
// LDS swizzle: 16B chunk p of row r holds global chunk p ^ ((r>>1)&3).
// gemm1 grid has a 9th z-slice of parasitic blocks (0 LDS) that convert
// w2 fp32 -> bf16 concurrently; gemm2 (next launch) consumes w2bf.
// ===========================================================================

// GEMM1: 128 gathered tokens x 64 h-cols. K = HID = 1024, NT = 32 steps.
__global__ __launch_bounds__(256, 3) void gemm1_kernel(
    const __hip_bfloat16* __restrict__ xb, const __hip_bfloat16* __restrict__ w1bf,
    const float* __restrict__ w1b, const int* __restrict__ gtok,
    const int* __restrict__ cnt, const int* __restrict__ off,
    __hip_bfloat16* __restrict__ h,
    const float* __restrict__ w2, __hip_bfloat16* __restrict__ w2bf)
{
    if (blockIdx.z == 8) {
        // Parasitic w2 conversion: 512 blocks x 4096 chunks (16 chunks/thread).
        int pb = blockIdx.x + 32 * blockIdx.y;            // 0..511
        const float4* src = (const float4*)w2;
        short8v* dst = (short8v*)w2bf;
        size_t cb0 = (size_t)pb * 4096;
        for (int it = 0; it < 4; ++it) {
            size_t cbase = cb0 + it*1024;
            float4 a[4], b[4];
#pragma unroll
            for (int u = 0; u < 4; ++u) {
                size_t c = cbase + u*256 + threadIdx.x;
                a[u] = src[2*c];
                b[u] = src[2*c + 1];
            }
#pragma unroll
            for (int u = 0; u < 4; ++u) {
                size_t c = cbase + u*256 + threadIdx.x;
                short8v o;
                o[0] = f2bf(a[u].x); o[1] = f2bf(a[u].y);
                o[2] = f2bf(a[u].z); o[3] = f2bf(a[u].w);
                o[4] = f2bf(b[u].x); o[5] = f2bf(b[u].y);
                o[6] = f2bf(b[u].z); o[7] = f2bf(b[u].w);
                dst[c] = o;
            }
        }
        return;
    }

    const int e  = blockIdx.z;
    const int ce = cnt[e];
    const int t0 = blockIdx.y * 128;
    if (t0 >= ce) return;
    const int n0   = blockIdx.x * 64;
    const int base = off[e];
    const __hip_bfloat16* w1e = w1bf + (size_t)e * (2*FFN_) * HID_;

    __shared__ __align__(16) __hip_bfloat16 As[3][128*32];
    __shared__ __align__(16) __hip_bfloat16 Bs[3][128*32];

    const int tid  = threadIdx.x;
    const int lane = tid & 63;
    const int wid  = tid >> 6;
    const int wm   = wid >> 1;
    const int wn   = wid & 1;

    const __hip_bfloat16 *asrc[2], *bsrc[2];
#pragma unroll
    for (int q = 0; q < 2; ++q) {
        int slot = q*256 + tid;
        int r = slot >> 2, p = slot & 3;
        int c = p ^ ((r >> 1) & 3);
        int rr  = min(t0 + r, ce - 1);
        asrc[q] = xb + (size_t)gtok[base + rr] * HID_ + c*8;
        int q2 = r >> 5, s = r & 31;
        int grow = (q2 & 1) ? (FFN_ + n0 + (q2>>1)*32 + s)
                            : (       n0 + (q2>>1)*32 + s);
        bsrc[q] = w1e + (size_t)grow * HID_ + c*8;
    }

    auto STAGE = [&](int b, int k0) {
#pragma unroll
        for (int q = 0; q < 2; ++q)
            __builtin_amdgcn_global_load_lds((GVOID*)(asrc[q] + k0),
                (LVOID*)(&As[b][(q*256 + wid*64)*8]), 16, 0, 0);
#pragma unroll
        for (int q = 0; q < 2; ++q)
            __builtin_amdgcn_global_load_lds((GVOID*)(bsrc[q] + k0),
                (LVOID*)(&Bs[b][(q*256 + wid*64)*8]), 16, 0, 0);
    };

    f32x4 acc[4][4];
#pragma unroll
    for (int m = 0; m < 4; ++m)
#pragma unroll
        for (int n = 0; n < 4; ++n) acc[m][n] = (f32x4){0.f,0.f,0.f,0.f};

    const int cf = lane >> 4;
    auto COMPUTE = [&](int cb) {
        bf16x8 af[4], bfr[4];
#pragma unroll
        for (int m = 0; m < 4; ++m) {
            int r = wm*64 + m*16 + (lane & 15);
            int sw = cf ^ ((r >> 1) & 3);
            af[m] = *(bf16x8*)&As[cb][r*32 + sw*8];
        }
#pragma unroll
        for (int n = 0; n < 4; ++n) {
            int r = wn*64 + n*16 + (lane & 15);
            int sw = cf ^ ((r >> 1) & 3);
            bfr[n] = *(bf16x8*)&Bs[cb][r*32 + sw*8];
        }
        __builtin_amdgcn_s_setprio(1);
#pragma unroll
        for (int m = 0; m < 4; ++m)
#pragma unroll
            for (int n = 0; n < 4; ++n)
                acc[m][n] = __builtin_amdgcn_mfma_f32_16x16x32_bf16(
                    af[m], bfr[n], acc[m][n], 0, 0, 0);
        __builtin_amdgcn_s_setprio(0);
    };

    const int NT = HID_/32;   // 32
    STAGE(0, 0);
    STAGE(1, 32);
    VMCNT4;
    __builtin_amdgcn_s_barrier();

    int cb = 0;
    for (int t = 0; t < NT-2; ++t) {
        int sb = cb + 2; if (sb >= 3) sb -= 3;
        STAGE(sb, (t+2)*32);
        COMPUTE(cb);
        VMCNT4;                         // tile t+1 landed; t+2 stays in flight
        __builtin_amdgcn_s_barrier();
        if (++cb == 3) cb = 0;
    }
    COMPUTE(cb);                        // t = NT-2
    VMCNT0;
    __builtin_amdgcn_s_barrier();
    if (++cb == 3) cb = 0;
    COMPUTE(cb);                        // t = NT-1

    // Epilogue: fused SiLU(gate)*up -> h (bf16)
    const float* w1be = w1b + e*2*FFN_;
#pragma unroll
    for (int n = 0; n < 2; ++n) {
        int col = n0 + wn*32 + n*16 + (lane & 15);
        float bg = w1be[col];
        float bu = w1be[FFN_ + col];
#pragma unroll
        for (int m = 0; m < 4; ++m) {
            int rb2 = t0 + wm*64 + m*16 + (lane >> 4)*4;
#pragma unroll
            for (int i = 0; i < 4; ++i) {
                int t = rb2 + i;
                if (t < ce) {
                    float g = acc[m][n][i]   + bg;
                    float u = acc[m][n+2][i] + bu;
                    float hv = (g / (1.f + __expf(-g))) * u;
                    h[(size_t)(base + t)*FFN_ + col] = __float2bfloat16(hv);
                }
            }
        }
    }
}

// GEMM2: 128 pairs x 128 hid cols, split-K=2 (z = e + 8*ks). Plain stores
// into dpair[ks] (no init, no atomics); combine sums 4 slices.
__global__ __launch_bounds__(256, 3) void gemm2_kernel(
    const __hip_bfloat16* __restrict__ h, const __hip_bfloat16* __restrict__ w2bf,
    const float* __restrict__ w2b, const float* __restrict__ gwt,
    const int* __restrict__ cnt, const int* __restrict__ off,
    float* __restrict__ dpair)
{
    const int e  = blockIdx.z & 7;
    const int ks = blockIdx.z >> 3;
    const int ce = cnt[e];
    const int t0 = blockIdx.y * 128;
    if (t0 >= ce) return;
    const int n0    = blockIdx.x * 128;
    const int base  = off[e];
    const int kbase = ks * (FFN_/2);
    const __hip_bfloat16* w2e = w2bf + (size_t)e * HID_ * FFN_;

    __shared__ __align__(16) __hip_bfloat16 As[3][128*32];
    __shared__ __align__(16) __hip_bfloat16 Bs[3][128*32];

    const int tid  = threadIdx.x;
    const int lane = tid & 63;
    const int wid  = tid >> 6;
    const int wm   = wid >> 1;
    const int wn   = wid & 1;

    const __hip_bfloat16 *asrc[2], *bsrc[2];
#pragma unroll
    for (int q = 0; q < 2; ++q) {
        int slot = q*256 + tid;
        int r = slot >> 2, p = slot & 3;
        int c = p ^ ((r >> 1) & 3);
        int rr = min(t0 + r, ce - 1);
        asrc[q] = h   + (size_t)(base + rr) * FFN_ + kbase + c*8;
        bsrc[q] = w2e + (size_t)(n0 + r)    * FFN_ + kbase + c*8;
    }

    auto STAGE = [&](int b, int k0) {
#pragma unroll
        for (int q = 0; q < 2; ++q)
            __builtin_amdgcn_global_load_lds((GVOID*)(asrc[q] + k0),
                (LVOID*)(&As[b][(q*256 + wid*64)*8]), 16, 0, 0);
#pragma unroll
        for (int q = 0; q < 2; ++q)
            __builtin_amdgcn_global_load_lds((GVOID*)(bsrc[q] + k0),
                (LVOID*)(&Bs[b][(q*256 + wid*64)*8]), 16, 0, 0);
    };

    f32x4 acc[4][4];
#pragma unroll
    for (int m = 0; m < 4; ++m)
#pragma unroll
        for (int n = 0; n < 4; ++n) acc[m][n] = (f32x4){0.f,0.f,0.f,0.f};

    const int cf = lane >> 4;
    auto COMPUTE = [&](int cb) {
        bf16x8 af[4], bfr[4];
#pragma unroll
        for (int m = 0; m < 4; ++m) {
            int r = wm*64 + m*16 + (lane & 15);
            int sw = cf ^ ((r >> 1) & 3);
            af[m] = *(bf16x8*)&As[cb][r*32 + sw*8];
        }
#pragma unroll
        for (int n = 0; n < 4; ++n) {
            int r = wn*64 + n*16 + (lane & 15);
            int sw = cf ^ ((r >> 1) & 3);
            bfr[n] = *(bf16x8*)&Bs[cb][r*32 + sw*8];
        }
        __builtin_amdgcn_s_setprio(1);
#pragma unroll
        for (int m = 0; m < 4; ++m)
#pragma unroll
            for (int n = 0; n < 4; ++n)
                acc[m][n] = __builtin_amdgcn_mfma_f32_16x16x32_bf16(
                    af[m], bfr[n], acc[m][n], 0, 0, 0);
        __builtin_amdgcn_s_setprio(0);
    };

    const int NT = (FFN_/2)/32;   // 32
    STAGE(0, 0);
    STAGE(1, 32);
    VMCNT4;
    __builtin_amdgcn_s_barrier();

    int cb = 0;
    for (int t = 0; t < NT-2; ++t) {
        int sb = cb + 2; if (sb >= 3) sb -= 3;
        STAGE(sb, (t+2)*32);
        COMPUTE(cb);
        VMCNT4;
        __builtin_amdgcn_s_barrier();
        if (++cb == 3) cb = 0;
    }
    COMPUTE(cb);
    VMCNT0;
    __builtin_amdgcn_s_barrier();
    if (++cb == 3) cb = 0;
    COMPUTE(cb);

    const float* w2be = w2b + e*HID_;
    float* dpk = dpair + (size_t)ks * NP_ * HID_;
#pragma unroll
    for (int n = 0; n < 4; ++n) {
        int col = n0 + wn*64 + n*16 + (lane & 15);
        float bias = (ks == 0) ? w2be[col] : 0.f;
#pragma unroll
        for (int m = 0; m < 4; ++m) {
            int rb2 = t0 + wm*64 + m*16 + (lane >> 4)*4;
#pragma unroll
            for (int i = 0; i < 4; ++i) {
                int t = rb2 + i;
                if (t < ce) {
                    int p   = base + t;
                    float w = gwt[p];
                    dpk[(size_t)p*HID_ + col] = w * (acc[m][n][i] + bias);
                }
            }
        }
    }
}

// out[m][c] = d0[p0][c]+d1[p0][c]+d0[p1][c]+d1[p1][c]   (fixed order)
__global__ __launch_bounds__(256) void combine_kernel(
    const float* __restrict__ dpair, const int* __restrict__ pos,
    float* __restrict__ out)
{
    int idx = blockIdx.x * 256 + threadIdx.x;
    int m   = idx >> 8;
    int c4  = (idx & 255) * 4;
    int p0 = pos[2*m], p1 = pos[2*m+1];
    const float* d0 = dpair;
    const float* d1 = dpair + (size_t)NP_ * HID_;
    float4 a0 = *(const float4*)(d0 + (size_t)p0*HID_ + c4);
    float4 a1 = *(const float4*)(d1 + (size_t)p0*HID_ + c4);
    float4 b0 = *(const float4*)(d0 + (size_t)p1*HID_ + c4);
    float4 b1 = *(const float4*)(d1 + (size_t)p1*HID_ + c4);
    float4 o = make_float4((a0.x+a1.x)+(b0.x+b1.x), (a0.y+a1.y)+(b0.y+b1.y),
                           (a0.z+a1.z)+(b0.z+b1.z), (a0.w+a1.w)+(b0.w+b1.w));
    *(float4*)(out + (size_t)m*HID_ + c4) = o;
}

// ===========================================================================
// FALLBACK (proven round-2 structure) — only if ws_size too small for tier2.
// ===========================================================================
__global__ __launch_bounds__(256) void gemm1_rs_kernel(
    const __hip_bfloat16* __restrict__ xb, const float* __restrict__ w1,
    const float* __restrict__ w1b, const int* __restrict__ gtok,
    const int* __restrict__ cnt, const int* __restrict__ off,
    __hip_bfloat16* __restrict__ h)
{
    const int e  = blockIdx.z;
    const int ce = cnt[e];
    const int t0 = blockIdx.y * 128;
    if (t0 >= ce) return;
    const int n0   = blockIdx.x * 64;
    const int base = off[e];
    const float* w1e = w1 + (size_t)e * (2*FFN_) * HID_;

    __shared__ __align__(16) __hip_bfloat16 As[128*64];
    __shared__ __align__(16) __hip_bfloat16 Bs[128*64];

    const int tid  = threadIdx.x;
    const int lane = tid & 63;
    const int wid  = tid >> 6;
    const int wm   = wid >> 1;
    const int wn   = wid & 1;

    const __hip_bfloat16* asrc[4];
#pragma unroll
    for (int q = 0; q < 4; ++q) {
        int slot = q*256 + tid;
        int r = slot >> 3, p = slot & 7;
        int rr  = min(t0 + r, ce - 1);
        int tok = gtok[base + rr];
        int c = p ^ (r & 7);
        asrc[q] = xb + (size_t)tok * HID_ + c*8;
    }

    const int brow = tid >> 1;
    const int hk   = tid & 1;
    const int q2 = brow >> 5, s = brow & 31;
    const int grow = (q2 & 1) ? (FFN_ + n0 + (q2>>1)*32 + s)
                              : (       n0 + (q2>>1)*32 + s);
    const float* bsrc = w1e + (size_t)grow * HID_ + hk*32;

    f32x4 acc[4][4];
#pragma unroll
    for (int m = 0; m < 4; ++m)
#pragma unroll
        for (int n = 0; n < 4; ++n) acc[m][n] = (f32x4){0.f,0.f,0.f,0.f};

    float4 breg[8];
#pragma unroll
    for (int j = 0; j < 8; ++j) breg[j] = *(const float4*)(bsrc + j*4);

    for (int k0 = 0; k0 < HID_; k0 += 64) {
#pragma unroll
        for (int q = 0; q < 4; ++q) {
            __builtin_amdgcn_global_load_lds(
                (GVOID*)(asrc[q] + k0),
                (LVOID*)(&As[(q*256 + wid*64)*8]), 16, 0, 0);
        }
#pragma unroll
        for (int cc = 0; cc < 4; ++cc) {
            union { bf16x8 v; short s8[8]; } u;
            const float* f0 = (const float*)&breg[2*cc];
#pragma unroll
            for (int j = 0; j < 8; ++j) u.s8[j] = f2bf(f0[j]);
            int c = hk*4 + cc, p = c ^ (brow & 7);
            *(bf16x8*)&Bs[brow*64 + p*8] = u.v;
        }
        __syncthreads();

        if (k0 + 64 < HID_) {
#pragma unroll
            for (int j = 0; j < 8; ++j) breg[j] = *(const float4*)(bsrc + (k0+64) + j*4);
        }

        bf16x8 af[4][2], bfr[4][2];
#pragma unroll
        for (int m = 0; m < 4; ++m)
#pragma unroll
            for (int kk = 0; kk < 2; ++kk) {
                int r = wm*64 + m*16 + (lane & 15);
                int c = kk*4 + (lane >> 4), p = c ^ (r & 7);
                af[m][kk] = *(bf16x8*)&As[r*64 + p*8];
            }
#pragma unroll
        for (int n = 0; n < 4; ++n)
#pragma unroll
            for (int kk = 0; kk < 2; ++kk) {
                int r = wn*64 + n*16 + (lane & 15);
                int c = kk*4 + (lane >> 4), p = c ^ (r & 7);
                bfr[n][kk] = *(bf16x8*)&Bs[r*64 + p*8];
            }
#pragma unroll
        for (int kk = 0; kk < 2; ++kk)
#pragma unroll
            for (int m = 0; m < 4; ++m)
#pragma unroll
                for (int n = 0; n < 4; ++n)
                    acc[m][n] = __builtin_amdgcn_mfma_f32_16x16x32_bf16(
                        af[m][kk], bfr[n][kk], acc[m][n], 0, 0, 0);
        __syncthreads();
    }

    const float* w1be = w1b + e*2*FFN_;
#pragma unroll
    for (int n = 0; n < 2; ++n) {
        int col = n0 + wn*32 + n*16 + (lane & 15);
        float bg = w1be[col];
        float bu = w1be[FFN_ + col];
#pragma unroll
        for (int m = 0; m < 4; ++m) {
            int rb2 = t0 + wm*64 + m*16 + (lane >> 4)*4;
#pragma unroll
            for (int i = 0; i < 4; ++i) {
                int t = rb2 + i;
                if (t < ce) {
                    float g = acc[m][n][i]   + bg;
                    float u = acc[m][n+2][i] + bu;
                    float hv = (g / (1.f + __expf(-g))) * u;
                    h[(size_t)(base + t)*FFN_ + col] = __float2bfloat16(hv);
                }
            }
        }
    }
}

__global__ __launch_bounds__(256) void gemm2_rs_kernel(
    const __hip_bfloat16* __restrict__ h, const float* __restrict__ w2,
    const float* __restrict__ w2b, const int* __restrict__ gtok,
    const float* __restrict__ gwt, const int* __restrict__ cnt,
    const int* __restrict__ off, float* __restrict__ out)
{
    const int e  = blockIdx.z;
    const int ce = cnt[e];
    const int t0 = blockIdx.y * 128;
    if (t0 >= ce) return;
    const int n0   = blockIdx.x * 128;
    const int base = off[e];
    const float* w2e = w2 + (size_t)e * HID_ * FFN_;

    __shared__ __align__(16) __hip_bfloat16 As[128*64];
    __shared__ __align__(16) __hip_bfloat16 Bs[128*64];

    const int tid  = threadIdx.x;
    const int lane = tid & 63;
    const int wid  = tid >> 6;
    const int wm   = wid >> 1;
    const int wn   = wid & 1;

    const __hip_bfloat16* asrc[4];
#pragma unroll
    for (int q = 0; q < 4; ++q) {
        int slot = q*256 + tid;
        int r = slot >> 3, p = slot & 7;
        int rr = min(t0 + r, ce - 1);
        int c = p ^ (r & 7);
        asrc[q] = h + (size_t)(base + rr) * FFN_ + c*8;
    }

    const int brow = tid >> 1;
    const int hk   = tid & 1;
    const float* bsrc = w2e + (size_t)(n0 + brow) * FFN_ + hk*32;

    f32x4 acc[4][4];
#pragma unroll
    for (int m = 0; m < 4; ++m)
#pragma unroll
        for (int n = 0; n < 4; ++n) acc[m][n] = (f32x4){0.f,0.f,0.f,0.f};

    float4 breg[8];
#pragma unroll
    for (int j = 0; j < 8; ++j) breg[j] = *(const float4*)(bsrc + j*4);

    for (int k0 = 0; k0 < FFN_; k0 += 64) {
#pragma unroll
        for (int q = 0; q < 4; ++q) {
            __builtin_amdgcn_global_load_lds(
                (GVOID*)(asrc[q] + k0),
                (LVOID*)(&As[(q*256 + wid*64)*8]), 16, 0, 0);
        }
#pragma unroll
        for (int cc = 0; cc < 4; ++cc) {
            union { bf16x8 v; short s8[8]; } u;
            const float* f0 = (const float*)&breg[2*cc];
#pragma unroll
            for (int j = 0; j < 8; ++j) u.s8[j] = f2bf(f0[j]);
            int c = hk*4 + cc, p = c ^ (brow & 7);
            *(bf16x8*)&Bs[brow*64 + p*8] = u.v;
        }
        __syncthreads();

        if (k0 + 64 < FFN_) {
#pragma unroll
            for (int j = 0; j < 8; ++j) breg[j] = *(const float4*)(bsrc + (k0+64) + j*4);
        }

        bf16x8 af[4][2], bfr[4][2];
#pragma unroll
        for (int m = 0; m < 4; ++m)
#pragma unroll
            for (int kk = 0; kk < 2; ++kk) {
                int r = wm*64 + m*16 + (lane & 15);
                int c = kk*4 + (lane >> 4), p = c ^ (r & 7);
                af[m][kk] = *(bf16x8*)&As[r*64 + p*8];
            }
#pragma unroll
        for (int n = 0; n < 4; ++n)
#pragma unroll
            for (int kk = 0; kk < 2; ++kk) {
                int r = wn*64 + n*16 + (lane & 15);
                int c = kk*4 + (lane >> 4), p = c ^ (r & 7);
                bfr[n][kk] = *(bf16x8*)&Bs[r*64 + p*8];
            }
#pragma unroll
        for (int kk = 0; kk < 2; ++kk)
#pragma unroll
            for (int m = 0; m < 4; ++m)
#pragma unroll
                for (int n = 0; n < 4; ++n)
                    acc[m][n] = __builtin_amdgcn_mfma_f32_16x16x32_bf16(
                        af[m][kk], bfr[n][kk], acc[m][n], 0, 0, 0);
        __syncthreads();
    }

    const float* w2be = w2b + e*HID_;
#pragma unroll
    for (int n = 0; n < 4; ++n) {
        int col = n0 + wn*64 + n*16 + (lane & 15);
        float bias = w2be[col];
#pragma unroll
        for (int m = 0; m < 4; ++m) {
            int rb2 = t0 + wm*64 + m*16 + (lane >> 4)*4;
#pragma unroll
            for (int i = 0; i < 4; ++i) {
                int t = rb2 + i;
                if (t < ce) {
                    int p   = base + t;
                    float w = gwt[p];
                    atomicAdd(&out[(size_t)gtok[p]*HID_ + col], w * (acc[m][n][i] + bias));
                }
            }
        }
    }
}

// ---------------------------------------------------------------------------
extern "C" void kernel_launch(void* const* d_in, const int* in_sizes, int n_in,
                              void* d_out, int out_size, void* d_ws, size_t ws_size,
                              hipStream_t stream)
{
    const float* x   = (const float*)d_in[0];
    const float* rw  = (const float*)d_in[1];
    const float* rb  = (const float*)d_in[2];
    const float* w1  = (const float*)d_in[3];
    const float* w1b = (const float*)d_in[4];
    const float* w2  = (const float*)d_in[5];
    const float* w2b = (const float*)d_in[6];

    float* out      = (float*)d_out;
    float* topk_out = out + (size_t)M_ * HID_;

    char*  ws   = (char*)d_ws;
    int*   ids  = (int*)  (ws);
    float* wts  = (float*)(ws + 16384);
    int*   gtok = (int*)  (ws + 32768);
    float* gwt  = (float*)(ws + 49152);
    int*   cnt  = (int*)  (ws + 65536);
    int*   off  = (int*)  (ws + 65536 + 128);
    int*   fill = (int*)  (ws + 65536 + 256);
    int*   pos  = (int*)  (ws + 98304);

    const size_t MB = 1024*1024;
    __hip_bfloat16* xb    = (__hip_bfloat16*)(ws + 131072);            // 4 MB
    __hip_bfloat16* h     = (__hip_bfloat16*)(ws + 131072 + 4*MB);     // 16 MB
    float*          dpair = (float*)         (ws + 131072 + 20*MB);    // 32 MB (2 slices)
    __hip_bfloat16* w1bf  = (__hip_bfloat16*)(ws + 131072 + 52*MB);    // 64 MB
    __hip_bfloat16* w2bf  = (__hip_bfloat16*)(ws + 131072 + 116*MB);   // 32 MB
    const bool tier2 = (ws_size >= 131072 + 148*MB);

    hipMemsetAsync(cnt, 0, E_ * sizeof(int), stream);

    router_kernel<<<M_, 64, 0, stream>>>(x, rw, rb, ids, wts, cnt, topk_out, xb);
    offsets_kernel<<<1, 64, 0, stream>>>(cnt, off, fill);
    scatter_kernel<<<M_/256, 256, 0, stream>>>(ids, wts, fill, gtok, gwt, pos);

    if (tier2) {
        cvt_w1_kernel<<<4096, 256, 0, stream>>>(w1, w1bf);

        dim3 g1(FFN_/64, M_/128, E_ + 1);    // (32, 16, 9): z=8 converts w2
        gemm1_kernel<<<g1, 256, 0, stream>>>(xb, w1bf, w1b, gtok, cnt, off, h,
                                             w2, w2bf);

        dim3 g2(HID_/128, M_/128, 2*E_);     // (8, 16, 16) split-K=2
        gemm2_kernel<<<g2, 256, 0, stream>>>(h, w2bf, w2b, gwt, cnt, off, dpair);

        combine_kernel<<<(M_*HID_)/(256*4), 256, 0, stream>>>(dpair, pos, out);
    } else {
        hipMemsetAsync(out, 0, (size_t)M_ * HID_ * sizeof(float), stream);

        dim3 g1(FFN_/64, M_/128, E_);
        gemm1_rs_kernel<<<g1, 256, 0, stream>>>(xb, w1, w1b, gtok, cnt, off, h);

        dim3 g2(HID_/128, M_/128, E_);
        gemm2_rs_kernel<<<g2, 256, 0, stream>>>(h, w2, w2b, gtok, gwt, cnt, off, out);
    }
}

// Round 14
// 229.691 us; speedup vs baseline: 1.3597x; 1.0350x over previous
//
#include <hip/hip_runtime.h>
#include <hip/hip_bf16.h>
#include <math.h>

#define E_    8
#define HID_  1024
#define FFN_  2048
#define M_    2048     // B*S
#define NP_   (M_*2)   // total (token, expert) pairs

typedef __attribute__((ext_vector_type(8))) short bf16x8;
typedef __attribute__((ext_vector_type(4))) float f32x4;
typedef __attribute__((ext_vector_type(4))) int   i32x4;

typedef const __attribute__((address_space(1))) void GVOID;
typedef __attribute__((address_space(3))) void LVOID;

__device__ __forceinline__ short f2bf(float f) {
    union { __hip_bfloat16 b; short s; } u;
    u.b = __float2bfloat16(f);
    return u.s;
}

// pack 8 consecutive-k fp32 (two f32x4) into one bf16x8 fragment (RNE)
__device__ __forceinline__ bf16x8 pk8(f32x4 lo, f32x4 hi) {
    unsigned u0, u1, u2, u3;
    asm("v_cvt_pk_bf16_f32 %0, %1, %2" : "=v"(u0) : "v"(lo.x), "v"(lo.y));
    asm("v_cvt_pk_bf16_f32 %0, %1, %2" : "=v"(u1) : "v"(lo.z), "v"(lo.w));
    asm("v_cvt_pk_bf16_f32 %0, %1, %2" : "=v"(u2) : "v"(hi.x), "v"(hi.y));
    asm("v_cvt_pk_bf16_f32 %0, %1, %2" : "=v"(u3) : "v"(hi.z), "v"(hi.w));
    union { i32x4 i; bf16x8 b; } r;
    r.i = (i32x4){(int)u0, (int)u1, (int)u2, (int)u3};
    return r.b;
}

// ---------------------------------------------------------------------------
// Router (+ fused x->bf16 conversion): one wave per token.  [proven]
// ---------------------------------------------------------------------------
__global__ __launch_bounds__(64) void router_kernel(
    const float* __restrict__ x, const float* __restrict__ rw,
    const float* __restrict__ rb, int* __restrict__ ids,
    float* __restrict__ wts, int* __restrict__ cnt,
    float* __restrict__ topk_out, __hip_bfloat16* __restrict__ xb)
{
    const int m    = blockIdx.x;
    const int lane = threadIdx.x;
    const float4* xm4 = (const float4*)(x + (size_t)m * HID_);

    float4 xv[4];
#pragma unroll
    for (int j = 0; j < 4; ++j) xv[j] = xm4[j*64 + lane];

    short4* xbr = (short4*)(xb + (size_t)m * HID_);
#pragma unroll
    for (int j = 0; j < 4; ++j) {
        short4 o;
        o.x = f2bf(xv[j].x); o.y = f2bf(xv[j].y);
        o.z = f2bf(xv[j].z); o.w = f2bf(xv[j].w);
        xbr[j*64 + lane] = o;
    }

    float lg[E_];
#pragma unroll
    for (int e = 0; e < E_; ++e) {
        const float4* we4 = (const float4*)(rw + e * HID_);
        float s = 0.f;
#pragma unroll
        for (int j = 0; j < 4; ++j) {
            float4 w = we4[j*64 + lane];
            s = fmaf(xv[j].x, w.x, s);
            s = fmaf(xv[j].y, w.y, s);
            s = fmaf(xv[j].z, w.z, s);
            s = fmaf(xv[j].w, w.w, s);
        }
        lg[e] = s;
    }
#pragma unroll
    for (int off = 32; off; off >>= 1)
#pragma unroll
        for (int e = 0; e < E_; ++e) lg[e] += __shfl_xor(lg[e], off);

    if (lane == 0) {
        float l2[E_], p[E_];
        float mx = -1e30f;
#pragma unroll
        for (int e = 0; e < E_; ++e) { l2[e] = lg[e] + rb[e]; mx = fmaxf(mx, l2[e]); }
        float sum = 0.f;
#pragma unroll
        for (int e = 0; e < E_; ++e) { p[e] = expf(l2[e] - mx); sum += p[e]; }
        float inv = 1.f / sum;
#pragma unroll
        for (int e = 0; e < E_; ++e) p[e] *= inv;

        int   i1 = -1, i2 = -1;
        float v1 = -1e30f, v2 = -1e30f;
#pragma unroll
        for (int e = 0; e < E_; ++e) {
            float pe = p[e];
            if (pe > v1)      { v2 = v1; i2 = i1; v1 = pe; i1 = e; }
            else if (pe > v2) { v2 = pe; i2 = e; }
        }
        ids[2*m]   = i1;  ids[2*m+1]   = i2;
        wts[2*m]   = v1;  wts[2*m+1]   = v2;
        topk_out[2*m]   = v1;
        topk_out[2*m+1] = v2;
        atomicAdd(&cnt[i1], 1);
        atomicAdd(&cnt[i2], 1);
    }
}

__global__ void offsets_kernel(const int* __restrict__ cnt,
                               int* __restrict__ off, int* __restrict__ fill)
{
    if (threadIdx.x == 0 && blockIdx.x == 0) {
        int acc = 0;
        for (int e = 0; e < E_; ++e) { off[e] = acc; fill[e] = acc; acc += cnt[e]; }
    }
}

__global__ __launch_bounds__(256) void scatter_kernel(
    const int* __restrict__ ids, const float* __restrict__ wts,
    int* __restrict__ fill, int* __restrict__ gtok, float* __restrict__ gwt,
    int* __restrict__ pos)
{
    int m = blockIdx.x * 256 + threadIdx.x;
    if (m >= M_) return;
#pragma unroll
    for (int s = 0; s < 2; ++s) {
        int e = ids[2*m + s];
        int p = atomicAdd(&fill[e], 1);
        gtok[p] = m;
        gwt[p]  = wts[2*m + s];
        pos[2*m + s] = p;
    }
}

// ===========================================================================
// TIER-2 GEMMs, NO weight pre-conversion: A (bf16) staged as before; B staged
// as RAW FP32 via global_load_lds into a 16KB fp32 LDS tile, converted to
// bf16 fragments at read time with v_cvt_pk_bf16_f32 (hidden under MFMA on
// the VALU pipe). Double-buffered (48KB total -> 3 blocks/CU), proven 2-phase
// schedule: STAGE(t+1) -> COMPUTE(t) -> __syncthreads (implicit vmcnt drain).
// A swizzle: 4 chunks/row, c = p ^ ((r>>1)&3).
// B swizzle: 8 chunks/row, c = p ^ (r&7)  (2-way bank alias max on read).
// ===========================================================================

// GEMM1: 128 gathered tokens x 64 h-cols. K = HID = 1024, NT = 32 steps.
__global__ __launch_bounds__(256, 3) void gemm1_kernel(
    const __hip_bfloat16* __restrict__ xb, const float* __restrict__ w1,
    const float* __restrict__ w1b, const int* __restrict__ gtok,
    const int* __restrict__ cnt, const int* __restrict__ off,
    __hip_bfloat16* __restrict__ h)
{
    const int e  = blockIdx.z;
    const int ce = cnt[e];
    const int t0 = blockIdx.y * 128;
    if (t0 >= ce) return;
    const int n0   = blockIdx.x * 64;
    const int base = off[e];
    const float* w1e = w1 + (size_t)e * (2*FFN_) * HID_;

    __shared__ __align__(16) __hip_bfloat16 As[2][128*32];   // 8KB each
    __shared__ __align__(16) float          Bsf[2][128*32];  // 16KB each

    const int tid  = threadIdx.x;
    const int lane = tid & 63;
    const int wid  = tid >> 6;
    const int wm   = wid >> 1;
    const int wn   = wid & 1;
    const int cf   = lane >> 4;

    // A stage sources (2 x 16B per thread), bf16 4-chunk swizzle
    const __hip_bfloat16* asrc[2];
#pragma unroll
    for (int q = 0; q < 2; ++q) {
        int slot = q*256 + tid;
        int r = slot >> 2, p = slot & 3;
        int c = p ^ ((r >> 1) & 3);
        int rr  = min(t0 + r, ce - 1);
        asrc[q] = xb + (size_t)gtok[base + rr] * HID_ + c*8;
    }
    // B stage sources (4 x 16B per thread), fp32 8-chunk swizzle
    const float* bsrc[4];
#pragma unroll
    for (int q = 0; q < 4; ++q) {
        int slot = q*256 + tid;
        int r = slot >> 3, p = slot & 7;
        int c = p ^ (r & 7);
        int q2 = r >> 5, s = r & 31;
        int grow = (q2 & 1) ? (FFN_ + n0 + (q2>>1)*32 + s)
                            : (       n0 + (q2>>1)*32 + s);
        bsrc[q] = w1e + (size_t)grow * HID_ + c*4;
    }

    auto STAGE = [&](int b, int k0) {
#pragma unroll
        for (int q = 0; q < 2; ++q)
            __builtin_amdgcn_global_load_lds((GVOID*)(asrc[q] + k0),
                (LVOID*)(&As[b][(q*256 + wid*64)*8]), 16, 0, 0);
#pragma unroll
        for (int q = 0; q < 4; ++q)
            __builtin_amdgcn_global_load_lds((GVOID*)(bsrc[q] + k0),
                (LVOID*)(&Bsf[b][(q*256 + wid*64)*4]), 16, 0, 0);
    };

    f32x4 acc[4][4];
#pragma unroll
    for (int m = 0; m < 4; ++m)
#pragma unroll
        for (int n = 0; n < 4; ++n) acc[m][n] = (f32x4){0.f,0.f,0.f,0.f};

    auto COMPUTE = [&](int cb) {
        bf16x8 af[4], bfr[4];
#pragma unroll
        for (int m = 0; m < 4; ++m) {
            int r = wm*64 + m*16 + (lane & 15);
            int sw = cf ^ ((r >> 1) & 3);
            af[m] = *(bf16x8*)&As[cb][r*32 + sw*8];
        }
#pragma unroll
        for (int n = 0; n < 4; ++n) {
            int r = wn*64 + n*16 + (lane & 15);
            int p0 = (2*cf)     ^ (r & 7);
            int p1 = (2*cf + 1) ^ (r & 7);
            f32x4 lo = *(f32x4*)&Bsf[cb][r*32 + p0*4];
            f32x4 hi = *(f32x4*)&Bsf[cb][r*32 + p1*4];
            bfr[n] = pk8(lo, hi);
        }
        __builtin_amdgcn_s_setprio(1);
#pragma unroll
        for (int m = 0; m < 4; ++m)
#pragma unroll
            for (int n = 0; n < 4; ++n)
                acc[m][n] = __builtin_amdgcn_mfma_f32_16x16x32_bf16(
                    af[m], bfr[n], acc[m][n], 0, 0, 0);
        __builtin_amdgcn_s_setprio(0);
    };

    const int NT = HID_/32;   // 32
    STAGE(0, 0);
    __syncthreads();
    for (int t = 0; t < NT; ++t) {
        int cur = t & 1, nxt = cur ^ 1;
        if (t + 1 < NT) STAGE(nxt, (t+1)*32);
        COMPUTE(cur);
        __syncthreads();
    }

    // Epilogue: fused SiLU(gate)*up -> h (bf16)
    const float* w1be = w1b + e*2*FFN_;
#pragma unroll
    for (int n = 0; n < 2; ++n) {
        int col = n0 + wn*32 + n*16 + (lane & 15);
        float bg = w1be[col];
        float bu = w1be[FFN_ + col];
#pragma unroll
        for (int m = 0; m < 4; ++m) {
            int rb2 = t0 + wm*64 + m*16 + (lane >> 4)*4;
#pragma unroll
            for (int i = 0; i < 4; ++i) {
                int t = rb2 + i;
                if (t < ce) {
                    float g = acc[m][n][i]   + bg;
                    float u = acc[m][n+2][i] + bu;
                    float hv = (g / (1.f + __expf(-g))) * u;
                    h[(size_t)(base + t)*FFN_ + col] = __float2bfloat16(hv);
                }
            }
        }
    }
}

// GEMM2: 128 pairs x 128 hid cols, split-K=2 (z = e + 8*ks). B = w2 fp32
// staged raw + cvt at read. Plain stores into dpair[ks]; combine sums.
__global__ __launch_bounds__(256, 3) void gemm2_kernel(
    const __hip_bfloat16* __restrict__ h, const float* __restrict__ w2,
    const float* __restrict__ w2b, const float* __restrict__ gwt,
    const int* __restrict__ cnt, const int* __restrict__ off,
    float* __restrict__ dpair)
{
    const int e  = blockIdx.z & 7;
    const int ks = blockIdx.z >> 3;
    const int ce = cnt[e];
    const int t0 = blockIdx.y * 128;
    if (t0 >= ce) return;
    const int n0    = blockIdx.x * 128;
    const int base  = off[e];
    const int kbase = ks * (FFN_/2);
    const float* w2e = w2 + (size_t)e * HID_ * FFN_;

    __shared__ __align__(16) __hip_bfloat16 As[2][128*32];
    __shared__ __align__(16) float          Bsf[2][128*32];

    const int tid  = threadIdx.x;
    const int lane = tid & 63;
    const int wid  = tid >> 6;
    const int wm   = wid >> 1;
    const int wn   = wid & 1;
    const int cf   = lane >> 4;

    const __hip_bfloat16* asrc[2];
#pragma unroll
    for (int q = 0; q < 2; ++q) {
        int slot = q*256 + tid;
        int r = slot >> 2, p = slot & 3;
        int c = p ^ ((r >> 1) & 3);
        int rr = min(t0 + r, ce - 1);
        asrc[q] = h + (size_t)(base + rr) * FFN_ + kbase + c*8;
    }
    const float* bsrc[4];
#pragma unroll
    for (int q = 0; q < 4; ++q) {
        int slot = q*256 + tid;
        int r = slot >> 3, p = slot & 7;
        int c = p ^ (r & 7);
        bsrc[q] = w2e + (size_t)(n0 + r) * FFN_ + kbase + c*4;
    }

    auto STAGE = [&](int b, int k0) {
#pragma unroll
        for (int q = 0; q < 2; ++q)
            __builtin_amdgcn_global_load_lds((GVOID*)(asrc[q] + k0),
                (LVOID*)(&As[b][(q*256 + wid*64)*8]), 16, 0, 0);
#pragma unroll
        for (int q = 0; q < 4; ++q)
            __builtin_amdgcn_global_load_lds((GVOID*)(bsrc[q] + k0),
                (LVOID*)(&Bsf[b][(q*256 + wid*64)*4]), 16, 0, 0);
    };

    f32x4 acc[4][4];
#pragma unroll
    for (int m = 0; m < 4; ++m)
#pragma unroll
        for (int n = 0; n < 4; ++n) acc[m][n] = (f32x4){0.f,0.f,0.f,0.f};

    auto COMPUTE = [&](int cb) {
        bf16x8 af[4], bfr[4];
#pragma unroll
        for (int m = 0; m < 4; ++m) {
            int r = wm*64 + m*16 + (lane & 15);
            int sw = cf ^ ((r >> 1) & 3);
            af[m] = *(bf16x8*)&As[cb][r*32 + sw*8];
        }
#pragma unroll
        for (int n = 0; n < 4; ++n) {
            int r = wn*64 + n*16 + (lane & 15);
            int p0 = (2*cf)     ^ (r & 7);
            int p1 = (2*cf + 1) ^ (r & 7);
            f32x4 lo = *(f32x4*)&Bsf[cb][r*32 + p0*4];
            f32x4 hi = *(f32x4*)&Bsf[cb][r*32 + p1*4];
            bfr[n] = pk8(lo, hi);
        }
        __builtin_amdgcn_s_setprio(1);
#pragma unroll
        for (int m = 0; m < 4; ++m)
#pragma unroll
            for (int n = 0; n < 4; ++n)
                acc[m][n] = __builtin_amdgcn_mfma_f32_16x16x32_bf16(
                    af[m], bfr[n], acc[m][n], 0, 0, 0);
        __builtin_amdgcn_s_setprio(0);
    };

    const int NT = (FFN_/2)/32;   // 32
    STAGE(0, 0);
    __syncthreads();
    for (int t = 0; t < NT; ++t) {
        int cur = t & 1, nxt = cur ^ 1;
        if (t + 1 < NT) STAGE(nxt, (t+1)*32);
        COMPUTE(cur);
        __syncthreads();
    }

    const float* w2be = w2b + e*HID_;
    float* dpk = dpair + (size_t)ks * NP_ * HID_;
#pragma unroll
    for (int n = 0; n < 4; ++n) {
        int col = n0 + wn*64 + n*16 + (lane & 15);
        float bias = (ks == 0) ? w2be[col] : 0.f;
#pragma unroll
        for (int m = 0; m < 4; ++m) {
            int rb2 = t0 + wm*64 + m*16 + (lane >> 4)*4;
#pragma unroll
            for (int i = 0; i < 4; ++i) {
                int t = rb2 + i;
                if (t < ce) {
                    int p   = base + t;
                    float w = gwt[p];
                    dpk[(size_t)p*HID_ + col] = w * (acc[m][n][i] + bias);
                }
            }
        }
    }
}

// out[m][c] = d0[p0][c]+d1[p0][c]+d0[p1][c]+d1[p1][c]   (fixed order)
__global__ __launch_bounds__(256) void combine_kernel(
    const float* __restrict__ dpair, const int* __restrict__ pos,
    float* __restrict__ out)
{
    int idx = blockIdx.x * 256 + threadIdx.x;
    int m   = idx >> 8;
    int c4  = (idx & 255) * 4;
    int p0 = pos[2*m], p1 = pos[2*m+1];
    const float* d0 = dpair;
    const float* d1 = dpair + (size_t)NP_ * HID_;
    float4 a0 = *(const float4*)(d0 + (size_t)p0*HID_ + c4);
    float4 a1 = *(const float4*)(d1 + (size_t)p0*HID_ + c4);
    float4 b0 = *(const float4*)(d0 + (size_t)p1*HID_ + c4);
    float4 b1 = *(const float4*)(d1 + (size_t)p1*HID_ + c4);
    float4 o = make_float4((a0.x+a1.x)+(b0.x+b1.x), (a0.y+a1.y)+(b0.y+b1.y),
                           (a0.z+a1.z)+(b0.z+b1.z), (a0.w+a1.w)+(b0.w+b1.w));
    *(float4*)(out + (size_t)m*HID_ + c4) = o;
}

// ===========================================================================
// FALLBACK (proven round-2 structure) — only if ws_size too small for tier2.
// ===========================================================================
__global__ __launch_bounds__(256) void gemm1_rs_kernel(
    const __hip_bfloat16* __restrict__ xb, const float* __restrict__ w1,
    const float* __restrict__ w1b, const int* __restrict__ gtok,
    const int* __restrict__ cnt, const int* __restrict__ off,
    __hip_bfloat16* __restrict__ h)
{
    const int e  = blockIdx.z;
    const int ce = cnt[e];
    const int t0 = blockIdx.y * 128;
    if (t0 >= ce) return;
    const int n0   = blockIdx.x * 64;
    const int base = off[e];
    const float* w1e = w1 + (size_t)e * (2*FFN_) * HID_;

    __shared__ __align__(16) __hip_bfloat16 As[128*64];
    __shared__ __align__(16) __hip_bfloat16 Bs[128*64];

    const int tid  = threadIdx.x;
    const int lane = tid & 63;
    const int wid  = tid >> 6;
    const int wm   = wid >> 1;
    const int wn   = wid & 1;

    const __hip_bfloat16* asrc[4];
#pragma unroll
    for (int q = 0; q < 4; ++q) {
        int slot = q*256 + tid;
        int r = slot >> 3, p = slot & 7;
        int rr  = min(t0 + r, ce - 1);
        int tok = gtok[base + rr];
        int c = p ^ (r & 7);
        asrc[q] = xb + (size_t)tok * HID_ + c*8;
    }

    const int brow = tid >> 1;
    const int hk   = tid & 1;
    const int q2 = brow >> 5, s = brow & 31;
    const int grow = (q2 & 1) ? (FFN_ + n0 + (q2>>1)*32 + s)
                              : (       n0 + (q2>>1)*32 + s);
    const float* bsrc = w1e + (size_t)grow * HID_ + hk*32;

    f32x4 acc[4][4];
#pragma unroll
    for (int m = 0; m < 4; ++m)
#pragma unroll
        for (int n = 0; n < 4; ++n) acc[m][n] = (f32x4){0.f,0.f,0.f,0.f};

    float4 breg[8];
#pragma unroll
    for (int j = 0; j < 8; ++j) breg[j] = *(const float4*)(bsrc + j*4);

    for (int k0 = 0; k0 < HID_; k0 += 64) {
#pragma unroll
        for (int q = 0; q < 4; ++q) {
            __builtin_amdgcn_global_load_lds(
                (GVOID*)(asrc[q] + k0),
                (LVOID*)(&As[(q*256 + wid*64)*8]), 16, 0, 0);
        }
#pragma unroll
        for (int cc = 0; cc < 4; ++cc) {
            union { bf16x8 v; short s8[8]; } u;
            const float* f0 = (const float*)&breg[2*cc];
#pragma unroll
            for (int j = 0; j < 8; ++j) u.s8[j] = f2bf(f0[j]);
            int c = hk*4 + cc, p = c ^ (brow & 7);
            *(bf16x8*)&Bs[brow*64 + p*8] = u.v;
        }
        __syncthreads();

        if (k0 + 64 < HID_) {
#pragma unroll
            for (int j = 0; j < 8; ++j) breg[j] = *(const float4*)(bsrc + (k0+64) + j*4);
        }

        bf16x8 af[4][2], bfr[4][2];
#pragma unroll
        for (int m = 0; m < 4; ++m)
#pragma unroll
            for (int kk = 0; kk < 2; ++kk) {
                int r = wm*64 + m*16 + (lane & 15);
                int c = kk*4 + (lane >> 4), p = c ^ (r & 7);
                af[m][kk] = *(bf16x8*)&As[r*64 + p*8];
            }
#pragma unroll
        for (int n = 0; n < 4; ++n)
#pragma unroll
            for (int kk = 0; kk < 2; ++kk) {
                int r = wn*64 + n*16 + (lane & 15);
                int c = kk*4 + (lane >> 4), p = c ^ (r & 7);
                bfr[n][kk] = *(bf16x8*)&Bs[r*64 + p*8];
            }
#pragma unroll
        for (int kk = 0; kk < 2; ++kk)
#pragma unroll
            for (int m = 0; m < 4; ++m)
#pragma unroll
                for (int n = 0; n < 4; ++n)
                    acc[m][n] = __builtin_amdgcn_mfma_f32_16x16x32_bf16(
                        af[m][kk], bfr[n][kk], acc[m][n], 0, 0, 0);
        __syncthreads();
    }

    const float* w1be = w1b + e*2*FFN_;
#pragma unroll
    for (int n = 0; n < 2; ++n) {
        int col = n0 + wn*32 + n*16 + (lane & 15);
        float bg = w1be[col];
        float bu = w1be[FFN_ + col];
#pragma unroll
        for (int m = 0; m < 4; ++m) {
            int rb2 = t0 + wm*64 + m*16 + (lane >> 4)*4;
#pragma unroll
            for (int i = 0; i < 4; ++i) {
                int t = rb2 + i;
                if (t < ce) {
                    float g = acc[m][n][i]   + bg;
                    float u = acc[m][n+2][i] + bu;
                    float hv = (g / (1.f + __expf(-g))) * u;
                    h[(size_t)(base + t)*FFN_ + col] = __float2bfloat16(hv);
                }
            }
        }
    }
}

__global__ __launch_bounds__(256) void gemm2_rs_kernel(
    const __hip_bfloat16* __restrict__ h, const float* __restrict__ w2,
    const float* __restrict__ w2b, const int* __restrict__ gtok,
    const float* __restrict__ gwt, const int* __restrict__ cnt,
    const int* __restrict__ off, float* __restrict__ out)
{
    const int e  = blockIdx.z;
    const int ce = cnt[e];
    const int t0 = blockIdx.y * 128;
    if (t0 >= ce) return;
    const int n0   = blockIdx.x * 128;
    const int base = off[e];
    const float* w2e = w2 + (size_t)e * HID_ * FFN_;

    __shared__ __align__(16) __hip_bfloat16 As[128*64];
    __shared__ __align__(16) __hip_bfloat16 Bs[128*64];

    const int tid  = threadIdx.x;
    const int lane = tid & 63;
    const int wid  = tid >> 6;
    const int wm   = wid >> 1;
    const int wn   = wid & 1;

    const __hip_bfloat16* asrc[4];
#pragma unroll
    for (int q = 0; q < 4; ++q) {
        int slot = q*256 + tid;
        int r = slot >> 3, p = slot & 7;
        int rr = min(t0 + r, ce - 1);
        int c = p ^ (r & 7);
        asrc[q] = h + (size_t)(base + rr) * FFN_ + c*8;
    }

    const int brow = tid >> 1;
    const int hk   = tid & 1;
    const float* bsrc = w2e + (size_t)(n0 + brow) * FFN_ + hk*32;

    f32x4 acc[4][4];
#pragma unroll
    for (int m = 0; m < 4; ++m)
#pragma unroll
        for (int n = 0; n < 4; ++n) acc[m][n] = (f32x4){0.f,0.f,0.f,0.f};

    float4 breg[8];
#pragma unroll
    for (int j = 0; j < 8; ++j) breg[j] = *(const float4*)(bsrc + j*4);

    for (int k0 = 0; k0 < FFN_; k0 += 64) {
#pragma unroll
        for (int q = 0; q < 4; ++q) {
            __builtin_amdgcn_global_load_lds(
                (GVOID*)(asrc[q] + k0),
                (LVOID*)(&As[(q*256 + wid*64)*8]), 16, 0, 0);
        }
#pragma unroll
        for (int cc = 0; cc < 4; ++cc) {
            union { bf16x8 v; short s8[8]; } u;
            const float* f0 = (const float*)&breg[2*cc];
#pragma unroll
            for (int j = 0; j < 8; ++j) u.s8[j] = f2bf(f0[j]);
            int c = hk*4 + cc, p = c ^ (brow & 7);
            *(bf16x8*)&Bs[brow*64 + p*8] = u.v;
        }
        __syncthreads();

        if (k0 + 64 < FFN_) {
#pragma unroll
            for (int j = 0; j < 8; ++j) breg[j] = *(const float4*)(bsrc + (k0+64) + j*4);
        }

        bf16x8 af[4][2], bfr[4][2];
#pragma unroll
        for (int m = 0; m < 4; ++m)
#pragma unroll
            for (int kk = 0; kk < 2; ++kk) {
                int r = wm*64 + m*16 + (lane & 15);
                int c = kk*4 + (lane >> 4), p = c ^ (r & 7);
                af[m][kk] = *(bf16x8*)&As[r*64 + p*8];
            }
#pragma unroll
        for (int n = 0; n < 4; ++n)
#pragma unroll
            for (int kk = 0; kk < 2; ++kk) {
                int r = wn*64 + n*16 + (lane & 15);
                int c = kk*4 + (lane >> 4), p = c ^ (r & 7);
                bfr[n][kk] = *(bf16x8*)&Bs[r*64 + p*8];
            }
#pragma unroll
        for (int kk = 0; kk < 2; ++kk)
#pragma unroll
            for (int m = 0; m < 4; ++m)
#pragma unroll
                for (int n = 0; n < 4; ++n)
                    acc[m][n] = __builtin_amdgcn_mfma_f32_16x16x32_bf16(
                        af[m][kk], bfr[n][kk], acc[m][n], 0, 0, 0);
        __syncthreads();
    }

    const float* w2be = w2b + e*HID_;
#pragma unroll
    for (int n = 0; n < 4; ++n) {
        int col = n0 + wn*64 + n*16 + (lane & 15);
        float bias = w2be[col];
#pragma unroll
        for (int m = 0; m < 4; ++m) {
            int rb2 = t0 + wm*64 + m*16 + (lane >> 4)*4;
#pragma unroll
            for (int i = 0; i < 4; ++i) {
                int t = rb2 + i;
                if (t < ce) {
                    int p   = base + t;
                    float w = gwt[p];
                    atomicAdd(&out[(size_t)gtok[p]*HID_ + col], w * (acc[m][n][i] + bias));
                }
            }
        }
    }
}

// ---------------------------------------------------------------------------
extern "C" void kernel_launch(void* const* d_in, const int* in_sizes, int n_in,
                              void* d_out, int out_size, void* d_ws, size_t ws_size,
                              hipStream_t stream)
{
    const float* x   = (const float*)d_in[0];
    const float* rw  = (const float*)d_in[1];
    const float* rb  = (const float*)d_in[2];
    const float* w1  = (const float*)d_in[3];
    const float* w1b = (const float*)d_in[4];
    const float* w2  = (const float*)d_in[5];
    const float* w2b = (const float*)d_in[6];

    float* out      = (float*)d_out;
    float* topk_out = out + (size_t)M_ * HID_;

    char*  ws   = (char*)d_ws;
    int*   ids  = (int*)  (ws);
    float* wts  = (float*)(ws + 16384);
    int*   gtok = (int*)  (ws + 32768);
    float* gwt  = (float*)(ws + 49152);
    int*   cnt  = (int*)  (ws + 65536);
    int*   off  = (int*)  (ws + 65536 + 128);
    int*   fill = (int*)  (ws + 65536 + 256);
    int*   pos  = (int*)  (ws + 98304);

    const size_t MB = 1024*1024;
    __hip_bfloat16* xb    = (__hip_bfloat16*)(ws + 131072);            // 4 MB
    __hip_bfloat16* h     = (__hip_bfloat16*)(ws + 131072 + 4*MB);     // 16 MB
    float*          dpair = (float*)         (ws + 131072 + 20*MB);    // 32 MB
    const bool tier2 = (ws_size >= 131072 + 52*MB);

    hipMemsetAsync(cnt, 0, E_ * sizeof(int), stream);

    router_kernel<<<M_, 64, 0, stream>>>(x, rw, rb, ids, wts, cnt, topk_out, xb);
    offsets_kernel<<<1, 64, 0, stream>>>(cnt, off, fill);
    scatter_kernel<<<M_/256, 256, 0, stream>>>(ids, wts, fill, gtok, gwt, pos);

    if (tier2) {
        dim3 g1(FFN_/64, M_/128, E_);        // (32, 16, 8)
        gemm1_kernel<<<g1, 256, 0, stream>>>(xb, w1, w1b, gtok, cnt, off, h);

        dim3 g2(HID_/128, M_/128, 2*E_);     // (8, 16, 16) split-K=2
        gemm2_kernel<<<g2, 256, 0, stream>>>(h, w2, w2b, gwt, cnt, off, dpair);

        combine_kernel<<<(M_*HID_)/(256*4), 256, 0, stream>>>(dpair, pos, out);
    } else {
        hipMemsetAsync(out, 0, (size_t)M_ * HID_ * sizeof(float), stream);

        dim3 g1(FFN_/64, M_/128, E_);
        gemm1_rs_kernel<<<g1, 256, 0, stream>>>(xb, w1, w1b, gtok, cnt, off, h);

        dim3 g2(HID_/128, M_/128, E_);
        gemm2_rs_kernel<<<g2, 256, 0, stream>>>(h, w2, w2b, gtok, gwt, cnt, off, out);
    }
}